// Round 1
// baseline (2298.121 us; speedup 1.0000x reference)
//
#include <hip/hip_runtime.h>
#include <math.h>

#define N_NODES 16000
#define N_EDGES 256000
#define DIN 1280
#define HID 256
#define HEADS 8
#define CPH 32
#define NG 32
#define NO 64
#define EPSC 1e-5f

__device__ __forceinline__ float lrelu(float v) { return v > 0.f ? v : 0.2f * v; }

__device__ __forceinline__ void atomicMaxFloat(float* addr, float val) {
    if (val >= 0.f) atomicMax((int*)addr, __float_as_int(val));
    else            atomicMin((unsigned int*)addr, __float_as_uint(val));
}

// ---------------- generic fused GEMM: C[M,256] = A[M,K] @ B[K,256] + bias ----------------
// mode 0: bias only; mode 1: bias,relu,bn; mode 2: bias,relu,bn,leaky(0.2)
__global__ __launch_bounds__(256) void gemm256(
    const float* __restrict__ A, const float* __restrict__ B,
    const float* __restrict__ bias, float* __restrict__ C,
    int M, int K, int mode, const float* __restrict__ g, const float* __restrict__ be)
{
    __shared__ float As[16][68];
    __shared__ float Bs[16][68];
    const int tid = threadIdx.x;
    const int bm = blockIdx.y * 64;
    const int bn = blockIdx.x * 64;
    const int trow = (tid >> 4) << 2;
    const int tcol = (tid & 15) << 2;
    const int arow = tid >> 2;
    const int acol = (tid & 3) << 2;
    const int brow = tid >> 4;
    const int bcol = (tid & 15) << 2;
    float acc[4][4] = {};
    for (int k0 = 0; k0 < K; k0 += 16) {
        float4 av = *(const float4*)(A + (size_t)(bm + arow) * K + k0 + acol);
        As[acol + 0][arow] = av.x;
        As[acol + 1][arow] = av.y;
        As[acol + 2][arow] = av.z;
        As[acol + 3][arow] = av.w;
        *(float4*)(&Bs[brow][bcol]) = *(const float4*)(B + (size_t)(k0 + brow) * HID + bn + bcol);
        __syncthreads();
#pragma unroll
        for (int k = 0; k < 16; ++k) {
            float4 a4 = *(const float4*)&As[k][trow];
            float4 b4 = *(const float4*)&Bs[k][tcol];
            acc[0][0] += a4.x * b4.x; acc[0][1] += a4.x * b4.y; acc[0][2] += a4.x * b4.z; acc[0][3] += a4.x * b4.w;
            acc[1][0] += a4.y * b4.x; acc[1][1] += a4.y * b4.y; acc[1][2] += a4.y * b4.z; acc[1][3] += a4.y * b4.w;
            acc[2][0] += a4.z * b4.x; acc[2][1] += a4.z * b4.y; acc[2][2] += a4.z * b4.z; acc[2][3] += a4.z * b4.w;
            acc[3][0] += a4.w * b4.x; acc[3][1] += a4.w * b4.y; acc[3][2] += a4.w * b4.z; acc[3][3] += a4.w * b4.w;
        }
        __syncthreads();
    }
    const float inv = rsqrtf(1.f + EPSC);
#pragma unroll
    for (int i = 0; i < 4; ++i) {
        int row = bm + trow + i;
#pragma unroll
        for (int j = 0; j < 4; ++j) {
            int col = bn + tcol + j;
            float z = acc[i][j] + bias[col];
            if (mode >= 1) { z = fmaxf(z, 0.f); z = z * (g[col] * inv) + be[col]; }
            if (mode == 2) z = lrelu(z);
            C[(size_t)row * HID + col] = z;
        }
    }
}

// ---------------- misc fills ----------------
__global__ void fill_kernel(float* p, float v, int n) {
    int i = blockIdx.x * 256 + threadIdx.x;
    if (i < n) p[i] = v;
}
__global__ void row_fill_kernel(float* p, const float* __restrict__ bias, int n) {
    int i = blockIdx.x * 256 + threadIdx.x;
    if (i < n) p[i] = bias[i & (HID - 1)];
}

// ---------------- GATv2 edge kernels ----------------
// elog[e,h] = sum_c leaky(xl[src,h,c]+xr[dst,h,c],0.2)*att[h,c]; atomicMax into m[dst,h]
__global__ void edge_logit_max(const float* __restrict__ xl, const float* __restrict__ xr,
                               const int* __restrict__ ei, const float* __restrict__ att,
                               float* __restrict__ elog, float* __restrict__ m)
{
    int idx = blockIdx.x * 256 + threadIdx.x;
    const int EP = N_EDGES + N_NODES;
    if (idx >= EP * HEADS) return;
    int e = idx >> 3, h = idx & 7;
    int s, d;
    if (e < N_EDGES) { s = ei[e]; d = ei[N_EDGES + e]; } else { s = e - N_EDGES; d = s; }
    const float* pl = xl + (size_t)s * HID + h * CPH;
    const float* pr = xr + (size_t)d * HID + h * CPH;
    const float* pa = att + h * CPH;
    float acc = 0.f;
#pragma unroll
    for (int c4 = 0; c4 < 8; ++c4) {
        float4 l = *(const float4*)(pl + c4 * 4);
        float4 r = *(const float4*)(pr + c4 * 4);
        float4 a = *(const float4*)(pa + c4 * 4);
        acc += lrelu(l.x + r.x) * a.x + lrelu(l.y + r.y) * a.y
             + lrelu(l.z + r.z) * a.z + lrelu(l.w + r.w) * a.w;
    }
    elog[idx] = acc;
    atomicMaxFloat(&m[d * HEADS + h], acc);
}

__global__ void edge_exp_sum(const int* __restrict__ ei, const float* __restrict__ m,
                             float* __restrict__ elog, float* __restrict__ ssum)
{
    int idx = blockIdx.x * 256 + threadIdx.x;
    const int EP = N_EDGES + N_NODES;
    if (idx >= EP * HEADS) return;
    int e = idx >> 3, h = idx & 7;
    int d;
    if (e < N_EDGES) d = ei[N_EDGES + e]; else d = e - N_EDGES;
    float ev = expf(elog[idx] - m[d * HEADS + h]);
    elog[idx] = ev;
    atomicAdd(&ssum[d * HEADS + h], ev);
}

// hnew[dst,ch] += (ev/(s+1e-16)) * xl[src,ch]
__global__ void edge_aggregate(const float* __restrict__ xl, const float* __restrict__ ev,
                               const float* __restrict__ ssum, const int* __restrict__ ei,
                               float* __restrict__ hnew)
{
    int e = blockIdx.x;
    int ch = threadIdx.x;
    int h = ch >> 5;
    int s, d;
    if (e < N_EDGES) { s = ei[e]; d = ei[N_EDGES + e]; } else { s = e - N_EDGES; d = s; }
    float a = ev[e * HEADS + h] / (ssum[d * HEADS + h] + 1e-16f);
    atomicAdd(&hnew[(size_t)d * HID + ch], a * xl[(size_t)s * HID + ch]);
}

// u[dst0,ch] += h[src0,ch]  (original edges only)
__global__ void gin_scatter(const float* __restrict__ h, const int* __restrict__ ei,
                            float* __restrict__ u)
{
    int e = blockIdx.x;
    int ch = threadIdx.x;
    int s = ei[e], d = ei[N_EDGES + e];
    atomicAdd(&u[(size_t)d * HID + ch], h[(size_t)s * HID + ch]);
}

// ---------------- global LN stats ----------------
__global__ void stats_kernel(const float* __restrict__ x, float* __restrict__ stats, int n) {
    float s = 0.f, sq = 0.f;
    for (int i = blockIdx.x * blockDim.x + threadIdx.x; i < n; i += gridDim.x * blockDim.x) {
        float v = x[i]; s += v; sq += v * v;
    }
    for (int o = 32; o > 0; o >>= 1) { s += __shfl_down(s, o); sq += __shfl_down(sq, o); }
    __shared__ float ls[4], lq[4];
    int wid = threadIdx.x >> 6, lane = threadIdx.x & 63;
    if (lane == 0) { ls[wid] = s; lq[wid] = sq; }
    __syncthreads();
    if (threadIdx.x == 0) {
        float ts = 0.f, tq = 0.f;
        for (int w = 0; w < 4; ++w) { ts += ls[w]; tq += lq[w]; }
        atomicAdd(&stats[0], ts);
        atomicAdd(&stats[1], tq);
    }
}

// h_out = leaky( (h-mu)/(sd+eps)*g + b + r , 0.2 )
__global__ void ln_res_kernel(const float* __restrict__ h, const float* __restrict__ r,
                              const float* __restrict__ stats, const float* __restrict__ g,
                              const float* __restrict__ b, float* __restrict__ out, int n)
{
    int i = blockIdx.x * 256 + threadIdx.x;
    if (i >= n) return;
    float inv_n = 1.0f / (float)n;
    float mu = stats[0] * inv_n;
    float var = stats[1] * inv_n - mu * mu;
    float sd = sqrtf(fmaxf(var, 0.f));
    int ch = i & (HID - 1);
    float v = (h[i] - mu) / (sd + EPSC) * g[ch] + b[ch] + r[i];
    out[i] = lrelu(v);
}

// ---------------- pooling ----------------
__global__ void pool_gate_kernel(const float* __restrict__ t, const float* __restrict__ W2,
                                 const float* __restrict__ b2, float* __restrict__ gate)
{
    int nidx = blockIdx.x;
    int k = threadIdx.x;
    __shared__ float red[256];
    red[k] = tanhf(t[(size_t)nidx * HID + k]) * W2[k];
    __syncthreads();
    for (int st = 128; st > 0; st >>= 1) { if (k < st) red[k] += red[k + st]; __syncthreads(); }
    if (k == 0) gate[nidx] = red[0] + b2[0];
}

__global__ void node_max_kernel(const float* __restrict__ gate, const int* __restrict__ batch,
                                float* __restrict__ gmax) {
    int n = blockIdx.x * 256 + threadIdx.x;
    if (n < N_NODES) atomicMaxFloat(&gmax[batch[n]], gate[n]);
}
__global__ void node_expsum_kernel(float* __restrict__ gate, const int* __restrict__ batch,
                                   const float* __restrict__ gmax, float* __restrict__ gsum) {
    int n = blockIdx.x * 256 + threadIdx.x;
    if (n < N_NODES) {
        float e = expf(gate[n] - gmax[batch[n]]);
        gate[n] = e;
        atomicAdd(&gsum[batch[n]], e);
    }
}
__global__ void emb_scatter(const float* __restrict__ e, const float* __restrict__ gsum,
                            const int* __restrict__ batch, const float* __restrict__ h,
                            float* __restrict__ emb) {
    int nidx = blockIdx.x;
    int k = threadIdx.x;
    int b = batch[nidx];
    float a = e[nidx] / (gsum[b] + 1e-16f);
    atomicAdd(&emb[b * HID + k], a * h[(size_t)nidx * HID + k]);
}

// ---------------- label heads ----------------
__global__ __launch_bounds__(256) void heads_kernel(
    const float* __restrict__ emb, const float* __restrict__ W1, const float* __restrict__ b1,
    const float* __restrict__ hg, const float* __restrict__ hbe, const float* __restrict__ W2,
    const float* __restrict__ b2, float* __restrict__ out)
{
    int o = blockIdx.x;
    int k = threadIdx.x;
    __shared__ float se[HID];
    __shared__ float red[256];
    const float w2 = W2[o * HID + k];
    const float bb1 = b1[o * HID + k];
    const float gk = hg[o * HID + k] * rsqrtf(1.f + EPSC);
    const float bek = hbe[o * HID + k];
    const float b2o = b2[o];
    const float* w1p = W1 + (size_t)o * HID * HID + k;   // W1[o][d][k], stride 256 over d
    for (int g = 0; g < NG; ++g) {
        __syncthreads();
        se[k] = emb[g * HID + k];
        __syncthreads();
        float z = bb1;
#pragma unroll 4
        for (int d4 = 0; d4 < HID / 4; ++d4) {
            float4 ev = *(const float4*)&se[d4 * 4];
            z = fmaf(ev.x, w1p[(size_t)(d4 * 4 + 0) * HID], z);
            z = fmaf(ev.y, w1p[(size_t)(d4 * 4 + 1) * HID], z);
            z = fmaf(ev.z, w1p[(size_t)(d4 * 4 + 2) * HID], z);
            z = fmaf(ev.w, w1p[(size_t)(d4 * 4 + 3) * HID], z);
        }
        float sil = z / (1.f + expf(-z));     // silu
        float val = (sil * gk + bek) * w2;    // bn then dot with W2
        red[k] = val;
        __syncthreads();
        for (int st = 128; st > 0; st >>= 1) { if (k < st) red[k] += red[k + st]; __syncthreads(); }
        if (k == 0) out[g * NO + o] = red[0] + b2o;
    }
}

extern "C" void kernel_launch(void* const* d_in, const int* in_sizes, int n_in,
                              void* d_out, int out_size, void* d_ws, size_t ws_size,
                              hipStream_t stream) {
    const float* x        = (const float*)d_in[0];
    const int*   ei       = (const int*)  d_in[1];
    const int*   batch    = (const int*)  d_in[2];
    const float* fp_W     = (const float*)d_in[3];
    const float* fp_b     = (const float*)d_in[4];
    const float* fp_g     = (const float*)d_in[5];
    const float* fp_be    = (const float*)d_in[6];
    const float* gat_Wl   = (const float*)d_in[7];
    const float* gat_bl   = (const float*)d_in[8];
    const float* gat_Wr   = (const float*)d_in[9];
    const float* gat_br   = (const float*)d_in[10];
    const float* gat_att  = (const float*)d_in[11];
    const float* gat_bias = (const float*)d_in[12];
    const float* gin_W    = (const float*)d_in[13];
    const float* gin_b    = (const float*)d_in[14];
    const float* gin_g    = (const float*)d_in[15];
    const float* gin_be   = (const float*)d_in[16];
    const float* ln_g     = (const float*)d_in[17];
    const float* ln_b     = (const float*)d_in[18];
    const float* res_W    = (const float*)d_in[19];
    const float* res_b    = (const float*)d_in[20];
    const float* pool_W1  = (const float*)d_in[21];
    const float* pool_b1  = (const float*)d_in[22];
    const float* pool_W2  = (const float*)d_in[23];
    const float* pool_b2  = (const float*)d_in[24];
    const float* head_W1  = (const float*)d_in[25];
    const float* head_b1  = (const float*)d_in[26];
    const float* head_g   = (const float*)d_in[27];
    const float* head_be  = (const float*)d_in[28];
    const float* head_W2  = (const float*)d_in[29];
    const float* head_b2  = (const float*)d_in[30];
    float* out = (float*)d_out;

    const size_t NH = (size_t)N_NODES * HID;        // 4,096,000
    const int    EP = N_EDGES + N_NODES;            // 272,000
    float* ws   = (float*)d_ws;
    float* B0   = ws;                                // current h
    float* B1   = B0 + NH;
    float* B2   = B1 + NH;
    float* B3   = B2 + NH;
    float* elog = B3 + NH;                           // EP*8
    float* mbuf = elog + (size_t)EP * HEADS;         // N*8
    float* sbuf = mbuf + (size_t)N_NODES * HEADS;    // N*8
    float* gate = sbuf + (size_t)N_NODES * HEADS;    // N
    float* gmax = gate + N_NODES;                    // 32
    float* gsum = gmax + NG;                         // 32
    float* emb  = gsum + NG;                         // 32*256
    float* stat = emb + NG * HID;                    // 2

    dim3 ggrid(HID / 64, N_NODES / 64);
    const int nhBlocks = (int)(NH / 256);            // 16000
    const int ehThreads = EP * HEADS;                // 2,176,000
    const int ehBlocks = (ehThreads + 255) / 256;

    // 1) feature projection: h = BN(relu(x@fp_W+fp_b))
    gemm256<<<ggrid, 256, 0, stream>>>(x, fp_W, fp_b, B0, N_NODES, DIN, 1, fp_g, fp_be);

    for (int i = 0; i < 2; ++i) {
        const float* Wl = gat_Wl + (size_t)i * HID * HID;
        const float* Wr = gat_Wr + (size_t)i * HID * HID;
        // xl, xr
        gemm256<<<ggrid, 256, 0, stream>>>(B0, Wl, gat_bl + i * HID, B1, N_NODES, HID, 0, nullptr, nullptr);
        gemm256<<<ggrid, 256, 0, stream>>>(B0, Wr, gat_br + i * HID, B2, N_NODES, HID, 0, nullptr, nullptr);
        // segment softmax over dst
        fill_kernel<<<(N_NODES * HEADS + 255) / 256, 256, 0, stream>>>(mbuf, -INFINITY, N_NODES * HEADS);
        hipMemsetAsync(sbuf, 0, (size_t)N_NODES * HEADS * sizeof(float), stream);
        edge_logit_max<<<ehBlocks, 256, 0, stream>>>(B1, B2, ei, gat_att + i * HEADS * CPH, elog, mbuf);
        edge_exp_sum<<<ehBlocks, 256, 0, stream>>>(ei, mbuf, elog, sbuf);
        // aggregate: h_new = bias + sum alpha*xl[src]
        row_fill_kernel<<<nhBlocks, 256, 0, stream>>>(B3, gat_bias + i * HID, (int)NH);
        edge_aggregate<<<EP, 256, 0, stream>>>(B1, elog, sbuf, ei, B3);
        // GIN: u = h + sum_{src0->dst0} h[src0]
        hipMemcpyAsync(B0, B3, NH * sizeof(float), hipMemcpyDeviceToDevice, stream);
        gin_scatter<<<N_EDGES, 256, 0, stream>>>(B3, ei, B0);
        // h = leaky(BN(relu(u@gin_W+gin_b)))
        gemm256<<<ggrid, 256, 0, stream>>>(B0, gin_W + (size_t)i * HID * HID, gin_b + i * HID, B1,
                                           N_NODES, HID, 2, gin_g + i * HID, gin_be + i * HID);
        // global LN stats
        hipMemsetAsync(stat, 0, 2 * sizeof(float), stream);
        stats_kernel<<<1024, 256, 0, stream>>>(B1, stat, (int)NH);
        // residual linear
        gemm256<<<ggrid, 256, 0, stream>>>(B1, res_W + (size_t)i * HID * HID, res_b + i * HID, B2,
                                           N_NODES, HID, 0, nullptr, nullptr);
        // h = leaky(LN(h) + r)
        ln_res_kernel<<<nhBlocks, 256, 0, stream>>>(B1, B2, stat, ln_g + i * HID, ln_b + i * HID, B0, (int)NH);
    }

    // global attention pooling
    gemm256<<<ggrid, 256, 0, stream>>>(B0, pool_W1, pool_b1, B1, N_NODES, HID, 0, nullptr, nullptr);
    pool_gate_kernel<<<N_NODES, 256, 0, stream>>>(B1, pool_W2, pool_b2, gate);
    fill_kernel<<<1, 256, 0, stream>>>(gmax, -INFINITY, NG);
    hipMemsetAsync(gsum, 0, NG * sizeof(float), stream);
    node_max_kernel<<<(N_NODES + 255) / 256, 256, 0, stream>>>(gate, batch, gmax);
    node_expsum_kernel<<<(N_NODES + 255) / 256, 256, 0, stream>>>(gate, batch, gmax, gsum);
    hipMemsetAsync(emb, 0, (size_t)NG * HID * sizeof(float), stream);
    emb_scatter<<<N_NODES, 256, 0, stream>>>(gate, gsum, batch, B0, emb);

    // label heads
    heads_kernel<<<NO, 256, 0, stream>>>(emb, head_W1, head_b1, head_g, head_be, head_W2, head_b2, out);
}

// Round 2
// 1204.822 us; speedup vs baseline: 1.9074x; 1.9074x over previous
//
#include <hip/hip_runtime.h>
#include <math.h>

#define N_NODES 16000
#define N_EDGES 256000
#define EPE (N_EDGES + N_NODES)
#define DIN 1280
#define HID 256
#define HEADS 8
#define CPH 32
#define NG 32
#define NO 64
#define EPSC 1e-5f

typedef __bf16 bf16;
typedef __attribute__((ext_vector_type(8))) __bf16 bf16x8;
typedef __attribute__((ext_vector_type(4))) float floatx4;

typedef __attribute__((address_space(3))) unsigned int lds_u32;
typedef const __attribute__((address_space(1))) unsigned int glob_u32;

__device__ __forceinline__ float lrelu(float v) { return v > 0.f ? v : 0.2f * v; }

__device__ __forceinline__ void atomicMaxFloat(float* a, float v) {
    if (v >= 0.f) atomicMax((int*)a, __float_as_int(v));
    else          atomicMin((unsigned int*)a, __float_as_uint(v));
}

__device__ __forceinline__ void gll16(const void* g, void* l) {
    __builtin_amdgcn_global_load_lds((glob_u32*)g, (lds_u32*)l, 16, 0, 0);
}

// ---------- conversions ----------
__global__ void f2b_kernel(const float* __restrict__ in, bf16* __restrict__ out, int n) {
    int i = (blockIdx.x * 256 + threadIdx.x) * 4;
    if (i >= n) return;
    float4 v = *(const float4*)(in + i);
    out[i + 0] = (bf16)v.x; out[i + 1] = (bf16)v.y;
    out[i + 2] = (bf16)v.z; out[i + 3] = (bf16)v.w;
}

// W[K,256] fp32 -> Wt[256,K] bf16
__global__ void wconv_kernel(const float* __restrict__ W, bf16* __restrict__ Wt, int K) {
    int idx = blockIdx.x * 256 + threadIdx.x;
    if (idx >= K * HID) return;
    int n = idx / K, k = idx - n * K;
    Wt[idx] = (bf16)W[(size_t)k * HID + n];
}

// ---------- MFMA GEMM: C[16000,256] = A[16000,K] @ Bt[256,K]^T, fused epilogue ----------
// mode 0: +bias; mode 1: +bias,relu,bn; mode 2: +bias,relu,bn,leaky
__global__ __launch_bounds__(256) void gemm_mfma(
    const bf16* __restrict__ A, const bf16* __restrict__ Bt,
    const float* __restrict__ bias, bf16* __restrict__ C,
    int K, int mode, const float* __restrict__ g, const float* __restrict__ be)
{
    __shared__ __align__(16) bf16 As[128 * 32];
    __shared__ __align__(16) bf16 Bs[128 * 32];
    const int tid = threadIdx.x;
    const int bm = blockIdx.y * 128, bn = blockIdx.x * 128;
    const int w = tid >> 6, lane = tid & 63;
    const int wm = (w & 1) * 64, wn = (w >> 1) * 64;
    const int lrow = lane & 15, lk8 = (lane >> 4) * 8;

    floatx4 acc[4][4];
#pragma unroll
    for (int i = 0; i < 4; i++)
#pragma unroll
        for (int j = 0; j < 4; j++) acc[i][j] = (floatx4){0.f, 0.f, 0.f, 0.f};

    const bf16* gA = A + (size_t)(bm + (tid >> 2)) * K + (tid & 3) * 8;
    const bf16* gB = Bt + (size_t)(bn + (tid >> 2)) * K + (tid & 3) * 8;
    bf16* lA0 = As + (size_t)(w * 64) * 8;
    bf16* lA1 = As + (size_t)(w * 64 + 256) * 8;
    bf16* lB0 = Bs + (size_t)(w * 64) * 8;
    bf16* lB1 = Bs + (size_t)(w * 64 + 256) * 8;
    const size_t rowskip = (size_t)64 * K;

    for (int k0 = 0; k0 < K; k0 += 32) {
        gll16(gA + k0, lA0);
        gll16(gA + rowskip + k0, lA1);
        gll16(gB + k0, lB0);
        gll16(gB + rowskip + k0, lB1);
        __syncthreads();
        bf16x8 af[4], bfr[4];
#pragma unroll
        for (int i = 0; i < 4; i++) af[i] = *(const bf16x8*)&As[(wm + 16 * i + lrow) * 32 + lk8];
#pragma unroll
        for (int j = 0; j < 4; j++) bfr[j] = *(const bf16x8*)&Bs[(wn + 16 * j + lrow) * 32 + lk8];
#pragma unroll
        for (int i = 0; i < 4; i++)
#pragma unroll
            for (int j = 0; j < 4; j++)
                acc[i][j] = __builtin_amdgcn_mfma_f32_16x16x32_bf16(af[i], bfr[j], acc[i][j], 0, 0, 0);
        __syncthreads();
    }

    const float inv = rsqrtf(1.f + EPSC);
#pragma unroll
    for (int j = 0; j < 4; j++) {
        int col = bn + wn + 16 * j + lrow;
        float bcol = bias[col];
        float gc = (mode >= 1) ? g[col] * inv : 0.f;
        float bec = (mode >= 1) ? be[col] : 0.f;
#pragma unroll
        for (int i = 0; i < 4; i++) {
            int row0 = bm + wm + 16 * i + (lane >> 4) * 4;
#pragma unroll
            for (int r = 0; r < 4; r++) {
                float z = acc[i][j][r] + bcol;
                if (mode >= 1) { z = fmaxf(z, 0.f); z = z * gc + bec; }
                if (mode == 2) z = lrelu(z);
                C[(size_t)(row0 + r) * HID + col] = (bf16)z;
            }
        }
    }
}

// ---------- CSR build (by dst, over E' = E + N self-loop edges) ----------
__global__ void hist_kernel(const int* __restrict__ ei, int* __restrict__ cnt) {
    int e = blockIdx.x * 256 + threadIdx.x;
    if (e >= EPE) return;
    int d = (e < N_EDGES) ? ei[N_EDGES + e] : (e - N_EDGES);
    atomicAdd(&cnt[d], 1);
}

__global__ __launch_bounds__(1024) void scan_kernel(const int* __restrict__ cnt,
                                                    int* __restrict__ roff, int* __restrict__ cursor) {
    __shared__ int wsum[16];
    int t = threadIdx.x;
    int base = t * 16;
    int local[16]; int s = 0;
#pragma unroll
    for (int i = 0; i < 16; i++) {
        int idx = base + i;
        int v = (idx < N_NODES) ? cnt[idx] : 0;
        local[i] = s; s += v;
    }
    int lane = t & 63, wid = t >> 6;
    int incl = s;
    for (int o = 1; o < 64; o <<= 1) { int v = __shfl_up(incl, o); if (lane >= o) incl += v; }
    if (lane == 63) wsum[wid] = incl;
    __syncthreads();
    if (t == 0) { int a = 0; for (int k = 0; k < 16; k++) { int v = wsum[k]; wsum[k] = a; a += v; } }
    __syncthreads();
    int texcl = incl - s + wsum[wid];
#pragma unroll
    for (int i = 0; i < 16; i++) {
        int idx = base + i;
        if (idx < N_NODES) { int o = texcl + local[i]; roff[idx] = o; cursor[idx] = o; }
    }
    if (t == 1023) roff[N_NODES] = texcl + s;
}

__global__ void scatter_kernel(const int* __restrict__ ei, int* __restrict__ cursor,
                               int* __restrict__ eid, int* __restrict__ esrc) {
    int e = blockIdx.x * 256 + threadIdx.x;
    if (e >= EPE) return;
    int s, d;
    if (e < N_EDGES) { s = ei[e]; d = ei[N_EDGES + e]; } else { s = d = e - N_EDGES; }
    int pos = atomicAdd(&cursor[d], 1);
    eid[pos] = e; esrc[pos] = s;
}

// ---------- GAT edge logits ----------
__global__ void edge_logit(const bf16* __restrict__ xl, const bf16* __restrict__ xr,
                           const int* __restrict__ ei, const float* __restrict__ att,
                           float* __restrict__ elog) {
    int idx = blockIdx.x * 256 + threadIdx.x;
    if (idx >= EPE * HEADS) return;
    int e = idx >> 3, h = idx & 7;
    int s, d;
    if (e < N_EDGES) { s = ei[e]; d = ei[N_EDGES + e]; } else { s = d = e - N_EDGES; }
    const bf16* pl = xl + (size_t)s * HID + h * CPH;
    const bf16* pr = xr + (size_t)d * HID + h * CPH;
    const float* pa = att + h * CPH;
    float acc = 0.f;
#pragma unroll
    for (int c8 = 0; c8 < 4; c8++) {
        bf16x8 l = *(const bf16x8*)(pl + c8 * 8);
        bf16x8 r = *(const bf16x8*)(pr + c8 * 8);
#pragma unroll
        for (int j = 0; j < 8; j++)
            acc += lrelu((float)l[j] + (float)r[j]) * pa[c8 * 8 + j];
    }
    elog[idx] = acc;
}

// ---------- GAT gather: segment softmax + weighted aggregation (one block per dst) ----------
__global__ __launch_bounds__(256) void gat_gather(
    const bf16* __restrict__ xl, const float* __restrict__ elog,
    const int* __restrict__ roff, const int* __restrict__ eid, const int* __restrict__ esrc,
    const float* __restrict__ gbias, bf16* __restrict__ out)
{
    int d = blockIdx.x, t = threadIdx.x;
    int beg = roff[d], deg = roff[d + 1] - beg;
    __shared__ float sm[8], srinv[8];
    __shared__ float alpha_s[32 * 8];
    __shared__ int src_s[32];
    if (t < 64) {
        int h = t & 7, j0 = t >> 3;
        float mx = -INFINITY;
        for (int j = j0; j < deg; j += 8) mx = fmaxf(mx, elog[eid[beg + j] * 8 + h]);
        for (int o = 8; o < 64; o <<= 1) mx = fmaxf(mx, __shfl_xor(mx, o));
        float ss = 0.f;
        for (int j = j0; j < deg; j += 8) ss += __expf(elog[eid[beg + j] * 8 + h] - mx);
        for (int o = 8; o < 64; o <<= 1) ss += __shfl_xor(ss, o);
        if (t < 8) { sm[h] = mx; srinv[h] = 1.f / (ss + 1e-16f); }
    }
    __syncthreads();
    float acc = gbias[t];
    int h = t >> 5;
    for (int c0 = 0; c0 < deg; c0 += 32) {
        int cn = min(32, deg - c0);
        __syncthreads();
        if (t < cn * 8) {
            int j = t >> 3, hh = t & 7;
            alpha_s[t] = __expf(elog[eid[beg + c0 + j] * 8 + hh] - sm[hh]) * srinv[hh];
        }
        if (t < cn) src_s[t] = esrc[beg + c0 + t];
        __syncthreads();
        for (int j = 0; j < cn; j++)
            acc += alpha_s[j * 8 + h] * (float)xl[(size_t)src_s[j] * HID + t];
    }
    out[(size_t)d * HID + t] = (bf16)acc;
}

// ---------- GIN gather: u[d] = h[d] + sum over incoming ORIGINAL edges h[src] ----------
__global__ __launch_bounds__(256) void gin_gather(
    const bf16* __restrict__ h, const int* __restrict__ roff,
    const int* __restrict__ eid, const int* __restrict__ esrc, bf16* __restrict__ u)
{
    int d = blockIdx.x, t = threadIdx.x;
    int beg = roff[d], end = roff[d + 1];
    __shared__ int src_s[64];
    float acc = (float)h[(size_t)d * HID + t];
    for (int c0 = beg; c0 < end; c0 += 64) {
        int cn = min(64, end - c0);
        __syncthreads();
        if (t < cn) src_s[t] = (eid[c0 + t] < N_EDGES) ? esrc[c0 + t] : -1;
        __syncthreads();
        for (int j = 0; j < cn; j++) {
            int s = src_s[j];
            if (s >= 0) acc += (float)h[(size_t)s * HID + t];
        }
    }
    u[(size_t)d * HID + t] = (bf16)acc;
}

// ---------- global LN ----------
__global__ void stats_kernel(const bf16* __restrict__ x, float* __restrict__ stats, int n8) {
    float s = 0.f, sq = 0.f;
    for (int i = blockIdx.x * blockDim.x + threadIdx.x; i < n8; i += gridDim.x * blockDim.x) {
        bf16x8 v = *(const bf16x8*)(x + (size_t)i * 8);
#pragma unroll
        for (int j = 0; j < 8; j++) { float f = (float)v[j]; s += f; sq += f * f; }
    }
    for (int o = 32; o > 0; o >>= 1) { s += __shfl_down(s, o); sq += __shfl_down(sq, o); }
    __shared__ float ls[4], lq[4];
    int wid = threadIdx.x >> 6, lane = threadIdx.x & 63;
    if (lane == 0) { ls[wid] = s; lq[wid] = sq; }
    __syncthreads();
    if (threadIdx.x == 0) {
        float ts = 0.f, tq = 0.f;
        for (int w = 0; w < 4; ++w) { ts += ls[w]; tq += lq[w]; }
        atomicAdd(&stats[0], ts);
        atomicAdd(&stats[1], tq);
    }
}

__global__ void ln_res_kernel(const bf16* __restrict__ h, const bf16* __restrict__ r,
                              const float* __restrict__ stats, const float* __restrict__ g,
                              const float* __restrict__ b, bf16* __restrict__ out)
{
    int i = (blockIdx.x * 256 + threadIdx.x) * 4;
    const float inv_n = 1.f / (float)((size_t)N_NODES * HID);
    float mu = stats[0] * inv_n;
    float var = stats[1] * inv_n - mu * mu;
    float sd = sqrtf(fmaxf(var, 0.f));
    float rs = 1.f / (sd + EPSC);
    int ch = i & (HID - 1);
#pragma unroll
    for (int j = 0; j < 4; j++) {
        float v = ((float)h[i + j] - mu) * rs * g[ch + j] + b[ch + j] + (float)r[i + j];
        out[i + j] = (bf16)lrelu(v);
    }
}

// ---------- pooling ----------
__global__ void fill_kernel(float* p, float v, int n) {
    int i = blockIdx.x * 256 + threadIdx.x;
    if (i < n) p[i] = v;
}

__global__ void pool_gate_kernel(const bf16* __restrict__ t, const float* __restrict__ W2,
                                 const float* __restrict__ b2, float* __restrict__ gate)
{
    int nidx = blockIdx.x;
    int k = threadIdx.x;
    __shared__ float red[256];
    red[k] = tanhf((float)t[(size_t)nidx * HID + k]) * W2[k];
    __syncthreads();
    for (int st = 128; st > 0; st >>= 1) { if (k < st) red[k] += red[k + st]; __syncthreads(); }
    if (k == 0) gate[nidx] = red[0] + b2[0];
}

__global__ void node_max_kernel(const float* __restrict__ gate, const int* __restrict__ batch,
                                float* __restrict__ gmax) {
    int n = blockIdx.x * 256 + threadIdx.x;
    if (n < N_NODES) atomicMaxFloat(&gmax[batch[n]], gate[n]);
}
__global__ void node_expsum_kernel(float* __restrict__ gate, const int* __restrict__ batch,
                                   const float* __restrict__ gmax, float* __restrict__ gsum) {
    int n = blockIdx.x * 256 + threadIdx.x;
    if (n < N_NODES) {
        float e = expf(gate[n] - gmax[batch[n]]);
        gate[n] = e;
        atomicAdd(&gsum[batch[n]], e);
    }
}

__global__ __launch_bounds__(256) void emb_scatter(const float* __restrict__ gate,
    const float* __restrict__ gsum, const int* __restrict__ batch,
    const bf16* __restrict__ h, float* __restrict__ emb)
{
    int n0 = blockIdx.x * 64, t = threadIdx.x;
    int cur = -1; float acc = 0.f;
    for (int j = 0; j < 64; j++) {
        int n = n0 + j;
        if (n >= N_NODES) break;
        int b = batch[n];
        float a = gate[n] / (gsum[b] + 1e-16f);
        if (b != cur) { if (cur >= 0) atomicAdd(&emb[cur * HID + t], acc); cur = b; acc = 0.f; }
        acc += a * (float)h[(size_t)n * HID + t];
    }
    if (cur >= 0) atomicAdd(&emb[cur * HID + t], acc);
}

// ---------- label heads ----------
__global__ __launch_bounds__(256) void heads_kernel(
    const float* __restrict__ emb, const float* __restrict__ W1, const float* __restrict__ b1,
    const float* __restrict__ hg, const float* __restrict__ hbe, const float* __restrict__ W2,
    const float* __restrict__ b2, float* __restrict__ out)
{
    int o = blockIdx.x;
    int k = threadIdx.x;
    __shared__ float se[HID];
    __shared__ float red[256];
    const float w2 = W2[o * HID + k];
    const float bb1 = b1[o * HID + k];
    const float gk = hg[o * HID + k] * rsqrtf(1.f + EPSC);
    const float bek = hbe[o * HID + k];
    const float b2o = b2[o];
    const float* w1p = W1 + (size_t)o * HID * HID + k;
    for (int g = 0; g < NG; ++g) {
        __syncthreads();
        se[k] = emb[g * HID + k];
        __syncthreads();
        float z = bb1;
#pragma unroll 4
        for (int d4 = 0; d4 < HID / 4; ++d4) {
            float4 ev = *(const float4*)&se[d4 * 4];
            z = fmaf(ev.x, w1p[(size_t)(d4 * 4 + 0) * HID], z);
            z = fmaf(ev.y, w1p[(size_t)(d4 * 4 + 1) * HID], z);
            z = fmaf(ev.z, w1p[(size_t)(d4 * 4 + 2) * HID], z);
            z = fmaf(ev.w, w1p[(size_t)(d4 * 4 + 3) * HID], z);
        }
        float sil = z / (1.f + expf(-z));
        float val = (sil * gk + bek) * w2;
        red[k] = val;
        __syncthreads();
        for (int st = 128; st > 0; st >>= 1) { if (k < st) red[k] += red[k + st]; __syncthreads(); }
        if (k == 0) out[g * NO + o] = red[0] + b2o;
    }
}

extern "C" void kernel_launch(void* const* d_in, const int* in_sizes, int n_in,
                              void* d_out, int out_size, void* d_ws, size_t ws_size,
                              hipStream_t stream) {
    const float* x        = (const float*)d_in[0];
    const int*   ei       = (const int*)  d_in[1];
    const int*   batch    = (const int*)  d_in[2];
    const float* fp_W     = (const float*)d_in[3];
    const float* fp_b     = (const float*)d_in[4];
    const float* fp_g     = (const float*)d_in[5];
    const float* fp_be    = (const float*)d_in[6];
    const float* gat_Wl   = (const float*)d_in[7];
    const float* gat_bl   = (const float*)d_in[8];
    const float* gat_Wr   = (const float*)d_in[9];
    const float* gat_br   = (const float*)d_in[10];
    const float* gat_att  = (const float*)d_in[11];
    const float* gat_bias = (const float*)d_in[12];
    const float* gin_W    = (const float*)d_in[13];
    const float* gin_b    = (const float*)d_in[14];
    const float* gin_g    = (const float*)d_in[15];
    const float* gin_be   = (const float*)d_in[16];
    const float* ln_g     = (const float*)d_in[17];
    const float* ln_b     = (const float*)d_in[18];
    const float* res_W    = (const float*)d_in[19];
    const float* res_b    = (const float*)d_in[20];
    const float* pool_W1  = (const float*)d_in[21];
    const float* pool_b1  = (const float*)d_in[22];
    const float* pool_W2  = (const float*)d_in[23];
    const float* pool_b2  = (const float*)d_in[24];
    const float* head_W1  = (const float*)d_in[25];
    const float* head_b1  = (const float*)d_in[26];
    const float* head_g   = (const float*)d_in[27];
    const float* head_be  = (const float*)d_in[28];
    const float* head_W2  = (const float*)d_in[29];
    const float* head_b2  = (const float*)d_in[30];
    float* out = (float*)d_out;

    char* base = (char*)d_ws;
    // region0: x_bf16 (dies after first GEMM), then aliased by elog/CSR/pool scratch
    bf16*  xb     = (bf16*)base;                               // 20,480,000 elems = 40,960,000 B
    float* elog   = (float*)base;                              // 2,176,000 f = 8,704,000 B
    int*   eidl   = (int*)(base + 8704000);                    // 1,088,000 B
    int*   esrc   = (int*)(base + 9792000);                    // 1,088,000 B
    int*   cnt    = (int*)(base + 10880000);                   // 64,000 B
    int*   roff   = (int*)(base + 10944000);                   // 64,004 B (pad to 64,256)
    int*   cursor = (int*)(base + 11008256);                   // 64,000 B
    float* gate   = (float*)(base + 11072256);                 // 64,000 B
    float* gmax   = (float*)(base + 11136256);                 // 128 B
    float* gsum   = (float*)(base + 11136384);                 // 128 B
    float* emb    = (float*)(base + 11136512);                 // 32,768 B
    float* stat   = (float*)(base + 11169280);                 // 8 B
    // persistent bf16 activation buffers
    bf16* Hb0 = (bf16*)(base + 42991616);                      // 8,192,000 B each
    bf16* Hb1 = (bf16*)(base + 42991616 + 8192000);
    bf16* Hb2 = (bf16*)(base + 42991616 + 16384000);
    // transposed bf16 weights
    bf16* WT    = (bf16*)(base + 42991616 + 24576000);
    bf16* fpWt  = WT;                                          // 327,680 elems
    bf16* wlT[2] = { fpWt + 327680,           fpWt + 327680 + 65536 };
    bf16* wrT[2] = { fpWt + 327680 + 131072,  fpWt + 327680 + 196608 };
    bf16* gwT[2] = { fpWt + 327680 + 262144,  fpWt + 327680 + 327680 };
    bf16* rwT[2] = { fpWt + 327680 + 393216,  fpWt + 327680 + 458752 };
    bf16* pwT    = fpWt + 327680 + 524288;

    dim3 ggrid(2, 125);   // N=256 -> 2 tiles of 128; M=16000 -> 125 tiles of 128

    // ---- convert x and weights to bf16 (weights transposed to [N,K]) ----
    f2b_kernel<<<20000, 256, 0, stream>>>(x, xb, N_NODES * DIN);
    wconv_kernel<<<(DIN * HID + 255) / 256, 256, 0, stream>>>(fp_W, fpWt, DIN);
    for (int i = 0; i < 2; i++) {
        wconv_kernel<<<256, 256, 0, stream>>>(gat_Wl + (size_t)i * HID * HID, wlT[i], HID);
        wconv_kernel<<<256, 256, 0, stream>>>(gat_Wr + (size_t)i * HID * HID, wrT[i], HID);
        wconv_kernel<<<256, 256, 0, stream>>>(gin_W + (size_t)i * HID * HID, gwT[i], HID);
        wconv_kernel<<<256, 256, 0, stream>>>(res_W + (size_t)i * HID * HID, rwT[i], HID);
    }
    wconv_kernel<<<256, 256, 0, stream>>>(pool_W1, pwT, HID);

    // ---- feature projection (uses xb; after this region0 is reusable) ----
    gemm_mfma<<<ggrid, 256, 0, stream>>>(xb, fpWt, fp_b, Hb0, DIN, 1, fp_g, fp_be);

    // ---- CSR build (by dst over E' edges) ----
    hipMemsetAsync(cnt, 0, N_NODES * sizeof(int), stream);
    hist_kernel<<<(EPE + 255) / 256, 256, 0, stream>>>(ei, cnt);
    scan_kernel<<<1, 1024, 0, stream>>>(cnt, roff, cursor);
    scatter_kernel<<<(EPE + 255) / 256, 256, 0, stream>>>(ei, cursor, eidl, esrc);

    const int ehBlocks = (EPE * HEADS + 255) / 256;
    for (int i = 0; i < 2; i++) {
        // xl -> Hb1, xr -> Hb2
        gemm_mfma<<<ggrid, 256, 0, stream>>>(Hb0, wlT[i], gat_bl + i * HID, Hb1, HID, 0, nullptr, nullptr);
        gemm_mfma<<<ggrid, 256, 0, stream>>>(Hb0, wrT[i], gat_br + i * HID, Hb2, HID, 0, nullptr, nullptr);
        edge_logit<<<ehBlocks, 256, 0, stream>>>(Hb1, Hb2, ei, gat_att + i * HEADS * CPH, elog);
        // GAT output (bias + softmax-weighted sum) -> Hb2
        gat_gather<<<N_NODES, 256, 0, stream>>>(Hb1, elog, roff, eidl, esrc, gat_bias + i * HID, Hb2);
        // GIN aggregate: u = h + sum_neigh h -> Hb0
        gin_gather<<<N_NODES, 256, 0, stream>>>(Hb2, roff, eidl, esrc, Hb0);
        // h_gin = leaky(BN(relu(u @ gin_W + b))) -> Hb1
        gemm_mfma<<<ggrid, 256, 0, stream>>>(Hb0, gwT[i], gin_b + i * HID, Hb1, HID, 2,
                                             gin_g + i * HID, gin_be + i * HID);
        // global LN stats over Hb1
        hipMemsetAsync(stat, 0, 2 * sizeof(float), stream);
        stats_kernel<<<1024, 256, 0, stream>>>(Hb1, stat, (N_NODES * HID) / 8);
        // residual linear -> Hb2
        gemm_mfma<<<ggrid, 256, 0, stream>>>(Hb1, rwT[i], res_b + i * HID, Hb2, HID, 0, nullptr, nullptr);
        // h = leaky(LN(h_gin) + r) -> Hb0
        ln_res_kernel<<<(N_NODES * HID) / 1024, 256, 0, stream>>>(Hb1, Hb2, stat,
                                                                  ln_g + i * HID, ln_b + i * HID, Hb0);
    }

    // ---- global attention pooling ----
    gemm_mfma<<<ggrid, 256, 0, stream>>>(Hb0, pwT, pool_b1, Hb1, HID, 0, nullptr, nullptr);
    pool_gate_kernel<<<N_NODES, 256, 0, stream>>>(Hb1, pool_W2, pool_b2, gate);
    fill_kernel<<<1, 256, 0, stream>>>(gmax, -INFINITY, NG);
    hipMemsetAsync(gsum, 0, NG * sizeof(float), stream);
    node_max_kernel<<<(N_NODES + 255) / 256, 256, 0, stream>>>(gate, batch, gmax);
    node_expsum_kernel<<<(N_NODES + 255) / 256, 256, 0, stream>>>(gate, batch, gmax, gsum);
    hipMemsetAsync(emb, 0, NG * HID * sizeof(float), stream);
    emb_scatter<<<N_NODES / 64, 256, 0, stream>>>(gate, gsum, batch, Hb0, emb);

    // ---- label heads ----
    heads_kernel<<<NO, 256, 0, stream>>>(emb, head_W1, head_b1, head_g, head_be, head_W2, head_b2, out);
}

// Round 3
// 1027.802 us; speedup vs baseline: 2.2360x; 1.1722x over previous
//
#include <hip/hip_runtime.h>
#include <math.h>

#define N_NODES 16000
#define N_EDGES 256000
#define EPE (N_EDGES + N_NODES)
#define DIN 1280
#define HID 256
#define HEADS 8
#define CPH 32
#define NG 32
#define NO 64
#define EPSC 1e-5f

typedef __bf16 bf16;
typedef __attribute__((ext_vector_type(8))) __bf16 bf16x8;
typedef __attribute__((ext_vector_type(4))) float floatx4;

typedef __attribute__((address_space(3))) unsigned int lds_u32;
typedef const __attribute__((address_space(1))) unsigned int glob_u32;

__device__ __forceinline__ float lrelu(float v) { return v > 0.f ? v : 0.2f * v; }

__device__ __forceinline__ void atomicMaxFloat(float* a, float v) {
    if (v >= 0.f) atomicMax((int*)a, __float_as_int(v));
    else          atomicMin((unsigned int*)a, __float_as_uint(v));
}

__device__ __forceinline__ void gll16(const void* g, void* l) {
    __builtin_amdgcn_global_load_lds((glob_u32*)g, (lds_u32*)l, 16, 0, 0);
}

// ---------- weight transpose/convert: W[L][K][256] fp32 -> WT[L][256][K] bf16 ----------
__global__ void wconv_gen(const float* __restrict__ W, bf16* __restrict__ Wt, int K, int total) {
    int idx = blockIdx.x * 256 + threadIdx.x;
    if (idx >= total) return;
    int per = K * HID;
    int l = idx / per, rem = idx - l * per;
    int n = rem / K, k = rem - n * K;
    Wt[idx] = (bf16)W[(size_t)l * per + (size_t)k * HID + n];
}

// [Wl|Wr] -> WT[512][256] bf16 (rows 0-255 = Wl^T, 256-511 = Wr^T)
__global__ void wconv_pair(const float* __restrict__ Wl, const float* __restrict__ Wr,
                           bf16* __restrict__ Wt) {
    int idx = blockIdx.x * 256 + threadIdx.x;  // 512*256
    int n = idx >> 8, k = idx & 255;
    float v = (n < 256) ? Wl[(size_t)k * HID + n] : Wr[(size_t)k * HID + (n - 256)];
    Wt[idx] = (bf16)v;
}

// ---------- MFMA GEMM (bf16 A): C[16000,ncols] = A @ Bt^T ----------
// mode 0: +bias; mode 1: +bias,relu,bn; mode 2: +bias,relu,bn,leaky
__global__ __launch_bounds__(256) void gemm_mfma(
    const bf16* __restrict__ A, const bf16* __restrict__ Bt,
    const float* __restrict__ bias, const float* __restrict__ bias2,
    bf16* __restrict__ C, int K, int ldc, int mode,
    const float* __restrict__ g, const float* __restrict__ be)
{
    __shared__ __align__(16) bf16 As[128 * 32];
    __shared__ __align__(16) bf16 Bs[128 * 32];
    const int tid = threadIdx.x;
    const int bm = blockIdx.y * 128, bn = blockIdx.x * 128;
    const int w = tid >> 6, lane = tid & 63;
    const int wm = (w & 1) * 64, wn = (w >> 1) * 64;
    const int lrow = lane & 15, lk8 = (lane >> 4) * 8;

    floatx4 acc[4][4];
#pragma unroll
    for (int i = 0; i < 4; i++)
#pragma unroll
        for (int j = 0; j < 4; j++) acc[i][j] = (floatx4){0.f, 0.f, 0.f, 0.f};

    const bf16* gA = A + (size_t)(bm + (tid >> 2)) * K + (tid & 3) * 8;
    const bf16* gB = Bt + (size_t)(bn + (tid >> 2)) * K + (tid & 3) * 8;
    bf16* lA0 = As + (size_t)(w * 64) * 8;
    bf16* lA1 = As + (size_t)(w * 64 + 256) * 8;
    bf16* lB0 = Bs + (size_t)(w * 64) * 8;
    bf16* lB1 = Bs + (size_t)(w * 64 + 256) * 8;
    const size_t rowskip = (size_t)64 * K;

    for (int k0 = 0; k0 < K; k0 += 32) {
        gll16(gA + k0, lA0);
        gll16(gA + rowskip + k0, lA1);
        gll16(gB + k0, lB0);
        gll16(gB + rowskip + k0, lB1);
        __syncthreads();
        bf16x8 af[4], bfr[4];
#pragma unroll
        for (int i = 0; i < 4; i++) af[i] = *(const bf16x8*)&As[(wm + 16 * i + lrow) * 32 + lk8];
#pragma unroll
        for (int j = 0; j < 4; j++) bfr[j] = *(const bf16x8*)&Bs[(wn + 16 * j + lrow) * 32 + lk8];
#pragma unroll
        for (int i = 0; i < 4; i++)
#pragma unroll
            for (int j = 0; j < 4; j++)
                acc[i][j] = __builtin_amdgcn_mfma_f32_16x16x32_bf16(af[i], bfr[j], acc[i][j], 0, 0, 0);
        __syncthreads();
    }

    const float inv = rsqrtf(1.f + EPSC);
#pragma unroll
    for (int j = 0; j < 4; j++) {
        int col = bn + wn + 16 * j + lrow;
        float bcol = (col < HID) ? bias[col] : bias2[col - HID];
        float gc = (mode >= 1) ? g[col] * inv : 0.f;
        float bec = (mode >= 1) ? be[col] : 0.f;
#pragma unroll
        for (int i = 0; i < 4; i++) {
            int row0 = bm + wm + 16 * i + (lane >> 4) * 4;
#pragma unroll
            for (int r = 0; r < 4; r++) {
                float z = acc[i][j][r] + bcol;
                if (mode >= 1) { z = fmaxf(z, 0.f); z = z * gc + bec; }
                if (mode == 2) z = lrelu(z);
                C[(size_t)(row0 + r) * ldc + col] = (bf16)z;
            }
        }
    }
}

// ---------- MFMA GEMM (fp32 A staged through regs): for the K=1280 feature projection ----------
__global__ __launch_bounds__(256) void gemm_f32A(
    const float* __restrict__ A, const bf16* __restrict__ Bt,
    const float* __restrict__ bias, bf16* __restrict__ C, int K,
    const float* __restrict__ g, const float* __restrict__ be)
{
    __shared__ __align__(16) bf16 As[128 * 32];
    __shared__ __align__(16) bf16 Bs[128 * 32];
    const int tid = threadIdx.x;
    const int bm = blockIdx.y * 128, bn = blockIdx.x * 128;
    const int w = tid >> 6, lane = tid & 63;
    const int wm = (w & 1) * 64, wn = (w >> 1) * 64;
    const int lrow = lane & 15, lk8 = (lane >> 4) * 8;

    floatx4 acc[4][4];
#pragma unroll
    for (int i = 0; i < 4; i++)
#pragma unroll
        for (int j = 0; j < 4; j++) acc[i][j] = (floatx4){0.f, 0.f, 0.f, 0.f};

    // A: thread covers row r2 = tid>>1 (0..127), 16-float half c2 = tid&1
    const int r2 = tid >> 1, c2 = tid & 1;
    const float* gA = A + (size_t)(bm + r2) * K + c2 * 16;
    bf16* sA = As + r2 * 32 + c2 * 16;
    // B: async direct-to-LDS
    const bf16* gB = Bt + (size_t)(bn + (tid >> 2)) * K + (tid & 3) * 8;
    bf16* lB0 = Bs + (size_t)(w * 64) * 8;
    bf16* lB1 = Bs + (size_t)(w * 64 + 256) * 8;
    const size_t rowskipB = (size_t)64 * K;

    for (int k0 = 0; k0 < K; k0 += 32) {
        gll16(gB + k0, lB0);
        gll16(gB + rowskipB + k0, lB1);
        float4 a0 = *(const float4*)(gA + k0 + 0);
        float4 a1 = *(const float4*)(gA + k0 + 4);
        float4 a2 = *(const float4*)(gA + k0 + 8);
        float4 a3 = *(const float4*)(gA + k0 + 12);
        bf16x8 h0, h1;
        h0[0] = (bf16)a0.x; h0[1] = (bf16)a0.y; h0[2] = (bf16)a0.z; h0[3] = (bf16)a0.w;
        h0[4] = (bf16)a1.x; h0[5] = (bf16)a1.y; h0[6] = (bf16)a1.z; h0[7] = (bf16)a1.w;
        h1[0] = (bf16)a2.x; h1[1] = (bf16)a2.y; h1[2] = (bf16)a2.z; h1[3] = (bf16)a2.w;
        h1[4] = (bf16)a3.x; h1[5] = (bf16)a3.y; h1[6] = (bf16)a3.z; h1[7] = (bf16)a3.w;
        *(bf16x8*)(sA + 0) = h0;
        *(bf16x8*)(sA + 8) = h1;
        __syncthreads();
        bf16x8 af[4], bfr[4];
#pragma unroll
        for (int i = 0; i < 4; i++) af[i] = *(const bf16x8*)&As[(wm + 16 * i + lrow) * 32 + lk8];
#pragma unroll
        for (int j = 0; j < 4; j++) bfr[j] = *(const bf16x8*)&Bs[(wn + 16 * j + lrow) * 32 + lk8];
#pragma unroll
        for (int i = 0; i < 4; i++)
#pragma unroll
            for (int j = 0; j < 4; j++)
                acc[i][j] = __builtin_amdgcn_mfma_f32_16x16x32_bf16(af[i], bfr[j], acc[i][j], 0, 0, 0);
        __syncthreads();
    }

    const float inv = rsqrtf(1.f + EPSC);
#pragma unroll
    for (int j = 0; j < 4; j++) {
        int col = bn + wn + 16 * j + lrow;
        float bcol = bias[col];
        float gc = g[col] * inv;
        float bec = be[col];
#pragma unroll
        for (int i = 0; i < 4; i++) {
            int row0 = bm + wm + 16 * i + (lane >> 4) * 4;
#pragma unroll
            for (int r = 0; r < 4; r++) {
                float z = fmaxf(acc[i][j][r] + bcol, 0.f) * gc + bec;
                C[(size_t)(row0 + r) * HID + col] = (bf16)z;
            }
        }
    }
}

// ---------- CSR build (by dst, over E' = E + N self-loop edges) ----------
__global__ void hist_kernel(const int* __restrict__ ei, int* __restrict__ cnt) {
    int e = blockIdx.x * 256 + threadIdx.x;
    if (e >= EPE) return;
    int d = (e < N_EDGES) ? ei[N_EDGES + e] : (e - N_EDGES);
    atomicAdd(&cnt[d], 1);
}

__global__ __launch_bounds__(1024) void scan_kernel(const int* __restrict__ cnt,
                                                    int* __restrict__ roff, int* __restrict__ cursor) {
    __shared__ int wsum[16];
    int t = threadIdx.x;
    int base = t * 16;
    int local[16]; int s = 0;
#pragma unroll
    for (int i = 0; i < 16; i++) {
        int idx = base + i;
        int v = (idx < N_NODES) ? cnt[idx] : 0;
        local[i] = s; s += v;
    }
    int lane = t & 63, wid = t >> 6;
    int incl = s;
    for (int o = 1; o < 64; o <<= 1) { int v = __shfl_up(incl, o); if (lane >= o) incl += v; }
    if (lane == 63) wsum[wid] = incl;
    __syncthreads();
    if (t == 0) { int a = 0; for (int k = 0; k < 16; k++) { int v = wsum[k]; wsum[k] = a; a += v; } }
    __syncthreads();
    int texcl = incl - s + wsum[wid];
#pragma unroll
    for (int i = 0; i < 16; i++) {
        int idx = base + i;
        if (idx < N_NODES) { int o = texcl + local[i]; roff[idx] = o; cursor[idx] = o; }
    }
    if (t == 1023) roff[N_NODES] = texcl + s;
}

// esrc: src | (selfloop<<31), edst: dst  (CSR position order)
__global__ void scatter_kernel(const int* __restrict__ ei, int* __restrict__ cursor,
                               int* __restrict__ esrc, int* __restrict__ edst) {
    int e = blockIdx.x * 256 + threadIdx.x;
    if (e >= EPE) return;
    int s, d, f;
    if (e < N_EDGES) { s = ei[e]; d = ei[N_EDGES + e]; f = 0; }
    else { s = d = e - N_EDGES; f = (int)0x80000000; }
    int pos = atomicAdd(&cursor[d], 1);
    esrc[pos] = s | f; edst[pos] = d;
}

// ---------- GAT edge logits (CSR order; XLR = [xl|xr] stride 512) ----------
__global__ void edge_logit(const bf16* __restrict__ XLR, const int* __restrict__ esrc,
                           const int* __restrict__ edst, const float* __restrict__ att,
                           float* __restrict__ elog) {
    int idx = blockIdx.x * 256 + threadIdx.x;
    if (idx >= EPE * HEADS) return;
    int p = idx >> 3, h = idx & 7;
    int s = esrc[p] & 0x7fffffff, d = edst[p];
    const bf16* pl = XLR + (size_t)s * 512 + h * CPH;
    const bf16* pr = XLR + (size_t)d * 512 + 256 + h * CPH;
    const float* pa = att + h * CPH;
    float acc = 0.f;
#pragma unroll
    for (int c8 = 0; c8 < 4; c8++) {
        bf16x8 l = *(const bf16x8*)(pl + c8 * 8);
        bf16x8 r = *(const bf16x8*)(pr + c8 * 8);
#pragma unroll
        for (int j = 0; j < 8; j++)
            acc += lrelu((float)l[j] + (float)r[j]) * pa[c8 * 8 + j];
    }
    elog[idx] = acc;
}

// ---------- GAT gather: segment softmax + weighted aggregation (one block per dst) ----------
__global__ __launch_bounds__(256) void gat_gather(
    const bf16* __restrict__ XLR, const float* __restrict__ elog,
    const int* __restrict__ roff, const int* __restrict__ esrc,
    const float* __restrict__ gbias, bf16* __restrict__ out)
{
    int d = blockIdx.x, t = threadIdx.x;
    int beg = roff[d], deg = roff[d + 1] - beg;
    __shared__ float sm[8], srinv[8];
    __shared__ float alpha_s[32 * 8];
    __shared__ int src_s[32];
    if (t < 64) {
        int h = t & 7, j0 = t >> 3;
        float mx = -INFINITY;
        for (int j = j0; j < deg; j += 8) mx = fmaxf(mx, elog[(beg + j) * 8 + h]);
        for (int o = 8; o < 64; o <<= 1) mx = fmaxf(mx, __shfl_xor(mx, o));
        float ss = 0.f;
        for (int j = j0; j < deg; j += 8) ss += __expf(elog[(beg + j) * 8 + h] - mx);
        for (int o = 8; o < 64; o <<= 1) ss += __shfl_xor(ss, o);
        if (t < 8) { sm[h] = mx; srinv[h] = 1.f / (ss + 1e-16f); }
    }
    __syncthreads();
    float acc = gbias[t];
    int h = t >> 5;
    for (int c0 = 0; c0 < deg; c0 += 32) {
        int cn = min(32, deg - c0);
        __syncthreads();
        if (t < cn * 8) {
            int j = t >> 3, hh = t & 7;
            alpha_s[t] = __expf(elog[(beg + c0 + j) * 8 + hh] - sm[hh]) * srinv[hh];
        }
        if (t < cn) src_s[t] = esrc[beg + c0 + t] & 0x7fffffff;
        __syncthreads();
        for (int j = 0; j < cn; j++)
            acc += alpha_s[j * 8 + h] * (float)XLR[(size_t)src_s[j] * 512 + t];
    }
    out[(size_t)d * HID + t] = (bf16)acc;
}

// ---------- GIN gather: u[d] = h[d] + sum over incoming ORIGINAL edges h[src] ----------
__global__ __launch_bounds__(256) void gin_gather(
    const bf16* __restrict__ h, const int* __restrict__ roff,
    const int* __restrict__ esrc, bf16* __restrict__ u)
{
    int d = blockIdx.x, t = threadIdx.x;
    int beg = roff[d], end = roff[d + 1];
    __shared__ int src_s[64];
    float acc = (float)h[(size_t)d * HID + t];
    for (int c0 = beg; c0 < end; c0 += 64) {
        int cn = min(64, end - c0);
        __syncthreads();
        if (t < cn) src_s[t] = esrc[c0 + t];
        __syncthreads();
        for (int j = 0; j < cn; j++) {
            int s = src_s[j];
            if (s >= 0) acc += (float)h[(size_t)s * HID + t];
        }
    }
    u[(size_t)d * HID + t] = (bf16)acc;
}

// ---------- global LN ----------
__global__ void stats_kernel(const bf16* __restrict__ x, float* __restrict__ stats, int n8) {
    float s = 0.f, sq = 0.f;
    for (int i = blockIdx.x * blockDim.x + threadIdx.x; i < n8; i += gridDim.x * blockDim.x) {
        bf16x8 v = *(const bf16x8*)(x + (size_t)i * 8);
#pragma unroll
        for (int j = 0; j < 8; j++) { float f = (float)v[j]; s += f; sq += f * f; }
    }
    for (int o = 32; o > 0; o >>= 1) { s += __shfl_down(s, o); sq += __shfl_down(sq, o); }
    __shared__ float ls[4], lq[4];
    int wid = threadIdx.x >> 6, lane = threadIdx.x & 63;
    if (lane == 0) { ls[wid] = s; lq[wid] = sq; }
    __syncthreads();
    if (threadIdx.x == 0) {
        float ts = 0.f, tq = 0.f;
        for (int w = 0; w < 4; ++w) { ts += ls[w]; tq += lq[w]; }
        atomicAdd(&stats[0], ts);
        atomicAdd(&stats[1], tq);
    }
}

__global__ void ln_res_kernel(const bf16* __restrict__ h, const bf16* __restrict__ r,
                              const float* __restrict__ stats, const float* __restrict__ g,
                              const float* __restrict__ b, bf16* __restrict__ out)
{
    int i = (blockIdx.x * 256 + threadIdx.x) * 4;
    const float inv_n = 1.f / (float)((size_t)N_NODES * HID);
    float mu = stats[0] * inv_n;
    float var = stats[1] * inv_n - mu * mu;
    float sd = sqrtf(fmaxf(var, 0.f));
    float rs = 1.f / (sd + EPSC);
    int ch = i & (HID - 1);
#pragma unroll
    for (int j = 0; j < 4; j++) {
        float v = ((float)h[i + j] - mu) * rs * g[ch + j] + b[ch + j] + (float)r[i + j];
        out[i + j] = (bf16)lrelu(v);
    }
}

// ---------- pooling ----------
__global__ void pool_init_kernel(float* __restrict__ emb, float* __restrict__ gmax,
                                 float* __restrict__ gsum) {
    int i = blockIdx.x * 256 + threadIdx.x;
    if (i < NG * HID) emb[i] = 0.f;
    else if (i < NG * HID + NG) gmax[i - NG * HID] = -INFINITY;
    else if (i < NG * HID + 2 * NG) gsum[i - NG * HID - NG] = 0.f;
}

__global__ void pool_gate_kernel(const bf16* __restrict__ t, const float* __restrict__ W2,
                                 const float* __restrict__ b2, float* __restrict__ gate)
{
    int nidx = blockIdx.x;
    int k = threadIdx.x;
    __shared__ float red[256];
    red[k] = tanhf((float)t[(size_t)nidx * HID + k]) * W2[k];
    __syncthreads();
    for (int st = 128; st > 0; st >>= 1) { if (k < st) red[k] += red[k + st]; __syncthreads(); }
    if (k == 0) gate[nidx] = red[0] + b2[0];
}

__global__ void node_max_kernel(const float* __restrict__ gate, const int* __restrict__ batch,
                                float* __restrict__ gmax) {
    int n = blockIdx.x * 256 + threadIdx.x;
    if (n < N_NODES) atomicMaxFloat(&gmax[batch[n]], gate[n]);
}
__global__ void node_expsum_kernel(float* __restrict__ gate, const int* __restrict__ batch,
                                   const float* __restrict__ gmax, float* __restrict__ gsum) {
    int n = blockIdx.x * 256 + threadIdx.x;
    if (n < N_NODES) {
        float e = expf(gate[n] - gmax[batch[n]]);
        gate[n] = e;
        atomicAdd(&gsum[batch[n]], e);
    }
}

__global__ __launch_bounds__(256) void emb_scatter(const float* __restrict__ gate,
    const float* __restrict__ gsum, const int* __restrict__ batch,
    const bf16* __restrict__ h, float* __restrict__ emb)
{
    int n0 = blockIdx.x * 64, t = threadIdx.x;
    int cur = -1; float acc = 0.f;
    for (int j = 0; j < 64; j++) {
        int n = n0 + j;
        if (n >= N_NODES) break;
        int b = batch[n];
        float a = gate[n] / (gsum[b] + 1e-16f);
        if (b != cur) { if (cur >= 0) atomicAdd(&emb[cur * HID + t], acc); cur = b; acc = 0.f; }
        acc += a * (float)h[(size_t)n * HID + t];
    }
    if (cur >= 0) atomicAdd(&emb[cur * HID + t], acc);
}

// ---------- label heads: grid (64 heads, 8 graph-tiles), 4 graphs/block ----------
__global__ __launch_bounds__(256) void heads_kernel(
    const float* __restrict__ emb, const float* __restrict__ W1, const float* __restrict__ b1,
    const float* __restrict__ hg, const float* __restrict__ hbe, const float* __restrict__ W2,
    const float* __restrict__ b2, float* __restrict__ out)
{
    int o = blockIdx.x;
    int g0 = blockIdx.y * 4;
    int k = threadIdx.x;
    __shared__ float se[4][HID];
    __shared__ float red[256];
#pragma unroll
    for (int j = 0; j < 4; j++) se[j][k] = emb[(g0 + j) * HID + k];
    __syncthreads();
    const float* w1p = W1 + (size_t)o * HID * HID + k;
    float zb = b1[o * HID + k];
    float z0 = zb, z1 = zb, z2 = zb, z3 = zb;
#pragma unroll 8
    for (int d = 0; d < HID; d++) {
        float w = w1p[(size_t)d * HID];
        z0 = fmaf(se[0][d], w, z0);
        z1 = fmaf(se[1][d], w, z1);
        z2 = fmaf(se[2][d], w, z2);
        z3 = fmaf(se[3][d], w, z3);
    }
    const float gk = hg[o * HID + k] * rsqrtf(1.f + EPSC);
    const float bek = hbe[o * HID + k];
    const float w2 = W2[o * HID + k];
    const float b2o = b2[o];
    float zz[4] = {z0, z1, z2, z3};
#pragma unroll
    for (int j = 0; j < 4; j++) {
        float z = zz[j];
        float sil = z / (1.f + expf(-z));
        red[k] = (sil * gk + bek) * w2;
        __syncthreads();
        for (int st = 128; st > 0; st >>= 1) { if (k < st) red[k] += red[k + st]; __syncthreads(); }
        if (k == 0) out[(g0 + j) * NO + o] = red[0] + b2o;
        __syncthreads();
    }
}

extern "C" void kernel_launch(void* const* d_in, const int* in_sizes, int n_in,
                              void* d_out, int out_size, void* d_ws, size_t ws_size,
                              hipStream_t stream) {
    const float* x        = (const float*)d_in[0];
    const int*   ei       = (const int*)  d_in[1];
    const int*   batch    = (const int*)  d_in[2];
    const float* fp_W     = (const float*)d_in[3];
    const float* fp_b     = (const float*)d_in[4];
    const float* fp_g     = (const float*)d_in[5];
    const float* fp_be    = (const float*)d_in[6];
    const float* gat_Wl   = (const float*)d_in[7];
    const float* gat_bl   = (const float*)d_in[8];
    const float* gat_Wr   = (const float*)d_in[9];
    const float* gat_br   = (const float*)d_in[10];
    const float* gat_att  = (const float*)d_in[11];
    const float* gat_bias = (const float*)d_in[12];
    const float* gin_W    = (const float*)d_in[13];
    const float* gin_b    = (const float*)d_in[14];
    const float* gin_g    = (const float*)d_in[15];
    const float* gin_be   = (const float*)d_in[16];
    const float* ln_g     = (const float*)d_in[17];
    const float* ln_b     = (const float*)d_in[18];
    const float* res_W    = (const float*)d_in[19];
    const float* res_b    = (const float*)d_in[20];
    const float* pool_W1  = (const float*)d_in[21];
    const float* pool_b1  = (const float*)d_in[22];
    const float* pool_W2  = (const float*)d_in[23];
    const float* pool_b2  = (const float*)d_in[24];
    const float* head_W1  = (const float*)d_in[25];
    const float* head_b1  = (const float*)d_in[26];
    const float* head_g   = (const float*)d_in[27];
    const float* head_be  = (const float*)d_in[28];
    const float* head_W2  = (const float*)d_in[29];
    const float* head_b2  = (const float*)d_in[30];
    float* out = (float*)d_out;

    char* base = (char*)d_ws;
    size_t off = 0;
    auto alloc = [&](size_t bytes) -> char* {
        char* p = base + off; off += (bytes + 255) & ~(size_t)255; return p;
    };
    float* elog   = (float*)alloc((size_t)EPE * HEADS * 4);
    int*   esrc   = (int*)  alloc((size_t)EPE * 4);
    int*   edst   = (int*)  alloc((size_t)EPE * 4);
    int*   cnt    = (int*)  alloc((size_t)N_NODES * 4);
    int*   roff   = (int*)  alloc((size_t)(N_NODES + 1) * 4);
    int*   cursor = (int*)  alloc((size_t)N_NODES * 4);
    float* gate   = (float*)alloc((size_t)N_NODES * 4);
    float* gmax   = (float*)alloc(NG * 4);
    float* gsum   = (float*)alloc(NG * 4);
    float* emb    = (float*)alloc(NG * HID * 4);
    float* stat   = (float*)alloc(8);
    bf16*  Hb0    = (bf16*) alloc((size_t)N_NODES * HID * 2);
    bf16*  Hb1    = (bf16*) alloc((size_t)N_NODES * HID * 2);
    bf16*  XLR    = (bf16*) alloc((size_t)N_NODES * 512 * 2);   // [xl|xr], also reused as gin-u
    bf16*  fpWt   = (bf16*) alloc((size_t)DIN * HID * 2);
    bf16*  wlrT0  = (bf16*) alloc((size_t)512 * HID * 2);
    bf16*  wlrT1  = (bf16*) alloc((size_t)512 * HID * 2);
    bf16*  gwT    = (bf16*) alloc((size_t)2 * HID * HID * 2);
    bf16*  rwT    = (bf16*) alloc((size_t)2 * HID * HID * 2);
    bf16*  pwT    = (bf16*) alloc((size_t)HID * HID * 2);
    bf16*  Ub     = XLR;   // gin aggregation buffer [16000,256], alias of XLR
    bf16*  wlrT[2] = { wlrT0, wlrT1 };

    // ---- weight conversions (transposed bf16) ----
    wconv_gen<<<(DIN * HID + 255) / 256, 256, 0, stream>>>(fp_W, fpWt, DIN, DIN * HID);
    wconv_pair<<<512, 256, 0, stream>>>(gat_Wl, gat_Wr, wlrT0);
    wconv_pair<<<512, 256, 0, stream>>>(gat_Wl + HID * HID, gat_Wr + HID * HID, wlrT1);
    wconv_gen<<<512, 256, 0, stream>>>(gin_W, gwT, HID, 2 * HID * HID);
    wconv_gen<<<512, 256, 0, stream>>>(res_W, rwT, HID, 2 * HID * HID);
    wconv_gen<<<256, 256, 0, stream>>>(pool_W1, pwT, HID, HID * HID);

    // ---- CSR build ----
    hipMemsetAsync(cnt, 0, N_NODES * sizeof(int), stream);
    hist_kernel<<<(EPE + 255) / 256, 256, 0, stream>>>(ei, cnt);
    scan_kernel<<<1, 1024, 0, stream>>>(cnt, roff, cursor);
    scatter_kernel<<<(EPE + 255) / 256, 256, 0, stream>>>(ei, cursor, esrc, edst);

    // ---- feature projection: h = BN(relu(x @ fp_W + b)) -> Hb0 ----
    dim3 grid256(2, 125), grid512(4, 125);
    gemm_f32A<<<grid256, 256, 0, stream>>>(x, fpWt, fp_b, Hb0, DIN, fp_g, fp_be);

    const int ehBlocks = (EPE * HEADS + 255) / 256;
    for (int i = 0; i < 2; i++) {
        // xl|xr -> XLR (N=512)
        gemm_mfma<<<grid512, 256, 0, stream>>>(Hb0, wlrT[i], gat_bl + i * HID, gat_br + i * HID,
                                               XLR, HID, 512, 0, nullptr, nullptr);
        edge_logit<<<ehBlocks, 256, 0, stream>>>(XLR, esrc, edst, gat_att + i * HEADS * CPH, elog);
        // GAT out -> Hb1
        gat_gather<<<N_NODES, 256, 0, stream>>>(XLR, elog, roff, esrc, gat_bias + i * HID, Hb1);
        // GIN aggregate -> Ub (aliases XLR; XLR dead now)
        gin_gather<<<N_NODES, 256, 0, stream>>>(Hb1, roff, esrc, Ub);
        // h_gin = leaky(BN(relu(u @ gin_W + b))) -> Hb0
        gemm_mfma<<<grid256, 256, 0, stream>>>(Ub, gwT + (size_t)i * HID * HID, gin_b + i * HID,
                                               nullptr, Hb0, HID, HID, 2,
                                               gin_g + i * HID, gin_be + i * HID);
        hipMemsetAsync(stat, 0, 2 * sizeof(float), stream);
        stats_kernel<<<1024, 256, 0, stream>>>(Hb0, stat, (N_NODES * HID) / 8);
        // residual linear -> Hb1
        gemm_mfma<<<grid256, 256, 0, stream>>>(Hb0, rwT + (size_t)i * HID * HID, res_b + i * HID,
                                               nullptr, Hb1, HID, HID, 0, nullptr, nullptr);
        // h = leaky(LN(h_gin) + r) -> Hb0 (in-place safe, elementwise)
        ln_res_kernel<<<(N_NODES * HID) / 1024, 256, 0, stream>>>(Hb0, Hb1, stat,
                                                                  ln_g + i * HID, ln_b + i * HID, Hb0);
    }

    // ---- global attention pooling ----
    pool_init_kernel<<<(NG * HID + 2 * NG + 255) / 256, 256, 0, stream>>>(emb, gmax, gsum);
    gemm_mfma<<<grid256, 256, 0, stream>>>(Hb0, pwT, pool_b1, nullptr, Hb1, HID, HID, 0, nullptr, nullptr);
    pool_gate_kernel<<<N_NODES, 256, 0, stream>>>(Hb1, pool_W2, pool_b2, gate);
    node_max_kernel<<<(N_NODES + 255) / 256, 256, 0, stream>>>(gate, batch, gmax);
    node_expsum_kernel<<<(N_NODES + 255) / 256, 256, 0, stream>>>(gate, batch, gmax, gsum);
    emb_scatter<<<N_NODES / 64, 256, 0, stream>>>(gate, gsum, batch, Hb0, emb);

    // ---- label heads ----
    dim3 hgrid(NO, 8);
    heads_kernel<<<hgrid, 256, 0, stream>>>(emb, head_W1, head_b1, head_g, head_be,
                                            head_W2, head_b2, out);
}

// Round 4
// 881.502 us; speedup vs baseline: 2.6071x; 1.1660x over previous
//
#include <hip/hip_runtime.h>
#include <math.h>

#define N_NODES 16000
#define N_EDGES 256000
#define EPE (N_EDGES + N_NODES)
#define DIN 1280
#define HID 256
#define HEADS 8
#define CPH 32
#define NG 32
#define NO 64
#define EPSC 1e-5f

typedef __bf16 bf16;
typedef __attribute__((ext_vector_type(8))) __bf16 bf16x8;
typedef __attribute__((ext_vector_type(4))) float floatx4;

typedef __attribute__((address_space(3))) unsigned int lds_u32;
typedef const __attribute__((address_space(1))) unsigned int glob_u32;

__device__ __forceinline__ float lrelu(float v) { return v > 0.f ? v : 0.2f * v; }

__device__ __forceinline__ void gll16(const void* g, void* l) {
    __builtin_amdgcn_global_load_lds((glob_u32*)g, (lds_u32*)l, 16, 0, 0);
}

// ---------- weight transpose/convert: W[L][K][256] fp32 -> WT[L][256][K] bf16 ----------
__global__ void wconv_gen(const float* __restrict__ W, bf16* __restrict__ Wt, int K, int total) {
    int idx = blockIdx.x * 256 + threadIdx.x;
    if (idx >= total) return;
    int per = K * HID;
    int l = idx / per, rem = idx - l * per;
    int n = rem / K, k = rem - n * K;
    Wt[idx] = (bf16)W[(size_t)l * per + (size_t)k * HID + n];
}

// [Wl|Wr] -> WT[512][256] bf16 (rows 0-255 = Wl^T, 256-511 = Wr^T)
__global__ void wconv_pair(const float* __restrict__ Wl, const float* __restrict__ Wr,
                           bf16* __restrict__ Wt) {
    int idx = blockIdx.x * 256 + threadIdx.x;  // 512*256
    int n = idx >> 8, k = idx & 255;
    float v = (n < 256) ? Wl[(size_t)k * HID + n] : Wr[(size_t)k * HID + (n - 256)];
    Wt[idx] = (bf16)v;
}

// ---------- MFMA GEMM (bf16 A): C[16000,ncols] = A @ Bt^T ----------
// mode 0: +bias; mode 1: +bias,relu,bn; mode 2: +bias,relu,bn,leaky
__global__ __launch_bounds__(256) void gemm_mfma(
    const bf16* __restrict__ A, const bf16* __restrict__ Bt,
    const float* __restrict__ bias, const float* __restrict__ bias2,
    bf16* __restrict__ C, int K, int ldc, int mode,
    const float* __restrict__ g, const float* __restrict__ be)
{
    __shared__ __align__(16) bf16 As[128 * 32];
    __shared__ __align__(16) bf16 Bs[128 * 32];
    const int tid = threadIdx.x;
    const int bm = blockIdx.y * 128, bn = blockIdx.x * 128;
    const int w = tid >> 6, lane = tid & 63;
    const int wm = (w & 1) * 64, wn = (w >> 1) * 64;
    const int lrow = lane & 15, lk8 = (lane >> 4) * 8;

    floatx4 acc[4][4];
#pragma unroll
    for (int i = 0; i < 4; i++)
#pragma unroll
        for (int j = 0; j < 4; j++) acc[i][j] = (floatx4){0.f, 0.f, 0.f, 0.f};

    const bf16* gA = A + (size_t)(bm + (tid >> 2)) * K + (tid & 3) * 8;
    const bf16* gB = Bt + (size_t)(bn + (tid >> 2)) * K + (tid & 3) * 8;
    bf16* lA0 = As + (size_t)(w * 64) * 8;
    bf16* lA1 = As + (size_t)(w * 64 + 256) * 8;
    bf16* lB0 = Bs + (size_t)(w * 64) * 8;
    bf16* lB1 = Bs + (size_t)(w * 64 + 256) * 8;
    const size_t rowskip = (size_t)64 * K;

    for (int k0 = 0; k0 < K; k0 += 32) {
        gll16(gA + k0, lA0);
        gll16(gA + rowskip + k0, lA1);
        gll16(gB + k0, lB0);
        gll16(gB + rowskip + k0, lB1);
        __syncthreads();
        bf16x8 af[4], bfr[4];
#pragma unroll
        for (int i = 0; i < 4; i++) af[i] = *(const bf16x8*)&As[(wm + 16 * i + lrow) * 32 + lk8];
#pragma unroll
        for (int j = 0; j < 4; j++) bfr[j] = *(const bf16x8*)&Bs[(wn + 16 * j + lrow) * 32 + lk8];
#pragma unroll
        for (int i = 0; i < 4; i++)
#pragma unroll
            for (int j = 0; j < 4; j++)
                acc[i][j] = __builtin_amdgcn_mfma_f32_16x16x32_bf16(af[i], bfr[j], acc[i][j], 0, 0, 0);
        __syncthreads();
    }

    const float inv = rsqrtf(1.f + EPSC);
#pragma unroll
    for (int j = 0; j < 4; j++) {
        int col = bn + wn + 16 * j + lrow;
        float bcol = (col < HID) ? bias[col] : bias2[col - HID];
        float gc = (mode >= 1) ? g[col] * inv : 0.f;
        float bec = (mode >= 1) ? be[col] : 0.f;
#pragma unroll
        for (int i = 0; i < 4; i++) {
            int row0 = bm + wm + 16 * i + (lane >> 4) * 4;
#pragma unroll
            for (int r = 0; r < 4; r++) {
                float z = acc[i][j][r] + bcol;
                if (mode >= 1) { z = fmaxf(z, 0.f); z = z * gc + bec; }
                if (mode == 2) z = lrelu(z);
                C[(size_t)(row0 + r) * ldc + col] = (bf16)z;
            }
        }
    }
}

// ---------- MFMA GEMM (fp32 A staged through regs): for the K=1280 feature projection ----------
__global__ __launch_bounds__(256) void gemm_f32A(
    const float* __restrict__ A, const bf16* __restrict__ Bt,
    const float* __restrict__ bias, bf16* __restrict__ C, int K,
    const float* __restrict__ g, const float* __restrict__ be)
{
    __shared__ __align__(16) bf16 As[128 * 32];
    __shared__ __align__(16) bf16 Bs[128 * 32];
    const int tid = threadIdx.x;
    const int bm = blockIdx.y * 128, bn = blockIdx.x * 128;
    const int w = tid >> 6, lane = tid & 63;
    const int wm = (w & 1) * 64, wn = (w >> 1) * 64;
    const int lrow = lane & 15, lk8 = (lane >> 4) * 8;

    floatx4 acc[4][4];
#pragma unroll
    for (int i = 0; i < 4; i++)
#pragma unroll
        for (int j = 0; j < 4; j++) acc[i][j] = (floatx4){0.f, 0.f, 0.f, 0.f};

    const int r2 = tid >> 1, c2 = tid & 1;
    const float* gA = A + (size_t)(bm + r2) * K + c2 * 16;
    bf16* sA = As + r2 * 32 + c2 * 16;
    const bf16* gB = Bt + (size_t)(bn + (tid >> 2)) * K + (tid & 3) * 8;
    bf16* lB0 = Bs + (size_t)(w * 64) * 8;
    bf16* lB1 = Bs + (size_t)(w * 64 + 256) * 8;
    const size_t rowskipB = (size_t)64 * K;

    for (int k0 = 0; k0 < K; k0 += 32) {
        gll16(gB + k0, lB0);
        gll16(gB + rowskipB + k0, lB1);
        float4 a0 = *(const float4*)(gA + k0 + 0);
        float4 a1 = *(const float4*)(gA + k0 + 4);
        float4 a2 = *(const float4*)(gA + k0 + 8);
        float4 a3 = *(const float4*)(gA + k0 + 12);
        bf16x8 h0, h1;
        h0[0] = (bf16)a0.x; h0[1] = (bf16)a0.y; h0[2] = (bf16)a0.z; h0[3] = (bf16)a0.w;
        h0[4] = (bf16)a1.x; h0[5] = (bf16)a1.y; h0[6] = (bf16)a1.z; h0[7] = (bf16)a1.w;
        h1[0] = (bf16)a2.x; h1[1] = (bf16)a2.y; h1[2] = (bf16)a2.z; h1[3] = (bf16)a2.w;
        h1[4] = (bf16)a3.x; h1[5] = (bf16)a3.y; h1[6] = (bf16)a3.z; h1[7] = (bf16)a3.w;
        *(bf16x8*)(sA + 0) = h0;
        *(bf16x8*)(sA + 8) = h1;
        __syncthreads();
        bf16x8 af[4], bfr[4];
#pragma unroll
        for (int i = 0; i < 4; i++) af[i] = *(const bf16x8*)&As[(wm + 16 * i + lrow) * 32 + lk8];
#pragma unroll
        for (int j = 0; j < 4; j++) bfr[j] = *(const bf16x8*)&Bs[(wn + 16 * j + lrow) * 32 + lk8];
#pragma unroll
        for (int i = 0; i < 4; i++)
#pragma unroll
            for (int j = 0; j < 4; j++)
                acc[i][j] = __builtin_amdgcn_mfma_f32_16x16x32_bf16(af[i], bfr[j], acc[i][j], 0, 0, 0);
        __syncthreads();
    }

    const float inv = rsqrtf(1.f + EPSC);
#pragma unroll
    for (int j = 0; j < 4; j++) {
        int col = bn + wn + 16 * j + lrow;
        float bcol = bias[col];
        float gc = g[col] * inv;
        float bec = be[col];
#pragma unroll
        for (int i = 0; i < 4; i++) {
            int row0 = bm + wm + 16 * i + (lane >> 4) * 4;
#pragma unroll
            for (int r = 0; r < 4; r++) {
                float z = fmaxf(acc[i][j][r] + bcol, 0.f) * gc + bec;
                C[(size_t)(row0 + r) * HID + col] = (bf16)z;
            }
        }
    }
}

// ---------- CSR build (by dst, over E' = E + N self-loop edges) ----------
__global__ void hist_kernel(const int* __restrict__ ei, int* __restrict__ cnt) {
    int e = blockIdx.x * 256 + threadIdx.x;
    if (e >= EPE) return;
    int d = (e < N_EDGES) ? ei[N_EDGES + e] : (e - N_EDGES);
    atomicAdd(&cnt[d], 1);
}

__global__ __launch_bounds__(1024) void scan_kernel(const int* __restrict__ cnt,
                                                    int* __restrict__ roff, int* __restrict__ cursor) {
    __shared__ int wsum[16];
    int t = threadIdx.x;
    int base = t * 16;
    int local[16]; int s = 0;
#pragma unroll
    for (int i = 0; i < 16; i++) {
        int idx = base + i;
        int v = (idx < N_NODES) ? cnt[idx] : 0;
        local[i] = s; s += v;
    }
    int lane = t & 63, wid = t >> 6;
    int incl = s;
    for (int o = 1; o < 64; o <<= 1) { int v = __shfl_up(incl, o); if (lane >= o) incl += v; }
    if (lane == 63) wsum[wid] = incl;
    __syncthreads();
    if (t == 0) { int a = 0; for (int k = 0; k < 16; k++) { int v = wsum[k]; wsum[k] = a; a += v; } }
    __syncthreads();
    int texcl = incl - s + wsum[wid];
#pragma unroll
    for (int i = 0; i < 16; i++) {
        int idx = base + i;
        if (idx < N_NODES) { int o = texcl + local[i]; roff[idx] = o; cursor[idx] = o; }
    }
    if (t == 1023) roff[N_NODES] = texcl + s;
}

// esrc: src | (selfloop<<31), edst: dst  (CSR position order)
__global__ void scatter_kernel(const int* __restrict__ ei, int* __restrict__ cursor,
                               int* __restrict__ esrc, int* __restrict__ edst) {
    int e = blockIdx.x * 256 + threadIdx.x;
    if (e >= EPE) return;
    int s, d, f;
    if (e < N_EDGES) { s = ei[e]; d = ei[N_EDGES + e]; f = 0; }
    else { s = d = e - N_EDGES; f = (int)0x80000000; }
    int pos = atomicAdd(&cursor[d], 1);
    esrc[pos] = s | f; edst[pos] = d;
}

// ---------- GAT edge logits (CSR order; XLR = [xl|xr] stride 512) ----------
__global__ void edge_logit(const bf16* __restrict__ XLR, const int* __restrict__ esrc,
                           const int* __restrict__ edst, const float* __restrict__ att,
                           float* __restrict__ elog) {
    int idx = blockIdx.x * 256 + threadIdx.x;
    if (idx >= EPE * HEADS) return;
    int p = idx >> 3, h = idx & 7;
    int s = esrc[p] & 0x7fffffff, d = edst[p];
    const bf16* pl = XLR + (size_t)s * 512 + h * CPH;
    const bf16* pr = XLR + (size_t)d * 512 + 256 + h * CPH;
    const float* pa = att + h * CPH;
    float acc = 0.f;
#pragma unroll
    for (int c8 = 0; c8 < 4; c8++) {
        bf16x8 l = *(const bf16x8*)(pl + c8 * 8);
        bf16x8 r = *(const bf16x8*)(pr + c8 * 8);
#pragma unroll
        for (int j = 0; j < 8; j++)
            acc += lrelu((float)l[j] + (float)r[j]) * pa[c8 * 8 + j];
    }
    elog[idx] = acc;
}

// ---------- GAT gather: segment softmax + weighted aggregation (one block per dst) ----------
__global__ __launch_bounds__(256) void gat_gather(
    const bf16* __restrict__ XLR, const float* __restrict__ elog,
    const int* __restrict__ roff, const int* __restrict__ esrc,
    const float* __restrict__ gbias, bf16* __restrict__ out)
{
    int d = blockIdx.x, t = threadIdx.x;
    int beg = roff[d], deg = roff[d + 1] - beg;
    __shared__ float sm[8], srinv[8];
    __shared__ float alpha_s[32 * 8];
    __shared__ int src_s[32];
    if (t < 64) {
        int h = t & 7, j0 = t >> 3;
        float mx = -INFINITY;
        for (int j = j0; j < deg; j += 8) mx = fmaxf(mx, elog[(beg + j) * 8 + h]);
        for (int o = 8; o < 64; o <<= 1) mx = fmaxf(mx, __shfl_xor(mx, o));
        float ss = 0.f;
        for (int j = j0; j < deg; j += 8) ss += __expf(elog[(beg + j) * 8 + h] - mx);
        for (int o = 8; o < 64; o <<= 1) ss += __shfl_xor(ss, o);
        if (t < 8) { sm[h] = mx; srinv[h] = 1.f / (ss + 1e-16f); }
    }
    __syncthreads();
    float acc = gbias[t];
    int h = t >> 5;
    for (int c0 = 0; c0 < deg; c0 += 32) {
        int cn = min(32, deg - c0);
        __syncthreads();
        if (t < cn * 8) {
            int j = t >> 3, hh = t & 7;
            alpha_s[t] = __expf(elog[(beg + c0 + j) * 8 + hh] - sm[hh]) * srinv[hh];
        }
        if (t < cn) src_s[t] = esrc[beg + c0 + t] & 0x7fffffff;
        __syncthreads();
        for (int j = 0; j < cn; j++)
            acc += alpha_s[j * 8 + h] * (float)XLR[(size_t)src_s[j] * 512 + t];
    }
    out[(size_t)d * HID + t] = (bf16)acc;
}

// ---------- GIN gather: u[d] = h[d] + sum over incoming ORIGINAL edges h[src] ----------
__global__ __launch_bounds__(256) void gin_gather(
    const bf16* __restrict__ h, const int* __restrict__ roff,
    const int* __restrict__ esrc, bf16* __restrict__ u)
{
    int d = blockIdx.x, t = threadIdx.x;
    int beg = roff[d], end = roff[d + 1];
    __shared__ int src_s[64];
    float acc = (float)h[(size_t)d * HID + t];
    for (int c0 = beg; c0 < end; c0 += 64) {
        int cn = min(64, end - c0);
        __syncthreads();
        if (t < cn) src_s[t] = esrc[c0 + t];
        __syncthreads();
        for (int j = 0; j < cn; j++) {
            int s = src_s[j];
            if (s >= 0) acc += (float)h[(size_t)s * HID + t];
        }
    }
    u[(size_t)d * HID + t] = (bf16)acc;
}

// ---------- global LN: per-block partials + tiny reduce (no atomics, no memset) ----------
__global__ void stats_kernel(const bf16* __restrict__ x, float2* __restrict__ part, int n8) {
    float s = 0.f, sq = 0.f;
    for (int i = blockIdx.x * blockDim.x + threadIdx.x; i < n8; i += gridDim.x * blockDim.x) {
        bf16x8 v = *(const bf16x8*)(x + (size_t)i * 8);
#pragma unroll
        for (int j = 0; j < 8; j++) { float f = (float)v[j]; s += f; sq += f * f; }
    }
    for (int o = 32; o > 0; o >>= 1) { s += __shfl_down(s, o); sq += __shfl_down(sq, o); }
    __shared__ float ls[4], lq[4];
    int wid = threadIdx.x >> 6, lane = threadIdx.x & 63;
    if (lane == 0) { ls[wid] = s; lq[wid] = sq; }
    __syncthreads();
    if (threadIdx.x == 0)
        part[blockIdx.x] = make_float2(ls[0] + ls[1] + ls[2] + ls[3],
                                       lq[0] + lq[1] + lq[2] + lq[3]);
}

__global__ void stats_reduce(const float2* __restrict__ part, float* __restrict__ stat) {
    int t = threadIdx.x;
    float2 v = part[t];
    float s = v.x, q = v.y;
    for (int o = 32; o > 0; o >>= 1) { s += __shfl_down(s, o); q += __shfl_down(q, o); }
    __shared__ float ls[4], lq[4];
    int wid = t >> 6, lane = t & 63;
    if (lane == 0) { ls[wid] = s; lq[wid] = q; }
    __syncthreads();
    if (t == 0) { stat[0] = ls[0] + ls[1] + ls[2] + ls[3]; stat[1] = lq[0] + lq[1] + lq[2] + lq[3]; }
}

__global__ void ln_res_kernel(const bf16* __restrict__ h, const bf16* __restrict__ r,
                              const float* __restrict__ stats, const float* __restrict__ g,
                              const float* __restrict__ b, bf16* __restrict__ out)
{
    int i = (blockIdx.x * 256 + threadIdx.x) * 4;
    const float inv_n = 1.f / (float)((size_t)N_NODES * HID);
    float mu = stats[0] * inv_n;
    float var = stats[1] * inv_n - mu * mu;
    float sd = sqrtf(fmaxf(var, 0.f));
    float rs = 1.f / (sd + EPSC);
    int ch = i & (HID - 1);
#pragma unroll
    for (int j = 0; j < 4; j++) {
        float v = ((float)h[i + j] - mu) * rs * g[ch + j] + b[ch + j] + (float)r[i + j];
        out[i + j] = (bf16)lrelu(v);
    }
}

// ---------- pooling (batch sorted -> contiguous graph segments, no atomics) ----------
__global__ void gbound_kernel(const int* __restrict__ batch, int* __restrict__ gstart) {
    int g = threadIdx.x;
    if (g > NG) return;
    int lo = 0, hi = N_NODES;
    while (lo < hi) { int mid = (lo + hi) >> 1; if (batch[mid] < g) lo = mid + 1; else hi = mid; }
    gstart[g] = lo;
}

// wave per node: gate[n] = tanh(t[n,:]) . W2 + b2
__global__ __launch_bounds__(256) void pool_gate_kernel(const bf16* __restrict__ t,
    const float* __restrict__ W2, const float* __restrict__ b2, float* __restrict__ gate)
{
    int n = blockIdx.x * 4 + (threadIdx.x >> 6);
    int lane = threadIdx.x & 63;
    const bf16* p = t + (size_t)n * HID + lane * 4;
    float4 w = *(const float4*)(W2 + lane * 4);
    float s = tanhf((float)p[0]) * w.x + tanhf((float)p[1]) * w.y
            + tanhf((float)p[2]) * w.z + tanhf((float)p[3]) * w.w;
    for (int o = 32; o > 0; o >>= 1) s += __shfl_down(s, o);
    if (lane == 0) gate[n] = s + b2[0];
}

// one block per graph: segment softmax over gate + weighted emb accumulation
__global__ __launch_bounds__(256) void pool_graph_kernel(
    const float* __restrict__ gate, const int* __restrict__ gstart,
    const bf16* __restrict__ h, float* __restrict__ emb)
{
    int g = blockIdx.x, t = threadIdx.x;
    int lo = gstart[g], hi = gstart[g + 1];
    __shared__ float red[256];
    float m = -INFINITY;
    for (int n = lo + t; n < hi; n += 256) m = fmaxf(m, gate[n]);
    red[t] = m; __syncthreads();
    for (int st = 128; st > 0; st >>= 1) { if (t < st) red[t] = fmaxf(red[t], red[t + st]); __syncthreads(); }
    m = red[0]; __syncthreads();
    float s = 0.f;
    for (int n = lo + t; n < hi; n += 256) s += __expf(gate[n] - m);
    red[t] = s; __syncthreads();
    for (int st = 128; st > 0; st >>= 1) { if (t < st) red[t] += red[t + st]; __syncthreads(); }
    float sinv = 1.f / (red[0] + 1e-16f);
    float acc = 0.f;
    for (int n = lo; n < hi; n++) {
        float a = __expf(gate[n] - m) * sinv;
        acc += a * (float)h[(size_t)n * HID + t];
    }
    emb[g * HID + t] = acc;
}

// ---------- label heads: grid (64 heads, 8 graph-tiles), 4 graphs/block ----------
__global__ __launch_bounds__(256) void heads_kernel(
    const float* __restrict__ emb, const float* __restrict__ W1, const float* __restrict__ b1,
    const float* __restrict__ hg, const float* __restrict__ hbe, const float* __restrict__ W2,
    const float* __restrict__ b2, float* __restrict__ out)
{
    int o = blockIdx.x;
    int g0 = blockIdx.y * 4;
    int k = threadIdx.x;
    __shared__ float se[4][HID];
    __shared__ float red[256];
#pragma unroll
    for (int j = 0; j < 4; j++) se[j][k] = emb[(g0 + j) * HID + k];
    __syncthreads();
    const float* w1p = W1 + (size_t)o * HID * HID + k;
    float zb = b1[o * HID + k];
    float z0 = zb, z1 = zb, z2 = zb, z3 = zb;
#pragma unroll 8
    for (int d = 0; d < HID; d++) {
        float w = w1p[(size_t)d * HID];
        z0 = fmaf(se[0][d], w, z0);
        z1 = fmaf(se[1][d], w, z1);
        z2 = fmaf(se[2][d], w, z2);
        z3 = fmaf(se[3][d], w, z3);
    }
    const float gk = hg[o * HID + k] * rsqrtf(1.f + EPSC);
    const float bek = hbe[o * HID + k];
    const float w2 = W2[o * HID + k];
    const float b2o = b2[o];
    float zz[4] = {z0, z1, z2, z3};
#pragma unroll
    for (int j = 0; j < 4; j++) {
        float z = zz[j];
        float sil = z / (1.f + expf(-z));
        red[k] = (sil * gk + bek) * w2;
        __syncthreads();
        for (int st = 128; st > 0; st >>= 1) { if (k < st) red[k] += red[k + st]; __syncthreads(); }
        if (k == 0) out[(g0 + j) * NO + o] = red[0] + b2o;
        __syncthreads();
    }
}

extern "C" void kernel_launch(void* const* d_in, const int* in_sizes, int n_in,
                              void* d_out, int out_size, void* d_ws, size_t ws_size,
                              hipStream_t stream) {
    const float* x        = (const float*)d_in[0];
    const int*   ei       = (const int*)  d_in[1];
    const int*   batch    = (const int*)  d_in[2];
    const float* fp_W     = (const float*)d_in[3];
    const float* fp_b     = (const float*)d_in[4];
    const float* fp_g     = (const float*)d_in[5];
    const float* fp_be    = (const float*)d_in[6];
    const float* gat_Wl   = (const float*)d_in[7];
    const float* gat_bl   = (const float*)d_in[8];
    const float* gat_Wr   = (const float*)d_in[9];
    const float* gat_br   = (const float*)d_in[10];
    const float* gat_att  = (const float*)d_in[11];
    const float* gat_bias = (const float*)d_in[12];
    const float* gin_W    = (const float*)d_in[13];
    const float* gin_b    = (const float*)d_in[14];
    const float* gin_g    = (const float*)d_in[15];
    const float* gin_be   = (const float*)d_in[16];
    const float* ln_g     = (const float*)d_in[17];
    const float* ln_b     = (const float*)d_in[18];
    const float* res_W    = (const float*)d_in[19];
    const float* res_b    = (const float*)d_in[20];
    const float* pool_W1  = (const float*)d_in[21];
    const float* pool_b1  = (const float*)d_in[22];
    const float* pool_W2  = (const float*)d_in[23];
    const float* pool_b2  = (const float*)d_in[24];
    const float* head_W1  = (const float*)d_in[25];
    const float* head_b1  = (const float*)d_in[26];
    const float* head_g   = (const float*)d_in[27];
    const float* head_be  = (const float*)d_in[28];
    const float* head_W2  = (const float*)d_in[29];
    const float* head_b2  = (const float*)d_in[30];
    float* out = (float*)d_out;

    char* base = (char*)d_ws;
    size_t off = 0;
    auto alloc = [&](size_t bytes) -> char* {
        char* p = base + off; off += (bytes + 255) & ~(size_t)255; return p;
    };
    float* elog   = (float*)alloc((size_t)EPE * HEADS * 4);
    int*   esrc   = (int*)  alloc((size_t)EPE * 4);
    int*   edst   = (int*)  alloc((size_t)EPE * 4);
    int*   cnt    = (int*)  alloc((size_t)N_NODES * 4);
    int*   roff   = (int*)  alloc((size_t)(N_NODES + 1) * 4);
    int*   cursor = (int*)  alloc((size_t)N_NODES * 4);
    float* gate   = (float*)alloc((size_t)N_NODES * 4);
    int*   gstart = (int*)  alloc((NG + 1) * 4);
    float* emb    = (float*)alloc(NG * HID * 4);
    float* stat   = (float*)alloc(8);
    float2* statp = (float2*)alloc(256 * 8);
    bf16*  Hb0    = (bf16*) alloc((size_t)N_NODES * HID * 2);
    bf16*  Hb1    = (bf16*) alloc((size_t)N_NODES * HID * 2);
    bf16*  XLR    = (bf16*) alloc((size_t)N_NODES * 512 * 2);   // [xl|xr], also reused as gin-u
    bf16*  fpWt   = (bf16*) alloc((size_t)DIN * HID * 2);
    bf16*  wlrT0  = (bf16*) alloc((size_t)512 * HID * 2);
    bf16*  wlrT1  = (bf16*) alloc((size_t)512 * HID * 2);
    bf16*  gwT    = (bf16*) alloc((size_t)2 * HID * HID * 2);
    bf16*  rwT    = (bf16*) alloc((size_t)2 * HID * HID * 2);
    bf16*  pwT    = (bf16*) alloc((size_t)HID * HID * 2);
    bf16*  Ub     = XLR;
    bf16*  wlrT[2] = { wlrT0, wlrT1 };

    // ---- weight conversions (transposed bf16) ----
    wconv_gen<<<(DIN * HID + 255) / 256, 256, 0, stream>>>(fp_W, fpWt, DIN, DIN * HID);
    wconv_pair<<<512, 256, 0, stream>>>(gat_Wl, gat_Wr, wlrT0);
    wconv_pair<<<512, 256, 0, stream>>>(gat_Wl + HID * HID, gat_Wr + HID * HID, wlrT1);
    wconv_gen<<<512, 256, 0, stream>>>(gin_W, gwT, HID, 2 * HID * HID);
    wconv_gen<<<512, 256, 0, stream>>>(res_W, rwT, HID, 2 * HID * HID);
    wconv_gen<<<256, 256, 0, stream>>>(pool_W1, pwT, HID, HID * HID);

    // ---- CSR build ----
    hipMemsetAsync(cnt, 0, N_NODES * sizeof(int), stream);
    hist_kernel<<<(EPE + 255) / 256, 256, 0, stream>>>(ei, cnt);
    scan_kernel<<<1, 1024, 0, stream>>>(cnt, roff, cursor);
    scatter_kernel<<<(EPE + 255) / 256, 256, 0, stream>>>(ei, cursor, esrc, edst);
    gbound_kernel<<<1, 64, 0, stream>>>(batch, gstart);

    // ---- feature projection: h = BN(relu(x @ fp_W + b)) -> Hb0 ----
    dim3 grid256(2, 125), grid512(4, 125);
    gemm_f32A<<<grid256, 256, 0, stream>>>(x, fpWt, fp_b, Hb0, DIN, fp_g, fp_be);

    const int ehBlocks = (EPE * HEADS + 255) / 256;
    for (int i = 0; i < 2; i++) {
        gemm_mfma<<<grid512, 256, 0, stream>>>(Hb0, wlrT[i], gat_bl + i * HID, gat_br + i * HID,
                                               XLR, HID, 512, 0, nullptr, nullptr);
        edge_logit<<<ehBlocks, 256, 0, stream>>>(XLR, esrc, edst, gat_att + i * HEADS * CPH, elog);
        gat_gather<<<N_NODES, 256, 0, stream>>>(XLR, elog, roff, esrc, gat_bias + i * HID, Hb1);
        gin_gather<<<N_NODES, 256, 0, stream>>>(Hb1, roff, esrc, Ub);
        gemm_mfma<<<grid256, 256, 0, stream>>>(Ub, gwT + (size_t)i * HID * HID, gin_b + i * HID,
                                               nullptr, Hb0, HID, HID, 2,
                                               gin_g + i * HID, gin_be + i * HID);
        stats_kernel<<<256, 256, 0, stream>>>(Hb0, statp, (N_NODES * HID) / 8);
        stats_reduce<<<1, 256, 0, stream>>>(statp, stat);
        gemm_mfma<<<grid256, 256, 0, stream>>>(Hb0, rwT + (size_t)i * HID * HID, res_b + i * HID,
                                               nullptr, Hb1, HID, HID, 0, nullptr, nullptr);
        ln_res_kernel<<<(N_NODES * HID) / 1024, 256, 0, stream>>>(Hb0, Hb1, stat,
                                                                  ln_g + i * HID, ln_b + i * HID, Hb0);
    }

    // ---- global attention pooling (segment-contiguous, no atomics) ----
    gemm_mfma<<<grid256, 256, 0, stream>>>(Hb0, pwT, pool_b1, nullptr, Hb1, HID, HID, 0, nullptr, nullptr);
    pool_gate_kernel<<<N_NODES / 4, 256, 0, stream>>>(Hb1, pool_W2, pool_b2, gate);
    pool_graph_kernel<<<NG, 256, 0, stream>>>(gate, gstart, Hb0, emb);

    // ---- label heads ----
    dim3 hgrid(NO, 8);
    heads_kernel<<<hgrid, 256, 0, stream>>>(emb, head_W1, head_b1, head_g, head_be,
                                            head_W2, head_b2, out);
}

// Round 5
// 852.674 us; speedup vs baseline: 2.6952x; 1.0338x over previous
//
#include <hip/hip_runtime.h>
#include <math.h>

#define N_NODES 16000
#define N_EDGES 256000
#define EPE (N_EDGES + N_NODES)
#define DIN 1280
#define HID 256
#define HEADS 8
#define CPH 32
#define NG 32
#define NO 64
#define EPSC 1e-5f
#define CAP 64   // src rows cached per chunk in gat_fused

typedef __bf16 bf16;
typedef __attribute__((ext_vector_type(8))) __bf16 bf16x8;
typedef __attribute__((ext_vector_type(4))) float floatx4;

typedef __attribute__((address_space(3))) unsigned int lds_u32;
typedef const __attribute__((address_space(1))) unsigned int glob_u32;

__device__ __forceinline__ float lrelu(float v) { return v > 0.f ? v : 0.2f * v; }

__device__ __forceinline__ void gll16(const void* g, void* l) {
    __builtin_amdgcn_global_load_lds((glob_u32*)g, (lds_u32*)l, 16, 0, 0);
}

// ---------- weight transpose/convert: W[L][K][256] fp32 -> WT[L][256][K] bf16 ----------
__global__ void wconv_gen(const float* __restrict__ W, bf16* __restrict__ Wt, int K, int total) {
    int idx = blockIdx.x * 256 + threadIdx.x;
    if (idx >= total) return;
    int per = K * HID;
    int l = idx / per, rem = idx - l * per;
    int n = rem / K, k = rem - n * K;
    Wt[idx] = (bf16)W[(size_t)l * per + (size_t)k * HID + n];
}

// [Wl|Wr] -> WT[512][256] bf16
__global__ void wconv_pair(const float* __restrict__ Wl, const float* __restrict__ Wr,
                           bf16* __restrict__ Wt) {
    int idx = blockIdx.x * 256 + threadIdx.x;
    int n = idx >> 8, k = idx & 255;
    float v = (n < 256) ? Wl[(size_t)k * HID + n] : Wr[(size_t)k * HID + (n - 256)];
    Wt[idx] = (bf16)v;
}

// ---------- MFMA GEMM (bf16 A): C[16000,ncols] = A @ Bt^T ----------
__global__ __launch_bounds__(256) void gemm_mfma(
    const bf16* __restrict__ A, const bf16* __restrict__ Bt,
    const float* __restrict__ bias, const float* __restrict__ bias2,
    bf16* __restrict__ C, int K, int ldc, int mode,
    const float* __restrict__ g, const float* __restrict__ be)
{
    __shared__ __align__(16) bf16 As[128 * 32];
    __shared__ __align__(16) bf16 Bs[128 * 32];
    const int tid = threadIdx.x;
    const int bm = blockIdx.y * 128, bn = blockIdx.x * 128;
    const int w = tid >> 6, lane = tid & 63;
    const int wm = (w & 1) * 64, wn = (w >> 1) * 64;
    const int lrow = lane & 15, lk8 = (lane >> 4) * 8;

    floatx4 acc[4][4];
#pragma unroll
    for (int i = 0; i < 4; i++)
#pragma unroll
        for (int j = 0; j < 4; j++) acc[i][j] = (floatx4){0.f, 0.f, 0.f, 0.f};

    const bf16* gA = A + (size_t)(bm + (tid >> 2)) * K + (tid & 3) * 8;
    const bf16* gB = Bt + (size_t)(bn + (tid >> 2)) * K + (tid & 3) * 8;
    bf16* lA0 = As + (size_t)(w * 64) * 8;
    bf16* lA1 = As + (size_t)(w * 64 + 256) * 8;
    bf16* lB0 = Bs + (size_t)(w * 64) * 8;
    bf16* lB1 = Bs + (size_t)(w * 64 + 256) * 8;
    const size_t rowskip = (size_t)64 * K;

    for (int k0 = 0; k0 < K; k0 += 32) {
        gll16(gA + k0, lA0);
        gll16(gA + rowskip + k0, lA1);
        gll16(gB + k0, lB0);
        gll16(gB + rowskip + k0, lB1);
        __syncthreads();
        bf16x8 af[4], bfr[4];
#pragma unroll
        for (int i = 0; i < 4; i++) af[i] = *(const bf16x8*)&As[(wm + 16 * i + lrow) * 32 + lk8];
#pragma unroll
        for (int j = 0; j < 4; j++) bfr[j] = *(const bf16x8*)&Bs[(wn + 16 * j + lrow) * 32 + lk8];
#pragma unroll
        for (int i = 0; i < 4; i++)
#pragma unroll
            for (int j = 0; j < 4; j++)
                acc[i][j] = __builtin_amdgcn_mfma_f32_16x16x32_bf16(af[i], bfr[j], acc[i][j], 0, 0, 0);
        __syncthreads();
    }

    const float inv = rsqrtf(1.f + EPSC);
#pragma unroll
    for (int j = 0; j < 4; j++) {
        int col = bn + wn + 16 * j + lrow;
        float bcol = (col < HID) ? bias[col] : bias2[col - HID];
        float gc = (mode >= 1) ? g[col] * inv : 0.f;
        float bec = (mode >= 1) ? be[col] : 0.f;
#pragma unroll
        for (int i = 0; i < 4; i++) {
            int row0 = bm + wm + 16 * i + (lane >> 4) * 4;
#pragma unroll
            for (int r = 0; r < 4; r++) {
                float z = acc[i][j][r] + bcol;
                if (mode >= 1) { z = fmaxf(z, 0.f); z = z * gc + bec; }
                if (mode == 2) z = lrelu(z);
                C[(size_t)(row0 + r) * ldc + col] = (bf16)z;
            }
        }
    }
}

// ---------- MFMA GEMM (fp32 A): K=1280 feature projection ----------
__global__ __launch_bounds__(256) void gemm_f32A(
    const float* __restrict__ A, const bf16* __restrict__ Bt,
    const float* __restrict__ bias, bf16* __restrict__ C, int K,
    const float* __restrict__ g, const float* __restrict__ be)
{
    __shared__ __align__(16) bf16 As[128 * 32];
    __shared__ __align__(16) bf16 Bs[128 * 32];
    const int tid = threadIdx.x;
    const int bm = blockIdx.y * 128, bn = blockIdx.x * 128;
    const int w = tid >> 6, lane = tid & 63;
    const int wm = (w & 1) * 64, wn = (w >> 1) * 64;
    const int lrow = lane & 15, lk8 = (lane >> 4) * 8;

    floatx4 acc[4][4];
#pragma unroll
    for (int i = 0; i < 4; i++)
#pragma unroll
        for (int j = 0; j < 4; j++) acc[i][j] = (floatx4){0.f, 0.f, 0.f, 0.f};

    const int r2 = tid >> 1, c2 = tid & 1;
    const float* gA = A + (size_t)(bm + r2) * K + c2 * 16;
    bf16* sA = As + r2 * 32 + c2 * 16;
    const bf16* gB = Bt + (size_t)(bn + (tid >> 2)) * K + (tid & 3) * 8;
    bf16* lB0 = Bs + (size_t)(w * 64) * 8;
    bf16* lB1 = Bs + (size_t)(w * 64 + 256) * 8;
    const size_t rowskipB = (size_t)64 * K;

    for (int k0 = 0; k0 < K; k0 += 32) {
        gll16(gB + k0, lB0);
        gll16(gB + rowskipB + k0, lB1);
        float4 a0 = *(const float4*)(gA + k0 + 0);
        float4 a1 = *(const float4*)(gA + k0 + 4);
        float4 a2 = *(const float4*)(gA + k0 + 8);
        float4 a3 = *(const float4*)(gA + k0 + 12);
        bf16x8 h0, h1;
        h0[0] = (bf16)a0.x; h0[1] = (bf16)a0.y; h0[2] = (bf16)a0.z; h0[3] = (bf16)a0.w;
        h0[4] = (bf16)a1.x; h0[5] = (bf16)a1.y; h0[6] = (bf16)a1.z; h0[7] = (bf16)a1.w;
        h1[0] = (bf16)a2.x; h1[1] = (bf16)a2.y; h1[2] = (bf16)a2.z; h1[3] = (bf16)a2.w;
        h1[4] = (bf16)a3.x; h1[5] = (bf16)a3.y; h1[6] = (bf16)a3.z; h1[7] = (bf16)a3.w;
        *(bf16x8*)(sA + 0) = h0;
        *(bf16x8*)(sA + 8) = h1;
        __syncthreads();
        bf16x8 af[4], bfr[4];
#pragma unroll
        for (int i = 0; i < 4; i++) af[i] = *(const bf16x8*)&As[(wm + 16 * i + lrow) * 32 + lk8];
#pragma unroll
        for (int j = 0; j < 4; j++) bfr[j] = *(const bf16x8*)&Bs[(wn + 16 * j + lrow) * 32 + lk8];
#pragma unroll
        for (int i = 0; i < 4; i++)
#pragma unroll
            for (int j = 0; j < 4; j++)
                acc[i][j] = __builtin_amdgcn_mfma_f32_16x16x32_bf16(af[i], bfr[j], acc[i][j], 0, 0, 0);
        __syncthreads();
    }

    const float inv = rsqrtf(1.f + EPSC);
#pragma unroll
    for (int j = 0; j < 4; j++) {
        int col = bn + wn + 16 * j + lrow;
        float bcol = bias[col];
        float gc = g[col] * inv;
        float bec = be[col];
#pragma unroll
        for (int i = 0; i < 4; i++) {
            int row0 = bm + wm + 16 * i + (lane >> 4) * 4;
#pragma unroll
            for (int r = 0; r < 4; r++) {
                float z = fmaxf(acc[i][j][r] + bcol, 0.f) * gc + bec;
                C[(size_t)(row0 + r) * HID + col] = (bf16)z;
            }
        }
    }
}

// ---------- CSR build ----------
__global__ void hist_kernel(const int* __restrict__ ei, int* __restrict__ cnt) {
    int e = blockIdx.x * 256 + threadIdx.x;
    if (e >= EPE) return;
    int d = (e < N_EDGES) ? ei[N_EDGES + e] : (e - N_EDGES);
    atomicAdd(&cnt[d], 1);
}

__global__ __launch_bounds__(1024) void scan_kernel(const int* __restrict__ cnt,
                                                    int* __restrict__ roff, int* __restrict__ cursor) {
    __shared__ int wsum[16];
    int t = threadIdx.x;
    int base = t * 16;
    int local[16]; int s = 0;
#pragma unroll
    for (int i = 0; i < 16; i++) {
        int idx = base + i;
        int v = (idx < N_NODES) ? cnt[idx] : 0;
        local[i] = s; s += v;
    }
    int lane = t & 63, wid = t >> 6;
    int incl = s;
    for (int o = 1; o < 64; o <<= 1) { int v = __shfl_up(incl, o); if (lane >= o) incl += v; }
    if (lane == 63) wsum[wid] = incl;
    __syncthreads();
    if (t == 0) { int a = 0; for (int k = 0; k < 16; k++) { int v = wsum[k]; wsum[k] = a; a += v; } }
    __syncthreads();
    int texcl = incl - s + wsum[wid];
#pragma unroll
    for (int i = 0; i < 16; i++) {
        int idx = base + i;
        if (idx < N_NODES) { int o = texcl + local[i]; roff[idx] = o; cursor[idx] = o; }
    }
    if (t == 1023) roff[N_NODES] = texcl + s;
}

__global__ void scatter_kernel(const int* __restrict__ ei, int* __restrict__ cursor,
                               int* __restrict__ esrc) {
    int e = blockIdx.x * 256 + threadIdx.x;
    if (e >= EPE) return;
    int s, d, f;
    if (e < N_EDGES) { s = ei[e]; d = ei[N_EDGES + e]; f = 0; }
    else { s = d = e - N_EDGES; f = (int)0x80000000; }
    int pos = atomicAdd(&cursor[d], 1);
    esrc[pos] = s | f;
}

// ---------- fused GATv2: logits + online softmax + weighted gather, block per dst ----------
__global__ __launch_bounds__(256) void gat_fused(
    const bf16* __restrict__ XLR, const int* __restrict__ roff, const int* __restrict__ esrc,
    const float* __restrict__ att, const float* __restrict__ gbias, bf16* __restrict__ out)
{
    int d = blockIdx.x, t = threadIdx.x;
    int beg = roff[d], deg = roff[d + 1] - beg;
    __shared__ __align__(16) bf16 xr_s[256];
    __shared__ __align__(16) bf16 xs[CAP][256];
    __shared__ float llog[CAP * 8];
    __shared__ int src_s[CAP];
    __shared__ float m_s[8], s_s[8], resc[8];

    if (t < 32) *(bf16x8*)(xr_s + t * 8) = *(const bf16x8*)(XLR + (size_t)d * 512 + 256 + t * 8);
    if (t < 8) { m_s[t] = -INFINITY; s_s[t] = 0.f; }
    __syncthreads();
    const float xrv = (float)xr_s[t];
    const float av = att[t];
    const int h = t >> 5;
    float acc = 0.f;

    for (int c0 = 0; c0 < deg; c0 += CAP) {
        int cn = min(CAP, deg - c0);
        __syncthreads();          // protect xs/src_s from previous iteration's readers
        if (t < cn) src_s[t] = esrc[beg + c0 + t] & 0x7fffffff;
        __syncthreads();
        // load cn src rows (xl halves, 512 B each): 32 lanes x 16 B per row, 8 rows per pass
        for (int r = t >> 5; r < cn; r += 8)
            *(bf16x8*)(&xs[r][(t & 31) * 8]) = *(const bf16x8*)(XLR + (size_t)src_s[r] * 512 + (t & 31) * 8);
        __syncthreads();
        // logits: 32-lane reduction per (edge, head)
        for (int j = 0; j < cn; j++) {
            float v = lrelu((float)xs[j][t] + xrv) * av;
#pragma unroll
            for (int o = 16; o > 0; o >>= 1) v += __shfl_xor(v, o);
            if ((t & 31) == 0) llog[j * 8 + h] = v;
        }
        __syncthreads();
        // online softmax update (per head, serial over chunk)
        if (t < 8) {
            float mo = m_s[t], mc = mo;
            for (int j = 0; j < cn; j++) mc = fmaxf(mc, llog[j * 8 + t]);
            float sc = __expf(mo - mc);
            float ss = s_s[t] * sc;
            for (int j = 0; j < cn; j++) {
                float e = __expf(llog[j * 8 + t] - mc);
                llog[j * 8 + t] = e;
                ss += e;
            }
            m_s[t] = mc; s_s[t] = ss; resc[t] = sc;
        }
        __syncthreads();
        acc *= resc[h];
        for (int j = 0; j < cn; j++)
            acc += llog[j * 8 + h] * (float)xs[j][t];
    }
    out[(size_t)d * HID + t] = (bf16)(gbias[t] + acc / (s_s[h] + 1e-16f));
}

// ---------- GIN gather ----------
__global__ __launch_bounds__(256) void gin_gather(
    const bf16* __restrict__ h, const int* __restrict__ roff,
    const int* __restrict__ esrc, bf16* __restrict__ u)
{
    int d = blockIdx.x, t = threadIdx.x;
    int beg = roff[d], end = roff[d + 1];
    __shared__ int src_s[64];
    float acc = (float)h[(size_t)d * HID + t];
    for (int c0 = beg; c0 < end; c0 += 64) {
        int cn = min(64, end - c0);
        __syncthreads();
        if (t < cn) src_s[t] = esrc[c0 + t];
        __syncthreads();
        for (int j = 0; j < cn; j++) {
            int s = src_s[j];
            if (s >= 0) acc += (float)h[(size_t)s * HID + t];
        }
    }
    u[(size_t)d * HID + t] = (bf16)acc;
}

// ---------- global LN ----------
__global__ void stats_kernel(const bf16* __restrict__ x, float2* __restrict__ part, int n8) {
    float s = 0.f, sq = 0.f;
    for (int i = blockIdx.x * blockDim.x + threadIdx.x; i < n8; i += gridDim.x * blockDim.x) {
        bf16x8 v = *(const bf16x8*)(x + (size_t)i * 8);
#pragma unroll
        for (int j = 0; j < 8; j++) { float f = (float)v[j]; s += f; sq += f * f; }
    }
    for (int o = 32; o > 0; o >>= 1) { s += __shfl_down(s, o); sq += __shfl_down(sq, o); }
    __shared__ float ls[4], lq[4];
    int wid = threadIdx.x >> 6, lane = threadIdx.x & 63;
    if (lane == 0) { ls[wid] = s; lq[wid] = sq; }
    __syncthreads();
    if (threadIdx.x == 0)
        part[blockIdx.x] = make_float2(ls[0] + ls[1] + ls[2] + ls[3],
                                       lq[0] + lq[1] + lq[2] + lq[3]);
}

__global__ void stats_reduce(const float2* __restrict__ part, float* __restrict__ stat) {
    int t = threadIdx.x;
    float2 v = part[t];
    float s = v.x, q = v.y;
    for (int o = 32; o > 0; o >>= 1) { s += __shfl_down(s, o); q += __shfl_down(q, o); }
    __shared__ float ls[4], lq[4];
    int wid = t >> 6, lane = t & 63;
    if (lane == 0) { ls[wid] = s; lq[wid] = q; }
    __syncthreads();
    if (t == 0) { stat[0] = ls[0] + ls[1] + ls[2] + ls[3]; stat[1] = lq[0] + lq[1] + lq[2] + lq[3]; }
}

__global__ void ln_res_kernel(const bf16* __restrict__ h, const bf16* __restrict__ r,
                              const float* __restrict__ stats, const float* __restrict__ g,
                              const float* __restrict__ b, bf16* __restrict__ out)
{
    int i = (blockIdx.x * 256 + threadIdx.x) * 4;
    const float inv_n = 1.f / (float)((size_t)N_NODES * HID);
    float mu = stats[0] * inv_n;
    float var = stats[1] * inv_n - mu * mu;
    float sd = sqrtf(fmaxf(var, 0.f));
    float rs = 1.f / (sd + EPSC);
    int ch = i & (HID - 1);
#pragma unroll
    for (int j = 0; j < 4; j++) {
        float v = ((float)h[i + j] - mu) * rs * g[ch + j] + b[ch + j] + (float)r[i + j];
        out[i + j] = (bf16)lrelu(v);
    }
}

// ---------- pooling ----------
__global__ void gbound_kernel(const int* __restrict__ batch, int* __restrict__ gstart) {
    int g = threadIdx.x;
    if (g > NG) return;
    int lo = 0, hi = N_NODES;
    while (lo < hi) { int mid = (lo + hi) >> 1; if (batch[mid] < g) lo = mid + 1; else hi = mid; }
    gstart[g] = lo;
}

__global__ __launch_bounds__(256) void pool_gate_kernel(const bf16* __restrict__ t,
    const float* __restrict__ W2, const float* __restrict__ b2, float* __restrict__ gate)
{
    int n = blockIdx.x * 4 + (threadIdx.x >> 6);
    int lane = threadIdx.x & 63;
    const bf16* p = t + (size_t)n * HID + lane * 4;
    float4 w = *(const float4*)(W2 + lane * 4);
    float s = tanhf((float)p[0]) * w.x + tanhf((float)p[1]) * w.y
            + tanhf((float)p[2]) * w.z + tanhf((float)p[3]) * w.w;
    for (int o = 32; o > 0; o >>= 1) s += __shfl_down(s, o);
    if (lane == 0) gate[n] = s + b2[0];
}

// block per graph: segment softmax stats, write alpha back into gate
__global__ __launch_bounds__(256) void pool_stats_kernel(
    float* __restrict__ gate, const int* __restrict__ gstart)
{
    int g = blockIdx.x, t = threadIdx.x;
    int lo = gstart[g], hi = gstart[g + 1];
    __shared__ float red[256];
    float m = -INFINITY;
    for (int n = lo + t; n < hi; n += 256) m = fmaxf(m, gate[n]);
    red[t] = m; __syncthreads();
    for (int st = 128; st > 0; st >>= 1) { if (t < st) red[t] = fmaxf(red[t], red[t + st]); __syncthreads(); }
    m = red[0]; __syncthreads();
    float s = 0.f;
    for (int n = lo + t; n < hi; n += 256) s += __expf(gate[n] - m);
    red[t] = s; __syncthreads();
    for (int st = 128; st > 0; st >>= 1) { if (t < st) red[t] += red[t + st]; __syncthreads(); }
    float sinv = 1.f / (red[0] + 1e-16f);
    for (int n = lo + t; n < hi; n += 256) gate[n] = __expf(gate[n] - m) * sinv;
}

// node-parallel weighted accumulation (batch sorted, flush on graph change)
__global__ __launch_bounds__(256) void emb_accum_kernel(
    const float* __restrict__ a, const int* __restrict__ batch,
    const bf16* __restrict__ h, float* __restrict__ emb)
{
    int n0 = blockIdx.x * 32, t = threadIdx.x;
    int cur = batch[n0]; float acc = 0.f;
    for (int j = 0; j < 32; j++) {
        int n = n0 + j;
        int b = batch[n];
        if (b != cur) { atomicAdd(&emb[cur * HID + t], acc); cur = b; acc = 0.f; }
        acc += a[n] * (float)h[(size_t)n * HID + t];
    }
    atomicAdd(&emb[cur * HID + t], acc);
}

// ---------- label heads ----------
__global__ __launch_bounds__(256) void heads_kernel(
    const float* __restrict__ emb, const float* __restrict__ W1, const float* __restrict__ b1,
    const float* __restrict__ hg, const float* __restrict__ hbe, const float* __restrict__ W2,
    const float* __restrict__ b2, float* __restrict__ out)
{
    int o = blockIdx.x;
    int g0 = blockIdx.y * 4;
    int k = threadIdx.x;
    __shared__ float se[4][HID];
    __shared__ float red[256];
#pragma unroll
    for (int j = 0; j < 4; j++) se[j][k] = emb[(g0 + j) * HID + k];
    __syncthreads();
    const float* w1p = W1 + (size_t)o * HID * HID + k;
    float zb = b1[o * HID + k];
    float z0 = zb, z1 = zb, z2 = zb, z3 = zb;
#pragma unroll 8
    for (int d = 0; d < HID; d++) {
        float w = w1p[(size_t)d * HID];
        z0 = fmaf(se[0][d], w, z0);
        z1 = fmaf(se[1][d], w, z1);
        z2 = fmaf(se[2][d], w, z2);
        z3 = fmaf(se[3][d], w, z3);
    }
    const float gk = hg[o * HID + k] * rsqrtf(1.f + EPSC);
    const float bek = hbe[o * HID + k];
    const float w2 = W2[o * HID + k];
    const float b2o = b2[o];
    float zz[4] = {z0, z1, z2, z3};
#pragma unroll
    for (int j = 0; j < 4; j++) {
        float z = zz[j];
        float sil = z / (1.f + expf(-z));
        red[k] = (sil * gk + bek) * w2;
        __syncthreads();
        for (int st = 128; st > 0; st >>= 1) { if (k < st) red[k] += red[k + st]; __syncthreads(); }
        if (k == 0) out[(g0 + j) * NO + o] = red[0] + b2o;
        __syncthreads();
    }
}

extern "C" void kernel_launch(void* const* d_in, const int* in_sizes, int n_in,
                              void* d_out, int out_size, void* d_ws, size_t ws_size,
                              hipStream_t stream) {
    const float* x        = (const float*)d_in[0];
    const int*   ei       = (const int*)  d_in[1];
    const int*   batch    = (const int*)  d_in[2];
    const float* fp_W     = (const float*)d_in[3];
    const float* fp_b     = (const float*)d_in[4];
    const float* fp_g     = (const float*)d_in[5];
    const float* fp_be    = (const float*)d_in[6];
    const float* gat_Wl   = (const float*)d_in[7];
    const float* gat_bl   = (const float*)d_in[8];
    const float* gat_Wr   = (const float*)d_in[9];
    const float* gat_br   = (const float*)d_in[10];
    const float* gat_att  = (const float*)d_in[11];
    const float* gat_bias = (const float*)d_in[12];
    const float* gin_W    = (const float*)d_in[13];
    const float* gin_b    = (const float*)d_in[14];
    const float* gin_g    = (const float*)d_in[15];
    const float* gin_be   = (const float*)d_in[16];
    const float* ln_g     = (const float*)d_in[17];
    const float* ln_b     = (const float*)d_in[18];
    const float* res_W    = (const float*)d_in[19];
    const float* res_b    = (const float*)d_in[20];
    const float* pool_W1  = (const float*)d_in[21];
    const float* pool_b1  = (const float*)d_in[22];
    const float* pool_W2  = (const float*)d_in[23];
    const float* pool_b2  = (const float*)d_in[24];
    const float* head_W1  = (const float*)d_in[25];
    const float* head_b1  = (const float*)d_in[26];
    const float* head_g   = (const float*)d_in[27];
    const float* head_be  = (const float*)d_in[28];
    const float* head_W2  = (const float*)d_in[29];
    const float* head_b2  = (const float*)d_in[30];
    float* out = (float*)d_out;

    char* base = (char*)d_ws;
    size_t off = 0;
    auto alloc = [&](size_t bytes) -> char* {
        char* p = base + off; off += (bytes + 255) & ~(size_t)255; return p;
    };
    int*   esrc   = (int*)  alloc((size_t)EPE * 4);
    int*   cnt    = (int*)  alloc((size_t)N_NODES * 4);
    int*   roff   = (int*)  alloc((size_t)(N_NODES + 1) * 4);
    int*   cursor = (int*)  alloc((size_t)N_NODES * 4);
    float* gate   = (float*)alloc((size_t)N_NODES * 4);
    int*   gstart = (int*)  alloc((NG + 1) * 4);
    float* emb    = (float*)alloc(NG * HID * 4);
    float* stat   = (float*)alloc(8);
    float2* statp = (float2*)alloc(256 * 8);
    bf16*  Hb0    = (bf16*) alloc((size_t)N_NODES * HID * 2);
    bf16*  Hb1    = (bf16*) alloc((size_t)N_NODES * HID * 2);
    bf16*  XLR    = (bf16*) alloc((size_t)N_NODES * 512 * 2);
    bf16*  fpWt   = (bf16*) alloc((size_t)DIN * HID * 2);
    bf16*  wlrT0  = (bf16*) alloc((size_t)512 * HID * 2);
    bf16*  wlrT1  = (bf16*) alloc((size_t)512 * HID * 2);
    bf16*  gwT    = (bf16*) alloc((size_t)2 * HID * HID * 2);
    bf16*  rwT    = (bf16*) alloc((size_t)2 * HID * HID * 2);
    bf16*  pwT    = (bf16*) alloc((size_t)HID * HID * 2);
    bf16*  Ub     = XLR;
    bf16*  wlrT[2] = { wlrT0, wlrT1 };

    // ---- weight conversions ----
    wconv_gen<<<(DIN * HID + 255) / 256, 256, 0, stream>>>(fp_W, fpWt, DIN, DIN * HID);
    wconv_pair<<<512, 256, 0, stream>>>(gat_Wl, gat_Wr, wlrT0);
    wconv_pair<<<512, 256, 0, stream>>>(gat_Wl + HID * HID, gat_Wr + HID * HID, wlrT1);
    wconv_gen<<<512, 256, 0, stream>>>(gin_W, gwT, HID, 2 * HID * HID);
    wconv_gen<<<512, 256, 0, stream>>>(res_W, rwT, HID, 2 * HID * HID);
    wconv_gen<<<256, 256, 0, stream>>>(pool_W1, pwT, HID, HID * HID);

    // ---- CSR build ----
    hipMemsetAsync(cnt, 0, N_NODES * sizeof(int), stream);
    hist_kernel<<<(EPE + 255) / 256, 256, 0, stream>>>(ei, cnt);
    scan_kernel<<<1, 1024, 0, stream>>>(cnt, roff, cursor);
    scatter_kernel<<<(EPE + 255) / 256, 256, 0, stream>>>(ei, cursor, esrc);
    gbound_kernel<<<1, 64, 0, stream>>>(batch, gstart);

    // ---- feature projection ----
    dim3 grid256(2, 125), grid512(4, 125);
    gemm_f32A<<<grid256, 256, 0, stream>>>(x, fpWt, fp_b, Hb0, DIN, fp_g, fp_be);

    for (int i = 0; i < 2; i++) {
        gemm_mfma<<<grid512, 256, 0, stream>>>(Hb0, wlrT[i], gat_bl + i * HID, gat_br + i * HID,
                                               XLR, HID, 512, 0, nullptr, nullptr);
        gat_fused<<<N_NODES, 256, 0, stream>>>(XLR, roff, esrc, gat_att + i * HEADS * CPH,
                                               gat_bias + i * HID, Hb1);
        gin_gather<<<N_NODES, 256, 0, stream>>>(Hb1, roff, esrc, Ub);
        gemm_mfma<<<grid256, 256, 0, stream>>>(Ub, gwT + (size_t)i * HID * HID, gin_b + i * HID,
                                               nullptr, Hb0, HID, HID, 2,
                                               gin_g + i * HID, gin_be + i * HID);
        stats_kernel<<<256, 256, 0, stream>>>(Hb0, statp, (N_NODES * HID) / 8);
        stats_reduce<<<1, 256, 0, stream>>>(statp, stat);
        gemm_mfma<<<grid256, 256, 0, stream>>>(Hb0, rwT + (size_t)i * HID * HID, res_b + i * HID,
                                               nullptr, Hb1, HID, HID, 0, nullptr, nullptr);
        ln_res_kernel<<<(N_NODES * HID) / 1024, 256, 0, stream>>>(Hb0, Hb1, stat,
                                                                  ln_g + i * HID, ln_b + i * HID, Hb0);
    }

    // ---- global attention pooling ----
    gemm_mfma<<<grid256, 256, 0, stream>>>(Hb0, pwT, pool_b1, nullptr, Hb1, HID, HID, 0, nullptr, nullptr);
    pool_gate_kernel<<<N_NODES / 4, 256, 0, stream>>>(Hb1, pool_W2, pool_b2, gate);
    pool_stats_kernel<<<NG, 256, 0, stream>>>(gate, gstart);
    hipMemsetAsync(emb, 0, NG * HID * sizeof(float), stream);
    emb_accum_kernel<<<N_NODES / 32, 256, 0, stream>>>(gate, batch, Hb0, emb);

    // ---- label heads ----
    dim3 hgrid(NO, 8);
    heads_kernel<<<hgrid, 256, 0, stream>>>(emb, head_W1, head_b1, head_g, head_be,
                                            head_W2, head_b2, out);
}

// Round 6
// 640.540 us; speedup vs baseline: 3.5878x; 1.3312x over previous
//
#include <hip/hip_runtime.h>
#include <math.h>

#define N_NODES 16000
#define N_EDGES 256000
#define EPE (N_EDGES + N_NODES)
#define DIN 1280
#define HID 256
#define HEADS 8
#define CPH 32
#define NG 32
#define NO 64
#define EPSC 1e-5f
#define CAP 32      // src rows cached per chunk in gat_fused
#define XPAD 264    // xs row stride (bf16): 528 B = 16 B-aligned

typedef __bf16 bf16;
typedef __attribute__((ext_vector_type(8))) __bf16 bf16x8;
typedef __attribute__((ext_vector_type(4))) float floatx4;

typedef __attribute__((address_space(3))) unsigned int lds_u32;
typedef const __attribute__((address_space(1))) unsigned int glob_u32;

__device__ __forceinline__ float lrelu(float v) { return v > 0.f ? v : 0.2f * v; }
__device__ __forceinline__ float bflo(unsigned int u) { return __uint_as_float(u << 16); }
__device__ __forceinline__ float bfhi(unsigned int u) { return __uint_as_float(u & 0xffff0000u); }

__device__ __forceinline__ void gll16(const void* g, void* l) {
    __builtin_amdgcn_global_load_lds((glob_u32*)g, (lds_u32*)l, 16, 0, 0);
}

// ---------- weight transpose/convert ----------
__global__ void wconv_gen(const float* __restrict__ W, bf16* __restrict__ Wt, int K, int total) {
    int idx = blockIdx.x * 256 + threadIdx.x;
    if (idx >= total) return;
    int per = K * HID;
    int l = idx / per, rem = idx - l * per;
    int n = rem / K, k = rem - n * K;
    Wt[idx] = (bf16)W[(size_t)l * per + (size_t)k * HID + n];
}

__global__ void wconv_pair(const float* __restrict__ Wl, const float* __restrict__ Wr,
                           bf16* __restrict__ Wt) {
    int idx = blockIdx.x * 256 + threadIdx.x;
    int n = idx >> 8, k = idx & 255;
    float v = (n < 256) ? Wl[(size_t)k * HID + n] : Wr[(size_t)k * HID + (n - 256)];
    Wt[idx] = (bf16)v;
}

// ---------- MFMA GEMM (bf16 A) ----------
__global__ __launch_bounds__(256) void gemm_mfma(
    const bf16* __restrict__ A, const bf16* __restrict__ Bt,
    const float* __restrict__ bias, const float* __restrict__ bias2,
    bf16* __restrict__ C, int K, int ldc, int mode,
    const float* __restrict__ g, const float* __restrict__ be)
{
    __shared__ __align__(16) bf16 As[128 * 32];
    __shared__ __align__(16) bf16 Bs[128 * 32];
    const int tid = threadIdx.x;
    const int bm = blockIdx.y * 128, bn = blockIdx.x * 128;
    const int w = tid >> 6, lane = tid & 63;
    const int wm = (w & 1) * 64, wn = (w >> 1) * 64;
    const int lrow = lane & 15, lk8 = (lane >> 4) * 8;

    floatx4 acc[4][4];
#pragma unroll
    for (int i = 0; i < 4; i++)
#pragma unroll
        for (int j = 0; j < 4; j++) acc[i][j] = (floatx4){0.f, 0.f, 0.f, 0.f};

    const bf16* gA = A + (size_t)(bm + (tid >> 2)) * K + (tid & 3) * 8;
    const bf16* gB = Bt + (size_t)(bn + (tid >> 2)) * K + (tid & 3) * 8;
    bf16* lA0 = As + (size_t)(w * 64) * 8;
    bf16* lA1 = As + (size_t)(w * 64 + 256) * 8;
    bf16* lB0 = Bs + (size_t)(w * 64) * 8;
    bf16* lB1 = Bs + (size_t)(w * 64 + 256) * 8;
    const size_t rowskip = (size_t)64 * K;

    for (int k0 = 0; k0 < K; k0 += 32) {
        gll16(gA + k0, lA0);
        gll16(gA + rowskip + k0, lA1);
        gll16(gB + k0, lB0);
        gll16(gB + rowskip + k0, lB1);
        __syncthreads();
        bf16x8 af[4], bfr[4];
#pragma unroll
        for (int i = 0; i < 4; i++) af[i] = *(const bf16x8*)&As[(wm + 16 * i + lrow) * 32 + lk8];
#pragma unroll
        for (int j = 0; j < 4; j++) bfr[j] = *(const bf16x8*)&Bs[(wn + 16 * j + lrow) * 32 + lk8];
#pragma unroll
        for (int i = 0; i < 4; i++)
#pragma unroll
            for (int j = 0; j < 4; j++)
                acc[i][j] = __builtin_amdgcn_mfma_f32_16x16x32_bf16(af[i], bfr[j], acc[i][j], 0, 0, 0);
        __syncthreads();
    }

    const float inv = rsqrtf(1.f + EPSC);
#pragma unroll
    for (int j = 0; j < 4; j++) {
        int col = bn + wn + 16 * j + lrow;
        float bcol = (col < HID) ? bias[col] : bias2[col - HID];
        float gc = (mode >= 1) ? g[col] * inv : 0.f;
        float bec = (mode >= 1) ? be[col] : 0.f;
#pragma unroll
        for (int i = 0; i < 4; i++) {
            int row0 = bm + wm + 16 * i + (lane >> 4) * 4;
#pragma unroll
            for (int r = 0; r < 4; r++) {
                float z = acc[i][j][r] + bcol;
                if (mode >= 1) { z = fmaxf(z, 0.f); z = z * gc + bec; }
                if (mode == 2) z = lrelu(z);
                C[(size_t)(row0 + r) * ldc + col] = (bf16)z;
            }
        }
    }
}

// ---------- MFMA GEMM (fp32 A): K=1280 feature projection ----------
__global__ __launch_bounds__(256) void gemm_f32A(
    const float* __restrict__ A, const bf16* __restrict__ Bt,
    const float* __restrict__ bias, bf16* __restrict__ C, int K,
    const float* __restrict__ g, const float* __restrict__ be)
{
    __shared__ __align__(16) bf16 As[128 * 32];
    __shared__ __align__(16) bf16 Bs[128 * 32];
    const int tid = threadIdx.x;
    const int bm = blockIdx.y * 128, bn = blockIdx.x * 128;
    const int w = tid >> 6, lane = tid & 63;
    const int wm = (w & 1) * 64, wn = (w >> 1) * 64;
    const int lrow = lane & 15, lk8 = (lane >> 4) * 8;

    floatx4 acc[4][4];
#pragma unroll
    for (int i = 0; i < 4; i++)
#pragma unroll
        for (int j = 0; j < 4; j++) acc[i][j] = (floatx4){0.f, 0.f, 0.f, 0.f};

    const int r2 = tid >> 1, c2 = tid & 1;
    const float* gA = A + (size_t)(bm + r2) * K + c2 * 16;
    bf16* sA = As + r2 * 32 + c2 * 16;
    const bf16* gB = Bt + (size_t)(bn + (tid >> 2)) * K + (tid & 3) * 8;
    bf16* lB0 = Bs + (size_t)(w * 64) * 8;
    bf16* lB1 = Bs + (size_t)(w * 64 + 256) * 8;
    const size_t rowskipB = (size_t)64 * K;

    for (int k0 = 0; k0 < K; k0 += 32) {
        gll16(gB + k0, lB0);
        gll16(gB + rowskipB + k0, lB1);
        float4 a0 = *(const float4*)(gA + k0 + 0);
        float4 a1 = *(const float4*)(gA + k0 + 4);
        float4 a2 = *(const float4*)(gA + k0 + 8);
        float4 a3 = *(const float4*)(gA + k0 + 12);
        bf16x8 h0, h1;
        h0[0] = (bf16)a0.x; h0[1] = (bf16)a0.y; h0[2] = (bf16)a0.z; h0[3] = (bf16)a0.w;
        h0[4] = (bf16)a1.x; h0[5] = (bf16)a1.y; h0[6] = (bf16)a1.z; h0[7] = (bf16)a1.w;
        h1[0] = (bf16)a2.x; h1[1] = (bf16)a2.y; h1[2] = (bf16)a2.z; h1[3] = (bf16)a2.w;
        h1[4] = (bf16)a3.x; h1[5] = (bf16)a3.y; h1[6] = (bf16)a3.z; h1[7] = (bf16)a3.w;
        *(bf16x8*)(sA + 0) = h0;
        *(bf16x8*)(sA + 8) = h1;
        __syncthreads();
        bf16x8 af[4], bfr[4];
#pragma unroll
        for (int i = 0; i < 4; i++) af[i] = *(const bf16x8*)&As[(wm + 16 * i + lrow) * 32 + lk8];
#pragma unroll
        for (int j = 0; j < 4; j++) bfr[j] = *(const bf16x8*)&Bs[(wn + 16 * j + lrow) * 32 + lk8];
#pragma unroll
        for (int i = 0; i < 4; i++)
#pragma unroll
            for (int j = 0; j < 4; j++)
                acc[i][j] = __builtin_amdgcn_mfma_f32_16x16x32_bf16(af[i], bfr[j], acc[i][j], 0, 0, 0);
        __syncthreads();
    }

    const float inv = rsqrtf(1.f + EPSC);
#pragma unroll
    for (int j = 0; j < 4; j++) {
        int col = bn + wn + 16 * j + lrow;
        float bcol = bias[col];
        float gc = g[col] * inv;
        float bec = be[col];
#pragma unroll
        for (int i = 0; i < 4; i++) {
            int row0 = bm + wm + 16 * i + (lane >> 4) * 4;
#pragma unroll
            for (int r = 0; r < 4; r++) {
                float z = fmaxf(acc[i][j][r] + bcol, 0.f) * gc + bec;
                C[(size_t)(row0 + r) * HID + col] = (bf16)z;
            }
        }
    }
}

// ---------- CSR build ----------
__global__ void hist_kernel(const int* __restrict__ ei, int* __restrict__ cnt) {
    int e = blockIdx.x * 256 + threadIdx.x;
    if (e >= EPE) return;
    int d = (e < N_EDGES) ? ei[N_EDGES + e] : (e - N_EDGES);
    atomicAdd(&cnt[d], 1);
}

__global__ __launch_bounds__(1024) void scan_kernel(const int* __restrict__ cnt,
                                                    int* __restrict__ roff, int* __restrict__ cursor) {
    __shared__ int wsum[16];
    int t = threadIdx.x;
    int base = t * 16;
    int local[16]; int s = 0;
#pragma unroll
    for (int i = 0; i < 16; i++) {
        int idx = base + i;
        int v = (idx < N_NODES) ? cnt[idx] : 0;
        local[i] = s; s += v;
    }
    int lane = t & 63, wid = t >> 6;
    int incl = s;
    for (int o = 1; o < 64; o <<= 1) { int v = __shfl_up(incl, o); if (lane >= o) incl += v; }
    if (lane == 63) wsum[wid] = incl;
    __syncthreads();
    if (t == 0) { int a = 0; for (int k = 0; k < 16; k++) { int v = wsum[k]; wsum[k] = a; a += v; } }
    __syncthreads();
    int texcl = incl - s + wsum[wid];
#pragma unroll
    for (int i = 0; i < 16; i++) {
        int idx = base + i;
        if (idx < N_NODES) { int o = texcl + local[i]; roff[idx] = o; cursor[idx] = o; }
    }
    if (t == 1023) roff[N_NODES] = texcl + s;
}

// plain src in CSR order (self-loop rows included; GIN sum over ALL entries == h[d]+sum_orig)
__global__ void scatter_kernel(const int* __restrict__ ei, int* __restrict__ cursor,
                               int* __restrict__ esrc) {
    int e = blockIdx.x * 256 + threadIdx.x;
    if (e >= EPE) return;
    int s, d;
    if (e < N_EDGES) { s = ei[e]; d = ei[N_EDGES + e]; }
    else { s = d = e - N_EDGES; }
    int pos = atomicAdd(&cursor[d], 1);
    esrc[pos] = s;
}

// ---------- fused GATv2 v2: parallel logits + parallel online softmax ----------
__global__ __launch_bounds__(256) void gat_fused(
    const bf16* __restrict__ XLR, const int* __restrict__ roff, const int* __restrict__ esrc,
    const float* __restrict__ att, const float* __restrict__ gbias, bf16* __restrict__ out)
{
    const int d = blockIdx.x, t = threadIdx.x;
    const int beg = roff[d], deg = roff[d + 1] - beg;
    __shared__ __align__(16) bf16 xs[CAP][XPAD];
    __shared__ __align__(16) float4 xa4[8 * 16];   // (xr,att,xr,att) per channel pair
    __shared__ float llog[CAP * 8];
    __shared__ float m_s[8], s_s[8], resc[8];

    // build xr+att table (once)
    if (t < 128) {
        int hh = t >> 4, cc = t & 15;
        int c = hh * 32 + cc * 2;
        float xr0 = (float)XLR[(size_t)d * 512 + 256 + c];
        float xr1 = (float)XLR[(size_t)d * 512 + 256 + c + 1];
        xa4[hh * 16 + cc] = (float4){xr0, att[c], xr1, att[c + 1]};
    }
    if (t < 8) { m_s[t] = -INFINITY; s_s[t] = 0.f; }

    const int jj = t & 31;        // edge slot (logit phase)
    const int hh = t >> 5;        // head (logit phase); also head of channel t (accum phase)
    const int g = t >> 5, l = t & 31;  // staging groups
    float acc = 0.f;

    for (int c0 = 0; c0 < deg; c0 += CAP) {
        int cn = min(CAP, deg - c0);
        __syncthreads();   // xa4 ready (1st iter) / previous accum phase done with xs
        // stage cn src rows: 16 B per lane, conflict-free dense b128
        for (int r = g; r < cn; r += 8) {
            int s = esrc[beg + c0 + r];
            *(bf16x8*)(&xs[r][l * 8]) = *(const bf16x8*)(XLR + (size_t)s * 512 + l * 8);
        }
        __syncthreads();
        // logits: one (edge,head) pair per thread, swizzled channel order
        if (jj < cn) {
            float lg = 0.f;
#pragma unroll
            for (int cc = 0; cc < 16; cc++) {
                int ce = (cc + jj) & 15;
                unsigned int p = *(const unsigned int*)&xs[jj][hh * 32 + ce * 2];
                float4 xa = xa4[hh * 16 + ce];
                lg += lrelu(bflo(p) + xa.x) * xa.y + lrelu(bfhi(p) + xa.z) * xa.w;
            }
            llog[jj * 8 + hh] = lg;
        }
        __syncthreads();
        // parallel online-softmax update (64 threads, 8 per head)
        if (t < 64) {
            int h2 = t & 7, j0 = t >> 3;
            float mx = -INFINITY;
            for (int j = j0; j < cn; j += 8) mx = fmaxf(mx, llog[j * 8 + h2]);
            for (int o = 8; o < 64; o <<= 1) mx = fmaxf(mx, __shfl_xor(mx, o));
            float mo = m_s[h2];
            float mn = fmaxf(mo, mx);
            float ss = 0.f;
            for (int j = j0; j < cn; j += 8) {
                float e = __expf(llog[j * 8 + h2] - mn);
                llog[j * 8 + h2] = e;
                ss += e;
            }
            for (int o = 8; o < 64; o <<= 1) ss += __shfl_xor(ss, o);
            if (t < 8) {
                float r = __expf(mo - mn);
                resc[h2] = r;
                s_s[h2] = s_s[h2] * r + ss;
                m_s[h2] = mn;
            }
        }
        __syncthreads();
        // weighted accumulation from LDS cache
        acc *= resc[hh];
        for (int j = 0; j < cn; j++)
            acc += llog[j * 8 + hh] * (float)xs[j][t];
    }
    out[(size_t)d * HID + t] = (bf16)(gbias[t] + acc / (s_s[hh] + 1e-16f));
}

// ---------- GIN gather v2: u[d] = sum over ALL CSR entries of h[src] (incl self-loop) ----------
__global__ __launch_bounds__(256) void gin_gather(
    const unsigned int* __restrict__ hu, const int* __restrict__ roff,
    const int* __restrict__ esrc, unsigned int* __restrict__ uu)
{
    int d = blockIdx.x, t = threadIdx.x;
    int grp = t >> 7, c = t & 127;
    int beg = roff[d], end = roff[d + 1];
    float a0 = 0.f, a1 = 0.f;
    int p = beg + grp;
    while (p + 14 < end) {
        int s[8];
#pragma unroll
        for (int k = 0; k < 8; k++) s[k] = esrc[p + 2 * k];
        unsigned int v[8];
#pragma unroll
        for (int k = 0; k < 8; k++) v[k] = hu[(size_t)s[k] * 128 + c];
#pragma unroll
        for (int k = 0; k < 8; k++) { a0 += bflo(v[k]); a1 += bfhi(v[k]); }
        p += 16;
    }
    for (; p < end; p += 2) {
        unsigned int v = hu[(size_t)esrc[p] * 128 + c];
        a0 += bflo(v); a1 += bfhi(v);
    }
    __shared__ float plo[128], phi[128];
    if (grp) { plo[c] = a0; phi[c] = a1; }
    __syncthreads();
    if (!grp) {
        a0 += plo[c]; a1 += phi[c];
        bf16 b0 = (bf16)a0, b1 = (bf16)a1;
        unsigned int r = ((unsigned int)*(unsigned short*)&b0) |
                         (((unsigned int)*(unsigned short*)&b1) << 16);
        uu[(size_t)d * 128 + c] = r;
    }
}

// ---------- global LN ----------
__global__ void stats_kernel(const bf16* __restrict__ x, float2* __restrict__ part, int n8) {
    float s = 0.f, sq = 0.f;
    for (int i = blockIdx.x * blockDim.x + threadIdx.x; i < n8; i += gridDim.x * blockDim.x) {
        bf16x8 v = *(const bf16x8*)(x + (size_t)i * 8);
#pragma unroll
        for (int j = 0; j < 8; j++) { float f = (float)v[j]; s += f; sq += f * f; }
    }
    for (int o = 32; o > 0; o >>= 1) { s += __shfl_down(s, o); sq += __shfl_down(sq, o); }
    __shared__ float ls[4], lq[4];
    int wid = threadIdx.x >> 6, lane = threadIdx.x & 63;
    if (lane == 0) { ls[wid] = s; lq[wid] = sq; }
    __syncthreads();
    if (threadIdx.x == 0)
        part[blockIdx.x] = make_float2(ls[0] + ls[1] + ls[2] + ls[3],
                                       lq[0] + lq[1] + lq[2] + lq[3]);
}

__global__ void stats_reduce(const float2* __restrict__ part, float* __restrict__ stat) {
    int t = threadIdx.x;
    float2 v = part[t];
    float s = v.x, q = v.y;
    for (int o = 32; o > 0; o >>= 1) { s += __shfl_down(s, o); q += __shfl_down(q, o); }
    __shared__ float ls[4], lq[4];
    int wid = t >> 6, lane = t & 63;
    if (lane == 0) { ls[wid] = s; lq[wid] = q; }
    __syncthreads();
    if (t == 0) { stat[0] = ls[0] + ls[1] + ls[2] + ls[3]; stat[1] = lq[0] + lq[1] + lq[2] + lq[3]; }
}

__global__ void ln_res_kernel(const bf16* __restrict__ h, const bf16* __restrict__ r,
                              const float* __restrict__ stats, const float* __restrict__ g,
                              const float* __restrict__ b, bf16* __restrict__ out)
{
    int i = (blockIdx.x * 256 + threadIdx.x) * 4;
    const float inv_n = 1.f / (float)((size_t)N_NODES * HID);
    float mu = stats[0] * inv_n;
    float var = stats[1] * inv_n - mu * mu;
    float sd = sqrtf(fmaxf(var, 0.f));
    float rs = 1.f / (sd + EPSC);
    int ch = i & (HID - 1);
#pragma unroll
    for (int j = 0; j < 4; j++) {
        float v = ((float)h[i + j] - mu) * rs * g[ch + j] + b[ch + j] + (float)r[i + j];
        out[i + j] = (bf16)lrelu(v);
    }
}

// ---------- pooling ----------
__global__ void gbound_kernel(const int* __restrict__ batch, int* __restrict__ gstart) {
    int g = threadIdx.x;
    if (g > NG) return;
    int lo = 0, hi = N_NODES;
    while (lo < hi) { int mid = (lo + hi) >> 1; if (batch[mid] < g) lo = mid + 1; else hi = mid; }
    gstart[g] = lo;
}

__global__ __launch_bounds__(256) void pool_gate_kernel(const bf16* __restrict__ t,
    const float* __restrict__ W2, const float* __restrict__ b2, float* __restrict__ gate)
{
    int n = blockIdx.x * 4 + (threadIdx.x >> 6);
    int lane = threadIdx.x & 63;
    const bf16* p = t + (size_t)n * HID + lane * 4;
    float4 w = *(const float4*)(W2 + lane * 4);
    float s = tanhf((float)p[0]) * w.x + tanhf((float)p[1]) * w.y
            + tanhf((float)p[2]) * w.z + tanhf((float)p[3]) * w.w;
    for (int o = 32; o > 0; o >>= 1) s += __shfl_down(s, o);
    if (lane == 0) gate[n] = s + b2[0];
}

__global__ __launch_bounds__(256) void pool_stats_kernel(
    float* __restrict__ gate, const int* __restrict__ gstart)
{
    int g = blockIdx.x, t = threadIdx.x;
    int lo = gstart[g], hi = gstart[g + 1];
    __shared__ float red[256];
    float m = -INFINITY;
    for (int n = lo + t; n < hi; n += 256) m = fmaxf(m, gate[n]);
    red[t] = m; __syncthreads();
    for (int st = 128; st > 0; st >>= 1) { if (t < st) red[t] = fmaxf(red[t], red[t + st]); __syncthreads(); }
    m = red[0]; __syncthreads();
    float s = 0.f;
    for (int n = lo + t; n < hi; n += 256) s += __expf(gate[n] - m);
    red[t] = s; __syncthreads();
    for (int st = 128; st > 0; st >>= 1) { if (t < st) red[t] += red[t + st]; __syncthreads(); }
    float sinv = 1.f / (red[0] + 1e-16f);
    for (int n = lo + t; n < hi; n += 256) gate[n] = __expf(gate[n] - m) * sinv;
}

__global__ __launch_bounds__(256) void emb_accum_kernel(
    const float* __restrict__ a, const int* __restrict__ batch,
    const bf16* __restrict__ h, float* __restrict__ emb)
{
    int n0 = blockIdx.x * 32, t = threadIdx.x;
    int cur = batch[n0]; float acc = 0.f;
    for (int j = 0; j < 32; j++) {
        int n = n0 + j;
        int b = batch[n];
        if (b != cur) { atomicAdd(&emb[cur * HID + t], acc); cur = b; acc = 0.f; }
        acc += a[n] * (float)h[(size_t)n * HID + t];
    }
    atomicAdd(&emb[cur * HID + t], acc);
}

// ---------- label heads ----------
__global__ __launch_bounds__(256) void heads_kernel(
    const float* __restrict__ emb, const float* __restrict__ W1, const float* __restrict__ b1,
    const float* __restrict__ hg, const float* __restrict__ hbe, const float* __restrict__ W2,
    const float* __restrict__ b2, float* __restrict__ out)
{
    int o = blockIdx.x;
    int g0 = blockIdx.y * 4;
    int k = threadIdx.x;
    __shared__ float se[4][HID];
    __shared__ float red[256];
#pragma unroll
    for (int j = 0; j < 4; j++) se[j][k] = emb[(g0 + j) * HID + k];
    __syncthreads();
    const float* w1p = W1 + (size_t)o * HID * HID + k;
    float zb = b1[o * HID + k];
    float z0 = zb, z1 = zb, z2 = zb, z3 = zb;
#pragma unroll 8
    for (int d = 0; d < HID; d++) {
        float w = w1p[(size_t)d * HID];
        z0 = fmaf(se[0][d], w, z0);
        z1 = fmaf(se[1][d], w, z1);
        z2 = fmaf(se[2][d], w, z2);
        z3 = fmaf(se[3][d], w, z3);
    }
    const float gk = hg[o * HID + k] * rsqrtf(1.f + EPSC);
    const float bek = hbe[o * HID + k];
    const float w2 = W2[o * HID + k];
    const float b2o = b2[o];
    float zz[4] = {z0, z1, z2, z3};
#pragma unroll
    for (int j = 0; j < 4; j++) {
        float z = zz[j];
        float sil = z / (1.f + expf(-z));
        red[k] = (sil * gk + bek) * w2;
        __syncthreads();
        for (int st = 128; st > 0; st >>= 1) { if (k < st) red[k] += red[k + st]; __syncthreads(); }
        if (k == 0) out[(g0 + j) * NO + o] = red[0] + b2o;
        __syncthreads();
    }
}

extern "C" void kernel_launch(void* const* d_in, const int* in_sizes, int n_in,
                              void* d_out, int out_size, void* d_ws, size_t ws_size,
                              hipStream_t stream) {
    const float* x        = (const float*)d_in[0];
    const int*   ei       = (const int*)  d_in[1];
    const int*   batch    = (const int*)  d_in[2];
    const float* fp_W     = (const float*)d_in[3];
    const float* fp_b     = (const float*)d_in[4];
    const float* fp_g     = (const float*)d_in[5];
    const float* fp_be    = (const float*)d_in[6];
    const float* gat_Wl   = (const float*)d_in[7];
    const float* gat_bl   = (const float*)d_in[8];
    const float* gat_Wr   = (const float*)d_in[9];
    const float* gat_br   = (const float*)d_in[10];
    const float* gat_att  = (const float*)d_in[11];
    const float* gat_bias = (const float*)d_in[12];
    const float* gin_W    = (const float*)d_in[13];
    const float* gin_b    = (const float*)d_in[14];
    const float* gin_g    = (const float*)d_in[15];
    const float* gin_be   = (const float*)d_in[16];
    const float* ln_g     = (const float*)d_in[17];
    const float* ln_b     = (const float*)d_in[18];
    const float* res_W    = (const float*)d_in[19];
    const float* res_b    = (const float*)d_in[20];
    const float* pool_W1  = (const float*)d_in[21];
    const float* pool_b1  = (const float*)d_in[22];
    const float* pool_W2  = (const float*)d_in[23];
    const float* pool_b2  = (const float*)d_in[24];
    const float* head_W1  = (const float*)d_in[25];
    const float* head_b1  = (const float*)d_in[26];
    const float* head_g   = (const float*)d_in[27];
    const float* head_be  = (const float*)d_in[28];
    const float* head_W2  = (const float*)d_in[29];
    const float* head_b2  = (const float*)d_in[30];
    float* out = (float*)d_out;

    char* base = (char*)d_ws;
    size_t off = 0;
    auto alloc = [&](size_t bytes) -> char* {
        char* p = base + off; off += (bytes + 255) & ~(size_t)255; return p;
    };
    int*   esrc   = (int*)  alloc((size_t)EPE * 4);
    int*   cnt    = (int*)  alloc((size_t)N_NODES * 4);
    int*   roff   = (int*)  alloc((size_t)(N_NODES + 1) * 4);
    int*   cursor = (int*)  alloc((size_t)N_NODES * 4);
    float* gate   = (float*)alloc((size_t)N_NODES * 4);
    int*   gstart = (int*)  alloc((NG + 1) * 4);
    float* emb    = (float*)alloc(NG * HID * 4);
    float* stat   = (float*)alloc(8);
    float2* statp = (float2*)alloc(256 * 8);
    bf16*  Hb0    = (bf16*) alloc((size_t)N_NODES * HID * 2);
    bf16*  Hb1    = (bf16*) alloc((size_t)N_NODES * HID * 2);
    bf16*  XLR    = (bf16*) alloc((size_t)N_NODES * 512 * 2);
    bf16*  fpWt   = (bf16*) alloc((size_t)DIN * HID * 2);
    bf16*  wlrT0  = (bf16*) alloc((size_t)512 * HID * 2);
    bf16*  wlrT1  = (bf16*) alloc((size_t)512 * HID * 2);
    bf16*  gwT    = (bf16*) alloc((size_t)2 * HID * HID * 2);
    bf16*  rwT    = (bf16*) alloc((size_t)2 * HID * HID * 2);
    bf16*  pwT    = (bf16*) alloc((size_t)HID * HID * 2);
    bf16*  Ub     = XLR;
    bf16*  wlrT[2] = { wlrT0, wlrT1 };

    // ---- weight conversions ----
    wconv_gen<<<(DIN * HID + 255) / 256, 256, 0, stream>>>(fp_W, fpWt, DIN, DIN * HID);
    wconv_pair<<<512, 256, 0, stream>>>(gat_Wl, gat_Wr, wlrT0);
    wconv_pair<<<512, 256, 0, stream>>>(gat_Wl + HID * HID, gat_Wr + HID * HID, wlrT1);
    wconv_gen<<<512, 256, 0, stream>>>(gin_W, gwT, HID, 2 * HID * HID);
    wconv_gen<<<512, 256, 0, stream>>>(res_W, rwT, HID, 2 * HID * HID);
    wconv_gen<<<256, 256, 0, stream>>>(pool_W1, pwT, HID, HID * HID);

    // ---- CSR build ----
    hipMemsetAsync(cnt, 0, N_NODES * sizeof(int), stream);
    hist_kernel<<<(EPE + 255) / 256, 256, 0, stream>>>(ei, cnt);
    scan_kernel<<<1, 1024, 0, stream>>>(cnt, roff, cursor);
    scatter_kernel<<<(EPE + 255) / 256, 256, 0, stream>>>(ei, cursor, esrc);
    gbound_kernel<<<1, 64, 0, stream>>>(batch, gstart);

    // ---- feature projection ----
    dim3 grid256(2, 125), grid512(4, 125);
    gemm_f32A<<<grid256, 256, 0, stream>>>(x, fpWt, fp_b, Hb0, DIN, fp_g, fp_be);

    for (int i = 0; i < 2; i++) {
        gemm_mfma<<<grid512, 256, 0, stream>>>(Hb0, wlrT[i], gat_bl + i * HID, gat_br + i * HID,
                                               XLR, HID, 512, 0, nullptr, nullptr);
        gat_fused<<<N_NODES, 256, 0, stream>>>(XLR, roff, esrc, gat_att + i * HEADS * CPH,
                                               gat_bias + i * HID, Hb1);
        gin_gather<<<N_NODES, 256, 0, stream>>>((const unsigned int*)Hb1, roff, esrc,
                                                (unsigned int*)Ub);
        gemm_mfma<<<grid256, 256, 0, stream>>>(Ub, gwT + (size_t)i * HID * HID, gin_b + i * HID,
                                               nullptr, Hb0, HID, HID, 2,
                                               gin_g + i * HID, gin_be + i * HID);
        stats_kernel<<<256, 256, 0, stream>>>(Hb0, statp, (N_NODES * HID) / 8);
        stats_reduce<<<1, 256, 0, stream>>>(statp, stat);
        gemm_mfma<<<grid256, 256, 0, stream>>>(Hb0, rwT + (size_t)i * HID * HID, res_b + i * HID,
                                               nullptr, Hb1, HID, HID, 0, nullptr, nullptr);
        ln_res_kernel<<<(N_NODES * HID) / 1024, 256, 0, stream>>>(Hb0, Hb1, stat,
                                                                  ln_g + i * HID, ln_b + i * HID, Hb0);
    }

    // ---- global attention pooling ----
    gemm_mfma<<<grid256, 256, 0, stream>>>(Hb0, pwT, pool_b1, nullptr, Hb1, HID, HID, 0, nullptr, nullptr);
    pool_gate_kernel<<<N_NODES / 4, 256, 0, stream>>>(Hb1, pool_W2, pool_b2, gate);
    pool_stats_kernel<<<NG, 256, 0, stream>>>(gate, gstart);
    hipMemsetAsync(emb, 0, NG * HID * sizeof(float), stream);
    emb_accum_kernel<<<N_NODES / 32, 256, 0, stream>>>(gate, batch, Hb0, emb);

    // ---- label heads ----
    dim3 hgrid(NO, 8);
    heads_kernel<<<hgrid, 256, 0, stream>>>(emb, head_W1, head_b1, head_g, head_be,
                                            head_W2, head_b2, out);
}

// Round 7
// 630.242 us; speedup vs baseline: 3.6464x; 1.0163x over previous
//
#include <hip/hip_runtime.h>
#include <math.h>

#define N_NODES 16000
#define N_EDGES 256000
#define EPE (N_EDGES + N_NODES)
#define DIN 1280
#define HID 256
#define HEADS 8
#define CPH 32
#define NG 32
#define NO 64
#define EPSC 1e-5f
#define CAP 32      // src rows cached per chunk in gat_fused
#define XPAD 264    // xs row stride (bf16) in gat_fused
#define SPAD 40     // GEMM LDS row stride (bf16): 80 B, 16B-aligned, <=2-way conflicts

typedef __bf16 bf16;
typedef __attribute__((ext_vector_type(8))) __bf16 bf16x8;
typedef __attribute__((ext_vector_type(4))) float floatx4;

__device__ __forceinline__ float lrelu(float v) { return v > 0.f ? v : 0.2f * v; }
__device__ __forceinline__ float bflo(unsigned int u) { return __uint_as_float(u << 16); }
__device__ __forceinline__ float bfhi(unsigned int u) { return __uint_as_float(u & 0xffff0000u); }

// ---------- weight transpose/convert ----------
__global__ void wconv_gen(const float* __restrict__ W, bf16* __restrict__ Wt, int K, int total) {
    int idx = blockIdx.x * 256 + threadIdx.x;
    if (idx >= total) return;
    int per = K * HID;
    int l = idx / per, rem = idx - l * per;
    int n = rem / K, k = rem - n * K;
    Wt[idx] = (bf16)W[(size_t)l * per + (size_t)k * HID + n];
}

__global__ void wconv_pair(const float* __restrict__ Wl, const float* __restrict__ Wr,
                           bf16* __restrict__ Wt) {
    int idx = blockIdx.x * 256 + threadIdx.x;
    int n = idx >> 8, k = idx & 255;
    float v = (n < 256) ? Wl[(size_t)k * HID + n] : Wr[(size_t)k * HID + (n - 256)];
    Wt[idx] = (bf16)v;
}

// ---------- MFMA GEMM 64x64 tile, reg-staged double-buffer ----------
// C[M,ncols] = A[M,K] @ Bt[ncols,K]^T ; mode 0:+bias 1:+bias,relu,bn 2:+..,leaky
__global__ __launch_bounds__(256) void gemm64(
    const bf16* __restrict__ A, const bf16* __restrict__ Bt,
    const float* __restrict__ bias, const float* __restrict__ bias2,
    bf16* __restrict__ C, int K, int ldc, int mode,
    const float* __restrict__ g, const float* __restrict__ be)
{
    __shared__ __align__(16) bf16 As[2][64 * SPAD];
    __shared__ __align__(16) bf16 Bs[2][64 * SPAD];
    const int tid = threadIdx.x;
    const int bm = blockIdx.y * 64, bn = blockIdx.x * 64;
    const int w = tid >> 6, lane = tid & 63;
    const int wm = w * 16;
    const int lrow = lane & 15, lk8 = (lane >> 4) * 8;
    const int row = tid >> 2, k8 = (tid & 3) * 8;

    const bf16* gA = A + (size_t)(bm + row) * K + k8;
    const bf16* gB = Bt + (size_t)(bn + row) * K + k8;

    floatx4 acc[4];
#pragma unroll
    for (int j = 0; j < 4; j++) acc[j] = (floatx4){0.f, 0.f, 0.f, 0.f};

    const int nk = K >> 5;
    bf16x8 ra = *(const bf16x8*)gA;
    bf16x8 rb = *(const bf16x8*)gB;

    for (int it = 0; it < nk; ++it) {
        int p = it & 1;
        *(bf16x8*)&As[p][row * SPAD + k8] = ra;
        *(bf16x8*)&Bs[p][row * SPAD + k8] = rb;
        __syncthreads();
        if (it + 1 < nk) {
            ra = *(const bf16x8*)(gA + (it + 1) * 32);
            rb = *(const bf16x8*)(gB + (it + 1) * 32);
        }
        bf16x8 af = *(const bf16x8*)&As[p][(wm + lrow) * SPAD + lk8];
        bf16x8 bfr[4];
#pragma unroll
        for (int j = 0; j < 4; j++) bfr[j] = *(const bf16x8*)&Bs[p][(16 * j + lrow) * SPAD + lk8];
#pragma unroll
        for (int j = 0; j < 4; j++)
            acc[j] = __builtin_amdgcn_mfma_f32_16x16x32_bf16(af, bfr[j], acc[j], 0, 0, 0);
        __syncthreads();
    }

    const float inv = rsqrtf(1.f + EPSC);
    const int row0 = bm + wm + (lane >> 4) * 4;
#pragma unroll
    for (int j = 0; j < 4; j++) {
        int col = bn + 16 * j + lrow;
        float bcol = (col < HID) ? bias[col] : bias2[col - HID];
        float gc = (mode >= 1) ? g[col] * inv : 0.f;
        float bec = (mode >= 1) ? be[col] : 0.f;
#pragma unroll
        for (int r = 0; r < 4; r++) {
            float z = acc[j][r] + bcol;
            if (mode >= 1) { z = fmaxf(z, 0.f); z = z * gc + bec; }
            if (mode == 2) z = lrelu(z);
            C[(size_t)(row0 + r) * ldc + col] = (bf16)z;
        }
    }
}

// ---------- MFMA GEMM (fp32 A), 128x128 tile, reg-staged double-buffer: K=1280 ----------
__global__ __launch_bounds__(256) void gemm_f32A(
    const float* __restrict__ A, const bf16* __restrict__ Bt,
    const float* __restrict__ bias, bf16* __restrict__ C, int K,
    const float* __restrict__ g, const float* __restrict__ be)
{
    __shared__ __align__(16) bf16 As[2][128 * SPAD];
    __shared__ __align__(16) bf16 Bs[2][128 * SPAD];
    const int tid = threadIdx.x;
    const int bm = blockIdx.y * 128, bn = blockIdx.x * 128;
    const int w = tid >> 6, lane = tid & 63;
    const int wm = (w & 1) * 64, wn = (w >> 1) * 64;
    const int lrow = lane & 15, lk8 = (lane >> 4) * 8;

    floatx4 acc[4][4];
#pragma unroll
    for (int i = 0; i < 4; i++)
#pragma unroll
        for (int j = 0; j < 4; j++) acc[i][j] = (floatx4){0.f, 0.f, 0.f, 0.f};

    // A: 128 rows x 32 fp32 per iter; thread: row r2, half c2 (16 floats)
    const int r2 = tid >> 1, c2 = tid & 1;
    const float* gA = A + (size_t)(bm + r2) * K + c2 * 16;
    // B: 128 rows x 32 bf16; thread: row r2, half c2 (16 bf16)
    const bf16* gB = Bt + (size_t)(bn + r2) * K + c2 * 16;

    const int nk = K >> 5;
    float4 a0 = *(const float4*)(gA + 0);
    float4 a1 = *(const float4*)(gA + 4);
    float4 a2 = *(const float4*)(gA + 8);
    float4 a3 = *(const float4*)(gA + 12);
    bf16x8 rb0 = *(const bf16x8*)(gB + 0);
    bf16x8 rb1 = *(const bf16x8*)(gB + 8);

    for (int it = 0; it < nk; ++it) {
        int p = it & 1;
        bf16x8 h0, h1;
        h0[0] = (bf16)a0.x; h0[1] = (bf16)a0.y; h0[2] = (bf16)a0.z; h0[3] = (bf16)a0.w;
        h0[4] = (bf16)a1.x; h0[5] = (bf16)a1.y; h0[6] = (bf16)a1.z; h0[7] = (bf16)a1.w;
        h1[0] = (bf16)a2.x; h1[1] = (bf16)a2.y; h1[2] = (bf16)a2.z; h1[3] = (bf16)a2.w;
        h1[4] = (bf16)a3.x; h1[5] = (bf16)a3.y; h1[6] = (bf16)a3.z; h1[7] = (bf16)a3.w;
        *(bf16x8*)&As[p][r2 * SPAD + c2 * 16 + 0] = h0;
        *(bf16x8*)&As[p][r2 * SPAD + c2 * 16 + 8] = h1;
        *(bf16x8*)&Bs[p][r2 * SPAD + c2 * 16 + 0] = rb0;
        *(bf16x8*)&Bs[p][r2 * SPAD + c2 * 16 + 8] = rb1;
        __syncthreads();
        if (it + 1 < nk) {
            const float* pa = gA + (it + 1) * 32;
            a0 = *(const float4*)(pa + 0);
            a1 = *(const float4*)(pa + 4);
            a2 = *(const float4*)(pa + 8);
            a3 = *(const float4*)(pa + 12);
            const bf16* pb = gB + (it + 1) * 32;
            rb0 = *(const bf16x8*)(pb + 0);
            rb1 = *(const bf16x8*)(pb + 8);
        }
        bf16x8 af[4], bfr[4];
#pragma unroll
        for (int i = 0; i < 4; i++) af[i] = *(const bf16x8*)&As[p][(wm + 16 * i + lrow) * SPAD + lk8];
#pragma unroll
        for (int j = 0; j < 4; j++) bfr[j] = *(const bf16x8*)&Bs[p][(wn + 16 * j + lrow) * SPAD + lk8];
#pragma unroll
        for (int i = 0; i < 4; i++)
#pragma unroll
            for (int j = 0; j < 4; j++)
                acc[i][j] = __builtin_amdgcn_mfma_f32_16x16x32_bf16(af[i], bfr[j], acc[i][j], 0, 0, 0);
        __syncthreads();
    }

    const float inv = rsqrtf(1.f + EPSC);
#pragma unroll
    for (int j = 0; j < 4; j++) {
        int col = bn + wn + 16 * j + lrow;
        float bcol = bias[col];
        float gc = g[col] * inv;
        float bec = be[col];
#pragma unroll
        for (int i = 0; i < 4; i++) {
            int row0 = bm + wm + 16 * i + (lane >> 4) * 4;
#pragma unroll
            for (int r = 0; r < 4; r++) {
                float z = fmaxf(acc[i][j][r] + bcol, 0.f) * gc + bec;
                C[(size_t)(row0 + r) * HID + col] = (bf16)z;
            }
        }
    }
}

// ---------- CSR build ----------
__global__ void hist_kernel(const int* __restrict__ ei, int* __restrict__ cnt) {
    int e = blockIdx.x * 256 + threadIdx.x;
    if (e >= EPE) return;
    int d = (e < N_EDGES) ? ei[N_EDGES + e] : (e - N_EDGES);
    atomicAdd(&cnt[d], 1);
}

__global__ __launch_bounds__(1024) void scan_kernel(const int* __restrict__ cnt,
                                                    int* __restrict__ roff, int* __restrict__ cursor) {
    __shared__ int wsum[16];
    int t = threadIdx.x;
    int base = t * 16;
    int local[16]; int s = 0;
#pragma unroll
    for (int i = 0; i < 16; i++) {
        int idx = base + i;
        int v = (idx < N_NODES) ? cnt[idx] : 0;
        local[i] = s; s += v;
    }
    int lane = t & 63, wid = t >> 6;
    int incl = s;
    for (int o = 1; o < 64; o <<= 1) { int v = __shfl_up(incl, o); if (lane >= o) incl += v; }
    if (lane == 63) wsum[wid] = incl;
    __syncthreads();
    if (t == 0) { int a = 0; for (int k = 0; k < 16; k++) { int v = wsum[k]; wsum[k] = a; a += v; } }
    __syncthreads();
    int texcl = incl - s + wsum[wid];
#pragma unroll
    for (int i = 0; i < 16; i++) {
        int idx = base + i;
        if (idx < N_NODES) { int o = texcl + local[i]; roff[idx] = o; cursor[idx] = o; }
    }
    if (t == 1023) roff[N_NODES] = texcl + s;
}

__global__ void scatter_kernel(const int* __restrict__ ei, int* __restrict__ cursor,
                               int* __restrict__ esrc) {
    int e = blockIdx.x * 256 + threadIdx.x;
    if (e >= EPE) return;
    int s, d;
    if (e < N_EDGES) { s = ei[e]; d = ei[N_EDGES + e]; }
    else { s = d = e - N_EDGES; }
    int pos = atomicAdd(&cursor[d], 1);
    esrc[pos] = s;
}

// ---------- fused GATv2: parallel logits + parallel online softmax ----------
__global__ __launch_bounds__(256) void gat_fused(
    const bf16* __restrict__ XLR, const int* __restrict__ roff, const int* __restrict__ esrc,
    const float* __restrict__ att, const float* __restrict__ gbias, bf16* __restrict__ out)
{
    const int d = blockIdx.x, t = threadIdx.x;
    const int beg = roff[d], deg = roff[d + 1] - beg;
    __shared__ __align__(16) bf16 xs[CAP][XPAD];
    __shared__ __align__(16) float4 xa4[8 * 16];
    __shared__ float llog[CAP * 8];
    __shared__ float m_s[8], s_s[8], resc[8];

    if (t < 128) {
        int hh = t >> 4, cc = t & 15;
        int c = hh * 32 + cc * 2;
        float xr0 = (float)XLR[(size_t)d * 512 + 256 + c];
        float xr1 = (float)XLR[(size_t)d * 512 + 256 + c + 1];
        xa4[hh * 16 + cc] = (float4){xr0, att[c], xr1, att[c + 1]};
    }
    if (t < 8) { m_s[t] = -INFINITY; s_s[t] = 0.f; }

    const int jj = t & 31;
    const int hh = t >> 5;
    const int g = t >> 5, l = t & 31;
    float acc = 0.f;

    for (int c0 = 0; c0 < deg; c0 += CAP) {
        int cn = min(CAP, deg - c0);
        __syncthreads();
        for (int r = g; r < cn; r += 8) {
            int s = esrc[beg + c0 + r];
            *(bf16x8*)(&xs[r][l * 8]) = *(const bf16x8*)(XLR + (size_t)s * 512 + l * 8);
        }
        __syncthreads();
        if (jj < cn) {
            float lg = 0.f;
#pragma unroll
            for (int cc = 0; cc < 16; cc++) {
                int ce = (cc + jj) & 15;
                unsigned int p = *(const unsigned int*)&xs[jj][hh * 32 + ce * 2];
                float4 xa = xa4[hh * 16 + ce];
                lg += lrelu(bflo(p) + xa.x) * xa.y + lrelu(bfhi(p) + xa.z) * xa.w;
            }
            llog[jj * 8 + hh] = lg;
        }
        __syncthreads();
        if (t < 64) {
            int h2 = t & 7, j0 = t >> 3;
            float mx = -INFINITY;
            for (int j = j0; j < cn; j += 8) mx = fmaxf(mx, llog[j * 8 + h2]);
            for (int o = 8; o < 64; o <<= 1) mx = fmaxf(mx, __shfl_xor(mx, o));
            float mo = m_s[h2];
            float mn = fmaxf(mo, mx);
            float ss = 0.f;
            for (int j = j0; j < cn; j += 8) {
                float e = __expf(llog[j * 8 + h2] - mn);
                llog[j * 8 + h2] = e;
                ss += e;
            }
            for (int o = 8; o < 64; o <<= 1) ss += __shfl_xor(ss, o);
            if (t < 8) {
                float r = __expf(mo - mn);
                resc[h2] = r;
                s_s[h2] = s_s[h2] * r + ss;
                m_s[h2] = mn;
            }
        }
        __syncthreads();
        acc *= resc[hh];
        for (int j = 0; j < cn; j++)
            acc += llog[j * 8 + hh] * (float)xs[j][t];
    }
    out[(size_t)d * HID + t] = (bf16)(gbias[t] + acc / (s_s[hh] + 1e-16f));
}

// ---------- GIN gather: u[d] = sum over ALL CSR entries of h[src] ----------
__global__ __launch_bounds__(256) void gin_gather(
    const unsigned int* __restrict__ hu, const int* __restrict__ roff,
    const int* __restrict__ esrc, unsigned int* __restrict__ uu)
{
    int d = blockIdx.x, t = threadIdx.x;
    int grp = t >> 7, c = t & 127;
    int beg = roff[d], end = roff[d + 1];
    float a0 = 0.f, a1 = 0.f;
    int p = beg + grp;
    while (p + 14 < end) {
        int s[8];
#pragma unroll
        for (int k = 0; k < 8; k++) s[k] = esrc[p + 2 * k];
        unsigned int v[8];
#pragma unroll
        for (int k = 0; k < 8; k++) v[k] = hu[(size_t)s[k] * 128 + c];
#pragma unroll
        for (int k = 0; k < 8; k++) { a0 += bflo(v[k]); a1 += bfhi(v[k]); }
        p += 16;
    }
    for (; p < end; p += 2) {
        unsigned int v = hu[(size_t)esrc[p] * 128 + c];
        a0 += bflo(v); a1 += bfhi(v);
    }
    __shared__ float plo[128], phi[128];
    if (grp) { plo[c] = a0; phi[c] = a1; }
    __syncthreads();
    if (!grp) {
        a0 += plo[c]; a1 += phi[c];
        bf16 b0 = (bf16)a0, b1 = (bf16)a1;
        unsigned int r = ((unsigned int)*(unsigned short*)&b0) |
                         (((unsigned int)*(unsigned short*)&b1) << 16);
        uu[(size_t)d * 128 + c] = r;
    }
}

// ---------- global LN ----------
__global__ void stats_kernel(const bf16* __restrict__ x, float2* __restrict__ part, int n8) {
    float s = 0.f, sq = 0.f;
    for (int i = blockIdx.x * blockDim.x + threadIdx.x; i < n8; i += gridDim.x * blockDim.x) {
        bf16x8 v = *(const bf16x8*)(x + (size_t)i * 8);
#pragma unroll
        for (int j = 0; j < 8; j++) { float f = (float)v[j]; s += f; sq += f * f; }
    }
    for (int o = 32; o > 0; o >>= 1) { s += __shfl_down(s, o); sq += __shfl_down(sq, o); }
    __shared__ float ls[4], lq[4];
    int wid = threadIdx.x >> 6, lane = threadIdx.x & 63;
    if (lane == 0) { ls[wid] = s; lq[wid] = sq; }
    __syncthreads();
    if (threadIdx.x == 0)
        part[blockIdx.x] = make_float2(ls[0] + ls[1] + ls[2] + ls[3],
                                       lq[0] + lq[1] + lq[2] + lq[3]);
}

__global__ void stats_reduce(const float2* __restrict__ part, float* __restrict__ stat) {
    int t = threadIdx.x;
    float2 v = part[t];
    float s = v.x, q = v.y;
    for (int o = 32; o > 0; o >>= 1) { s += __shfl_down(s, o); q += __shfl_down(q, o); }
    __shared__ float ls[4], lq[4];
    int wid = t >> 6, lane = t & 63;
    if (lane == 0) { ls[wid] = s; lq[wid] = q; }
    __syncthreads();
    if (t == 0) { stat[0] = ls[0] + ls[1] + ls[2] + ls[3]; stat[1] = lq[0] + lq[1] + lq[2] + lq[3]; }
}

__global__ void ln_res_kernel(const bf16* __restrict__ h, const bf16* __restrict__ r,
                              const float* __restrict__ stats, const float* __restrict__ g,
                              const float* __restrict__ b, bf16* __restrict__ out)
{
    int i = (blockIdx.x * 256 + threadIdx.x) * 4;
    const float inv_n = 1.f / (float)((size_t)N_NODES * HID);
    float mu = stats[0] * inv_n;
    float var = stats[1] * inv_n - mu * mu;
    float sd = sqrtf(fmaxf(var, 0.f));
    float rs = 1.f / (sd + EPSC);
    int ch = i & (HID - 1);
#pragma unroll
    for (int j = 0; j < 4; j++) {
        float v = ((float)h[i + j] - mu) * rs * g[ch + j] + b[ch + j] + (float)r[i + j];
        out[i + j] = (bf16)lrelu(v);
    }
}

// ---------- pooling ----------
__global__ void gbound_kernel(const int* __restrict__ batch, int* __restrict__ gstart) {
    int g = threadIdx.x;
    if (g > NG) return;
    int lo = 0, hi = N_NODES;
    while (lo < hi) { int mid = (lo + hi) >> 1; if (batch[mid] < g) lo = mid + 1; else hi = mid; }
    gstart[g] = lo;
}

__global__ __launch_bounds__(256) void pool_gate_kernel(const bf16* __restrict__ t,
    const float* __restrict__ W2, const float* __restrict__ b2, float* __restrict__ gate)
{
    int n = blockIdx.x * 4 + (threadIdx.x >> 6);
    int lane = threadIdx.x & 63;
    const bf16* p = t + (size_t)n * HID + lane * 4;
    float4 w = *(const float4*)(W2 + lane * 4);
    float s = tanhf((float)p[0]) * w.x + tanhf((float)p[1]) * w.y
            + tanhf((float)p[2]) * w.z + tanhf((float)p[3]) * w.w;
    for (int o = 32; o > 0; o >>= 1) s += __shfl_down(s, o);
    if (lane == 0) gate[n] = s + b2[0];
}

__global__ __launch_bounds__(256) void pool_stats_kernel(
    float* __restrict__ gate, const int* __restrict__ gstart)
{
    int g = blockIdx.x, t = threadIdx.x;
    int lo = gstart[g], hi = gstart[g + 1];
    __shared__ float red[256];
    float m = -INFINITY;
    for (int n = lo + t; n < hi; n += 256) m = fmaxf(m, gate[n]);
    red[t] = m; __syncthreads();
    for (int st = 128; st > 0; st >>= 1) { if (t < st) red[t] = fmaxf(red[t], red[t + st]); __syncthreads(); }
    m = red[0]; __syncthreads();
    float s = 0.f;
    for (int n = lo + t; n < hi; n += 256) s += __expf(gate[n] - m);
    red[t] = s; __syncthreads();
    for (int st = 128; st > 0; st >>= 1) { if (t < st) red[t] += red[t + st]; __syncthreads(); }
    float sinv = 1.f / (red[0] + 1e-16f);
    for (int n = lo + t; n < hi; n += 256) gate[n] = __expf(gate[n] - m) * sinv;
}

__global__ __launch_bounds__(256) void emb_accum_kernel(
    const float* __restrict__ a, const int* __restrict__ batch,
    const bf16* __restrict__ h, float* __restrict__ emb)
{
    int n0 = blockIdx.x * 32, t = threadIdx.x;
    int cur = batch[n0]; float acc = 0.f;
    for (int j = 0; j < 32; j++) {
        int n = n0 + j;
        int b = batch[n];
        if (b != cur) { atomicAdd(&emb[cur * HID + t], acc); cur = b; acc = 0.f; }
        acc += a[n] * (float)h[(size_t)n * HID + t];
    }
    atomicAdd(&emb[cur * HID + t], acc);
}

// ---------- label heads ----------
__global__ __launch_bounds__(256) void heads_kernel(
    const float* __restrict__ emb, const float* __restrict__ W1, const float* __restrict__ b1,
    const float* __restrict__ hg, const float* __restrict__ hbe, const float* __restrict__ W2,
    const float* __restrict__ b2, float* __restrict__ out)
{
    int o = blockIdx.x;
    int g0 = blockIdx.y * 4;
    int k = threadIdx.x;
    __shared__ float se[4][HID];
    __shared__ float red[256];
#pragma unroll
    for (int j = 0; j < 4; j++) se[j][k] = emb[(g0 + j) * HID + k];
    __syncthreads();
    const float* w1p = W1 + (size_t)o * HID * HID + k;
    float zb = b1[o * HID + k];
    float z0 = zb, z1 = zb, z2 = zb, z3 = zb;
#pragma unroll 8
    for (int d = 0; d < HID; d++) {
        float w = w1p[(size_t)d * HID];
        z0 = fmaf(se[0][d], w, z0);
        z1 = fmaf(se[1][d], w, z1);
        z2 = fmaf(se[2][d], w, z2);
        z3 = fmaf(se[3][d], w, z3);
    }
    const float gk = hg[o * HID + k] * rsqrtf(1.f + EPSC);
    const float bek = hbe[o * HID + k];
    const float w2 = W2[o * HID + k];
    const float b2o = b2[o];
    float zz[4] = {z0, z1, z2, z3};
#pragma unroll
    for (int j = 0; j < 4; j++) {
        float z = zz[j];
        float sil = z / (1.f + expf(-z));
        red[k] = (sil * gk + bek) * w2;
        __syncthreads();
        for (int st = 128; st > 0; st >>= 1) { if (k < st) red[k] += red[k + st]; __syncthreads(); }
        if (k == 0) out[(g0 + j) * NO + o] = red[0] + b2o;
        __syncthreads();
    }
}

extern "C" void kernel_launch(void* const* d_in, const int* in_sizes, int n_in,
                              void* d_out, int out_size, void* d_ws, size_t ws_size,
                              hipStream_t stream) {
    const float* x        = (const float*)d_in[0];
    const int*   ei       = (const int*)  d_in[1];
    const int*   batch    = (const int*)  d_in[2];
    const float* fp_W     = (const float*)d_in[3];
    const float* fp_b     = (const float*)d_in[4];
    const float* fp_g     = (const float*)d_in[5];
    const float* fp_be    = (const float*)d_in[6];
    const float* gat_Wl   = (const float*)d_in[7];
    const float* gat_bl   = (const float*)d_in[8];
    const float* gat_Wr   = (const float*)d_in[9];
    const float* gat_br   = (const float*)d_in[10];
    const float* gat_att  = (const float*)d_in[11];
    const float* gat_bias = (const float*)d_in[12];
    const float* gin_W    = (const float*)d_in[13];
    const float* gin_b    = (const float*)d_in[14];
    const float* gin_g    = (const float*)d_in[15];
    const float* gin_be   = (const float*)d_in[16];
    const float* ln_g     = (const float*)d_in[17];
    const float* ln_b     = (const float*)d_in[18];
    const float* res_W    = (const float*)d_in[19];
    const float* res_b    = (const float*)d_in[20];
    const float* pool_W1  = (const float*)d_in[21];
    const float* pool_b1  = (const float*)d_in[22];
    const float* pool_W2  = (const float*)d_in[23];
    const float* pool_b2  = (const float*)d_in[24];
    const float* head_W1  = (const float*)d_in[25];
    const float* head_b1  = (const float*)d_in[26];
    const float* head_g   = (const float*)d_in[27];
    const float* head_be  = (const float*)d_in[28];
    const float* head_W2  = (const float*)d_in[29];
    const float* head_b2  = (const float*)d_in[30];
    float* out = (float*)d_out;

    char* base = (char*)d_ws;
    size_t off = 0;
    auto alloc = [&](size_t bytes) -> char* {
        char* p = base + off; off += (bytes + 255) & ~(size_t)255; return p;
    };
    int*   esrc   = (int*)  alloc((size_t)EPE * 4);
    int*   cnt    = (int*)  alloc((size_t)N_NODES * 4);
    int*   roff   = (int*)  alloc((size_t)(N_NODES + 1) * 4);
    int*   cursor = (int*)  alloc((size_t)N_NODES * 4);
    float* gate   = (float*)alloc((size_t)N_NODES * 4);
    int*   gstart = (int*)  alloc((NG + 1) * 4);
    float* emb    = (float*)alloc(NG * HID * 4);
    float* stat   = (float*)alloc(8);
    float2* statp = (float2*)alloc(256 * 8);
    bf16*  Hb0    = (bf16*) alloc((size_t)N_NODES * HID * 2);
    bf16*  Hb1    = (bf16*) alloc((size_t)N_NODES * HID * 2);
    bf16*  XLR    = (bf16*) alloc((size_t)N_NODES * 512 * 2);
    bf16*  fpWt   = (bf16*) alloc((size_t)DIN * HID * 2);
    bf16*  wlrT0  = (bf16*) alloc((size_t)512 * HID * 2);
    bf16*  wlrT1  = (bf16*) alloc((size_t)512 * HID * 2);
    bf16*  gwT    = (bf16*) alloc((size_t)2 * HID * HID * 2);
    bf16*  rwT    = (bf16*) alloc((size_t)2 * HID * HID * 2);
    bf16*  pwT    = (bf16*) alloc((size_t)HID * HID * 2);
    bf16*  Ub     = XLR;
    bf16*  wlrT[2] = { wlrT0, wlrT1 };

    // ---- weight conversions ----
    wconv_gen<<<(DIN * HID + 255) / 256, 256, 0, stream>>>(fp_W, fpWt, DIN, DIN * HID);
    wconv_pair<<<512, 256, 0, stream>>>(gat_Wl, gat_Wr, wlrT0);
    wconv_pair<<<512, 256, 0, stream>>>(gat_Wl + HID * HID, gat_Wr + HID * HID, wlrT1);
    wconv_gen<<<512, 256, 0, stream>>>(gin_W, gwT, HID, 2 * HID * HID);
    wconv_gen<<<512, 256, 0, stream>>>(res_W, rwT, HID, 2 * HID * HID);
    wconv_gen<<<256, 256, 0, stream>>>(pool_W1, pwT, HID, HID * HID);

    // ---- CSR build ----
    hipMemsetAsync(cnt, 0, N_NODES * sizeof(int), stream);
    hist_kernel<<<(EPE + 255) / 256, 256, 0, stream>>>(ei, cnt);
    scan_kernel<<<1, 1024, 0, stream>>>(cnt, roff, cursor);
    scatter_kernel<<<(EPE + 255) / 256, 256, 0, stream>>>(ei, cursor, esrc);
    gbound_kernel<<<1, 64, 0, stream>>>(batch, gstart);

    // ---- feature projection ----
    dim3 gridF(2, 125);          // 128x128 tiles
    dim3 g64_256(4, 250);        // 64x64 tiles, 256 cols
    dim3 g64_512(8, 250);        // 64x64 tiles, 512 cols
    gemm_f32A<<<gridF, 256, 0, stream>>>(x, fpWt, fp_b, Hb0, DIN, fp_g, fp_be);

    for (int i = 0; i < 2; i++) {
        gemm64<<<g64_512, 256, 0, stream>>>(Hb0, wlrT[i], gat_bl + i * HID, gat_br + i * HID,
                                            XLR, HID, 512, 0, nullptr, nullptr);
        gat_fused<<<N_NODES, 256, 0, stream>>>(XLR, roff, esrc, gat_att + i * HEADS * CPH,
                                               gat_bias + i * HID, Hb1);
        gin_gather<<<N_NODES, 256, 0, stream>>>((const unsigned int*)Hb1, roff, esrc,
                                                (unsigned int*)Ub);
        gemm64<<<g64_256, 256, 0, stream>>>(Ub, gwT + (size_t)i * HID * HID, gin_b + i * HID,
                                            nullptr, Hb0, HID, HID, 2,
                                            gin_g + i * HID, gin_be + i * HID);
        stats_kernel<<<256, 256, 0, stream>>>(Hb0, statp, (N_NODES * HID) / 8);
        stats_reduce<<<1, 256, 0, stream>>>(statp, stat);
        gemm64<<<g64_256, 256, 0, stream>>>(Hb0, rwT + (size_t)i * HID * HID, res_b + i * HID,
                                            nullptr, Hb1, HID, HID, 0, nullptr, nullptr);
        ln_res_kernel<<<(N_NODES * HID) / 1024, 256, 0, stream>>>(Hb0, Hb1, stat,
                                                                  ln_g + i * HID, ln_b + i * HID, Hb0);
    }

    // ---- global attention pooling ----
    gemm64<<<g64_256, 256, 0, stream>>>(Hb0, pwT, pool_b1, nullptr, Hb1, HID, HID, 0, nullptr, nullptr);
    pool_gate_kernel<<<N_NODES / 4, 256, 0, stream>>>(Hb1, pool_W2, pool_b2, gate);
    pool_stats_kernel<<<NG, 256, 0, stream>>>(gate, gstart);
    hipMemsetAsync(emb, 0, NG * HID * sizeof(float), stream);
    emb_accum_kernel<<<N_NODES / 32, 256, 0, stream>>>(gate, batch, Hb0, emb);

    // ---- label heads ----
    dim3 hgrid(NO, 8);
    heads_kernel<<<hgrid, 256, 0, stream>>>(emb, head_W1, head_b1, head_g, head_be,
                                            head_W2, head_b2, out);
}

// Round 8
// 608.398 us; speedup vs baseline: 3.7773x; 1.0359x over previous
//
#include <hip/hip_runtime.h>
#include <math.h>

#define N_NODES 16000
#define N_EDGES 256000
#define EPE (N_EDGES + N_NODES)
#define DIN 1280
#define HID 256
#define HEADS 8
#define CPH 32
#define NG 32
#define NO 64
#define EPSC 1e-5f
#define CAP 32      // src rows cached per chunk in gat_fused
#define XPAD 264    // xs row stride (bf16) in gat_fused
#define SPAD 40     // GEMM LDS row stride (bf16): 80 B, 16B-aligned

typedef __bf16 bf16;
typedef __attribute__((ext_vector_type(8))) __bf16 bf16x8;
typedef __attribute__((ext_vector_type(4))) float floatx4;

__device__ __forceinline__ float lrelu(float v) { return v > 0.f ? v : 0.2f * v; }
__device__ __forceinline__ float bflo(unsigned int u) { return __uint_as_float(u << 16); }
__device__ __forceinline__ float bfhi(unsigned int u) { return __uint_as_float(u & 0xffff0000u); }

// ---------- weight transpose/convert ----------
__global__ void wconv_gen(const float* __restrict__ W, bf16* __restrict__ Wt, int K, int total) {
    int idx = blockIdx.x * 256 + threadIdx.x;
    if (idx >= total) return;
    int per = K * HID;
    int l = idx / per, rem = idx - l * per;
    int n = rem / K, k = rem - n * K;
    Wt[idx] = (bf16)W[(size_t)l * per + (size_t)k * HID + n];
}

__global__ void wconv_pair(const float* __restrict__ Wl, const float* __restrict__ Wr,
                           bf16* __restrict__ Wt) {
    int idx = blockIdx.x * 256 + threadIdx.x;
    int n = idx >> 8, k = idx & 255;
    float v = (n < 256) ? Wl[(size_t)k * HID + n] : Wr[(size_t)k * HID + (n - 256)];
    Wt[idx] = (bf16)v;
}

// ---------- MFMA GEMM 64x64 tile, single barrier/iter, reg prefetch ----------
__global__ __launch_bounds__(256) void gemm64(
    const bf16* __restrict__ A, const bf16* __restrict__ Bt,
    const float* __restrict__ bias, const float* __restrict__ bias2,
    bf16* __restrict__ C, int K, int ldc, int mode,
    const float* __restrict__ g, const float* __restrict__ be)
{
    __shared__ __align__(16) bf16 As[2][64 * SPAD];
    __shared__ __align__(16) bf16 Bs[2][64 * SPAD];
    const int tid = threadIdx.x;
    const int bm = blockIdx.y * 64, bn = blockIdx.x * 64;
    const int w = tid >> 6, lane = tid & 63;
    const int wm = w * 16;
    const int lrow = lane & 15, lk8 = (lane >> 4) * 8;
    const int row = tid >> 2, k8 = (tid & 3) * 8;

    const bf16* gA = A + (size_t)(bm + row) * K + k8;
    const bf16* gB = Bt + (size_t)(bn + row) * K + k8;

    floatx4 acc[4];
#pragma unroll
    for (int j = 0; j < 4; j++) acc[j] = (floatx4){0.f, 0.f, 0.f, 0.f};

    const int nk = K >> 5;
    bf16x8 ra = *(const bf16x8*)gA;
    bf16x8 rb = *(const bf16x8*)gB;

    for (int it = 0; it < nk; ++it) {
        int p = it & 1;
        *(bf16x8*)&As[p][row * SPAD + k8] = ra;
        *(bf16x8*)&Bs[p][row * SPAD + k8] = rb;
        __syncthreads();
        if (it + 1 < nk) {
            ra = *(const bf16x8*)(gA + (it + 1) * 32);
            rb = *(const bf16x8*)(gB + (it + 1) * 32);
        }
        bf16x8 af = *(const bf16x8*)&As[p][(wm + lrow) * SPAD + lk8];
        bf16x8 bfr[4];
#pragma unroll
        for (int j = 0; j < 4; j++) bfr[j] = *(const bf16x8*)&Bs[p][(16 * j + lrow) * SPAD + lk8];
#pragma unroll
        for (int j = 0; j < 4; j++)
            acc[j] = __builtin_amdgcn_mfma_f32_16x16x32_bf16(af, bfr[j], acc[j], 0, 0, 0);
        // no trailing barrier: dbuf + next iteration's barrier orders reuse of this buffer
    }

    const float inv = rsqrtf(1.f + EPSC);
    const int row0 = bm + wm + (lane >> 4) * 4;
#pragma unroll
    for (int j = 0; j < 4; j++) {
        int col = bn + 16 * j + lrow;
        float bcol = (col < HID) ? bias[col] : bias2[col - HID];
        float gc = (mode >= 1) ? g[col] * inv : 0.f;
        float bec = (mode >= 1) ? be[col] : 0.f;
#pragma unroll
        for (int r = 0; r < 4; r++) {
            float z = acc[j][r] + bcol;
            if (mode >= 1) { z = fmaxf(z, 0.f); z = z * gc + bec; }
            if (mode == 2) z = lrelu(z);
            C[(size_t)(row0 + r) * ldc + col] = (bf16)z;
        }
    }
}

// ---------- MFMA GEMM (fp32 A), 128x128 tile, 4-deep register pipeline ----------
__global__ __launch_bounds__(256, 1) void gemm_f32A(
    const float* __restrict__ A, const bf16* __restrict__ Bt,
    const float* __restrict__ bias, bf16* __restrict__ C, int K,
    const float* __restrict__ g, const float* __restrict__ be)
{
    __shared__ __align__(16) bf16 As[2][128 * SPAD];
    __shared__ __align__(16) bf16 Bs[2][128 * SPAD];
    const int tid = threadIdx.x;
    const int bm = blockIdx.y * 128, bn = blockIdx.x * 128;
    const int w = tid >> 6, lane = tid & 63;
    const int wm = (w & 1) * 64, wn = (w >> 1) * 64;
    const int lrow = lane & 15, lk8 = (lane >> 4) * 8;

    floatx4 acc[4][4];
#pragma unroll
    for (int i = 0; i < 4; i++)
#pragma unroll
        for (int j = 0; j < 4; j++) acc[i][j] = (floatx4){0.f, 0.f, 0.f, 0.f};

    const int r2 = tid >> 1, c2 = tid & 1;
    const float* gA = A + (size_t)(bm + r2) * K + c2 * 16;
    const bf16* gB = Bt + (size_t)(bn + r2) * K + c2 * 16;
    bf16* sA = &As[0][r2 * SPAD + c2 * 16];   // [p] via +128*SPAD
    bf16* sB = &Bs[0][r2 * SPAD + c2 * 16];

    const int nk = K >> 5;   // 40, divisible by 4
    float4 a[4][4];
    bf16x8 b[4][2];
#pragma unroll
    for (int u = 0; u < 4; u++) {
        const float* pa = gA + u * 32;
        a[u][0] = *(const float4*)(pa + 0);
        a[u][1] = *(const float4*)(pa + 4);
        a[u][2] = *(const float4*)(pa + 8);
        a[u][3] = *(const float4*)(pa + 12);
        const bf16* pb = gB + u * 32;
        b[u][0] = *(const bf16x8*)(pb + 0);
        b[u][1] = *(const bf16x8*)(pb + 8);
    }

    for (int it0 = 0; it0 < nk; it0 += 4) {
#pragma unroll
        for (int u = 0; u < 4; u++) {
            const int it = it0 + u;
            const int p = u & 1;
            const int po = p * 128 * SPAD;
            bf16x8 h0, h1;
            h0[0] = (bf16)a[u][0].x; h0[1] = (bf16)a[u][0].y; h0[2] = (bf16)a[u][0].z; h0[3] = (bf16)a[u][0].w;
            h0[4] = (bf16)a[u][1].x; h0[5] = (bf16)a[u][1].y; h0[6] = (bf16)a[u][1].z; h0[7] = (bf16)a[u][1].w;
            h1[0] = (bf16)a[u][2].x; h1[1] = (bf16)a[u][2].y; h1[2] = (bf16)a[u][2].z; h1[3] = (bf16)a[u][2].w;
            h1[4] = (bf16)a[u][3].x; h1[5] = (bf16)a[u][3].y; h1[6] = (bf16)a[u][3].z; h1[7] = (bf16)a[u][3].w;
            *(bf16x8*)(sA + po + 0) = h0;
            *(bf16x8*)(sA + po + 8) = h1;
            *(bf16x8*)(sB + po + 0) = b[u][0];
            *(bf16x8*)(sB + po + 8) = b[u][1];
            __syncthreads();
            if (it + 4 < nk) {
                const float* pa = gA + (it + 4) * 32;
                a[u][0] = *(const float4*)(pa + 0);
                a[u][1] = *(const float4*)(pa + 4);
                a[u][2] = *(const float4*)(pa + 8);
                a[u][3] = *(const float4*)(pa + 12);
                const bf16* pb = gB + (it + 4) * 32;
                b[u][0] = *(const bf16x8*)(pb + 0);
                b[u][1] = *(const bf16x8*)(pb + 8);
            }
            bf16x8 af[4], bfr[4];
#pragma unroll
            for (int i = 0; i < 4; i++) af[i] = *(const bf16x8*)&As[p][(wm + 16 * i + lrow) * SPAD + lk8];
#pragma unroll
            for (int j = 0; j < 4; j++) bfr[j] = *(const bf16x8*)&Bs[p][(wn + 16 * j + lrow) * SPAD + lk8];
#pragma unroll
            for (int i = 0; i < 4; i++)
#pragma unroll
                for (int j = 0; j < 4; j++)
                    acc[i][j] = __builtin_amdgcn_mfma_f32_16x16x32_bf16(af[i], bfr[j], acc[i][j], 0, 0, 0);
            // single barrier per iteration (dbuf ordering argument)
        }
    }

    const float inv = rsqrtf(1.f + EPSC);
#pragma unroll
    for (int j = 0; j < 4; j++) {
        int col = bn + wn + 16 * j + lrow;
        float bcol = bias[col];
        float gc = g[col] * inv;
        float bec = be[col];
#pragma unroll
        for (int i = 0; i < 4; i++) {
            int row0 = bm + wm + 16 * i + (lane >> 4) * 4;
#pragma unroll
            for (int r = 0; r < 4; r++) {
                float z = fmaxf(acc[i][j][r] + bcol, 0.f) * gc + bec;
                C[(size_t)(row0 + r) * HID + col] = (bf16)z;
            }
        }
    }
}

// ---------- CSR build ----------
__global__ void hist_kernel(const int* __restrict__ ei, int* __restrict__ cnt) {
    int e = blockIdx.x * 256 + threadIdx.x;
    if (e >= EPE) return;
    int d = (e < N_EDGES) ? ei[N_EDGES + e] : (e - N_EDGES);
    atomicAdd(&cnt[d], 1);
}

__global__ __launch_bounds__(1024) void scan_kernel(const int* __restrict__ cnt,
                                                    int* __restrict__ roff, int* __restrict__ cursor) {
    __shared__ int wsum[16];
    int t = threadIdx.x;
    int base = t * 16;
    int local[16]; int s = 0;
#pragma unroll
    for (int i = 0; i < 16; i++) {
        int idx = base + i;
        int v = (idx < N_NODES) ? cnt[idx] : 0;
        local[i] = s; s += v;
    }
    int lane = t & 63, wid = t >> 6;
    int incl = s;
    for (int o = 1; o < 64; o <<= 1) { int v = __shfl_up(incl, o); if (lane >= o) incl += v; }
    if (lane == 63) wsum[wid] = incl;
    __syncthreads();
    if (t == 0) { int a = 0; for (int k = 0; k < 16; k++) { int v = wsum[k]; wsum[k] = a; a += v; } }
    __syncthreads();
    int texcl = incl - s + wsum[wid];
#pragma unroll
    for (int i = 0; i < 16; i++) {
        int idx = base + i;
        if (idx < N_NODES) { int o = texcl + local[i]; roff[idx] = o; cursor[idx] = o; }
    }
    if (t == 1023) roff[N_NODES] = texcl + s;
}

__global__ void scatter_kernel(const int* __restrict__ ei, int* __restrict__ cursor,
                               int* __restrict__ esrc) {
    int e = blockIdx.x * 256 + threadIdx.x;
    if (e >= EPE) return;
    int s, d;
    if (e < N_EDGES) { s = ei[e]; d = ei[N_EDGES + e]; }
    else { s = d = e - N_EDGES; }
    int pos = atomicAdd(&cursor[d], 1);
    esrc[pos] = s;
}

// ---------- fused GATv2: parallel logits + parallel online softmax ----------
__global__ __launch_bounds__(256) void gat_fused(
    const bf16* __restrict__ XLR, const int* __restrict__ roff, const int* __restrict__ esrc,
    const float* __restrict__ att, const float* __restrict__ gbias, bf16* __restrict__ out)
{
    const int d = blockIdx.x, t = threadIdx.x;
    const int beg = roff[d], deg = roff[d + 1] - beg;
    __shared__ __align__(16) bf16 xs[CAP][XPAD];
    __shared__ __align__(16) float4 xa4[8 * 16];
    __shared__ float llog[CAP * 8];
    __shared__ float m_s[8], s_s[8], resc[8];

    if (t < 128) {
        int hh = t >> 4, cc = t & 15;
        int c = hh * 32 + cc * 2;
        float xr0 = (float)XLR[(size_t)d * 512 + 256 + c];
        float xr1 = (float)XLR[(size_t)d * 512 + 256 + c + 1];
        xa4[hh * 16 + cc] = (float4){xr0, att[c], xr1, att[c + 1]};
    }
    if (t < 8) { m_s[t] = -INFINITY; s_s[t] = 0.f; }

    const int jj = t & 31;
    const int hh = t >> 5;
    const int g = t >> 5, l = t & 31;
    float acc = 0.f;

    for (int c0 = 0; c0 < deg; c0 += CAP) {
        int cn = min(CAP, deg - c0);
        __syncthreads();
        for (int r = g; r < cn; r += 8) {
            int s = esrc[beg + c0 + r];
            *(bf16x8*)(&xs[r][l * 8]) = *(const bf16x8*)(XLR + (size_t)s * 512 + l * 8);
        }
        __syncthreads();
        if (jj < cn) {
            float lg = 0.f;
#pragma unroll
            for (int cc = 0; cc < 16; cc++) {
                int ce = (cc + jj) & 15;
                unsigned int p = *(const unsigned int*)&xs[jj][hh * 32 + ce * 2];
                float4 xa = xa4[hh * 16 + ce];
                lg += lrelu(bflo(p) + xa.x) * xa.y + lrelu(bfhi(p) + xa.z) * xa.w;
            }
            llog[jj * 8 + hh] = lg;
        }
        __syncthreads();
        if (t < 64) {
            int h2 = t & 7, j0 = t >> 3;
            float mx = -INFINITY;
            for (int j = j0; j < cn; j += 8) mx = fmaxf(mx, llog[j * 8 + h2]);
            for (int o = 8; o < 64; o <<= 1) mx = fmaxf(mx, __shfl_xor(mx, o));
            float mo = m_s[h2];
            float mn = fmaxf(mo, mx);
            float ss = 0.f;
            for (int j = j0; j < cn; j += 8) {
                float e = __expf(llog[j * 8 + h2] - mn);
                llog[j * 8 + h2] = e;
                ss += e;
            }
            for (int o = 8; o < 64; o <<= 1) ss += __shfl_xor(ss, o);
            if (t < 8) {
                float r = __expf(mo - mn);
                resc[h2] = r;
                s_s[h2] = s_s[h2] * r + ss;
                m_s[h2] = mn;
            }
        }
        __syncthreads();
        acc *= resc[hh];
        for (int j = 0; j < cn; j++)
            acc += llog[j * 8 + hh] * (float)xs[j][t];
    }
    out[(size_t)d * HID + t] = (bf16)(gbias[t] + acc / (s_s[hh] + 1e-16f));
}

// ---------- GIN gather: u[d] = sum over ALL CSR entries of h[src] ----------
__global__ __launch_bounds__(256) void gin_gather(
    const unsigned int* __restrict__ hu, const int* __restrict__ roff,
    const int* __restrict__ esrc, unsigned int* __restrict__ uu)
{
    int d = blockIdx.x, t = threadIdx.x;
    int grp = t >> 7, c = t & 127;
    int beg = roff[d], end = roff[d + 1];
    float a0 = 0.f, a1 = 0.f;
    int p = beg + grp;
    while (p + 14 < end) {
        int s[8];
#pragma unroll
        for (int k = 0; k < 8; k++) s[k] = esrc[p + 2 * k];
        unsigned int v[8];
#pragma unroll
        for (int k = 0; k < 8; k++) v[k] = hu[(size_t)s[k] * 128 + c];
#pragma unroll
        for (int k = 0; k < 8; k++) { a0 += bflo(v[k]); a1 += bfhi(v[k]); }
        p += 16;
    }
    for (; p < end; p += 2) {
        unsigned int v = hu[(size_t)esrc[p] * 128 + c];
        a0 += bflo(v); a1 += bfhi(v);
    }
    __shared__ float plo[128], phi[128];
    if (grp) { plo[c] = a0; phi[c] = a1; }
    __syncthreads();
    if (!grp) {
        a0 += plo[c]; a1 += phi[c];
        bf16 b0 = (bf16)a0, b1 = (bf16)a1;
        unsigned int r = ((unsigned int)*(unsigned short*)&b0) |
                         (((unsigned int)*(unsigned short*)&b1) << 16);
        uu[(size_t)d * 128 + c] = r;
    }
}

// ---------- global LN ----------
__global__ void stats_kernel(const bf16* __restrict__ x, float2* __restrict__ part, int n8) {
    float s = 0.f, sq = 0.f;
    for (int i = blockIdx.x * blockDim.x + threadIdx.x; i < n8; i += gridDim.x * blockDim.x) {
        bf16x8 v = *(const bf16x8*)(x + (size_t)i * 8);
#pragma unroll
        for (int j = 0; j < 8; j++) { float f = (float)v[j]; s += f; sq += f * f; }
    }
    for (int o = 32; o > 0; o >>= 1) { s += __shfl_down(s, o); sq += __shfl_down(sq, o); }
    __shared__ float ls[4], lq[4];
    int wid = threadIdx.x >> 6, lane = threadIdx.x & 63;
    if (lane == 0) { ls[wid] = s; lq[wid] = sq; }
    __syncthreads();
    if (threadIdx.x == 0)
        part[blockIdx.x] = make_float2(ls[0] + ls[1] + ls[2] + ls[3],
                                       lq[0] + lq[1] + lq[2] + lq[3]);
}

__global__ void stats_reduce(const float2* __restrict__ part, float* __restrict__ stat) {
    int t = threadIdx.x;
    float2 v = part[t];
    float s = v.x, q = v.y;
    for (int o = 32; o > 0; o >>= 1) { s += __shfl_down(s, o); q += __shfl_down(q, o); }
    __shared__ float ls[4], lq[4];
    int wid = t >> 6, lane = t & 63;
    if (lane == 0) { ls[wid] = s; lq[wid] = q; }
    __syncthreads();
    if (t == 0) { stat[0] = ls[0] + ls[1] + ls[2] + ls[3]; stat[1] = lq[0] + lq[1] + lq[2] + lq[3]; }
}

__global__ void ln_res_kernel(const bf16* __restrict__ h, const bf16* __restrict__ r,
                              const float* __restrict__ stats, const float* __restrict__ g,
                              const float* __restrict__ b, bf16* __restrict__ out)
{
    int i = (blockIdx.x * 256 + threadIdx.x) * 4;
    const float inv_n = 1.f / (float)((size_t)N_NODES * HID);
    float mu = stats[0] * inv_n;
    float var = stats[1] * inv_n - mu * mu;
    float sd = sqrtf(fmaxf(var, 0.f));
    float rs = 1.f / (sd + EPSC);
    int ch = i & (HID - 1);
#pragma unroll
    for (int j = 0; j < 4; j++) {
        float v = ((float)h[i + j] - mu) * rs * g[ch + j] + b[ch + j] + (float)r[i + j];
        out[i + j] = (bf16)lrelu(v);
    }
}

// ---------- pooling ----------
__global__ void gbound_kernel(const int* __restrict__ batch, int* __restrict__ gstart) {
    int g = threadIdx.x;
    if (g > NG) return;
    int lo = 0, hi = N_NODES;
    while (lo < hi) { int mid = (lo + hi) >> 1; if (batch[mid] < g) lo = mid + 1; else hi = mid; }
    gstart[g] = lo;
}

__global__ __launch_bounds__(256) void pool_gate_kernel(const bf16* __restrict__ t,
    const float* __restrict__ W2, const float* __restrict__ b2, float* __restrict__ gate)
{
    int n = blockIdx.x * 4 + (threadIdx.x >> 6);
    int lane = threadIdx.x & 63;
    const bf16* p = t + (size_t)n * HID + lane * 4;
    float4 w = *(const float4*)(W2 + lane * 4);
    float s = tanhf((float)p[0]) * w.x + tanhf((float)p[1]) * w.y
            + tanhf((float)p[2]) * w.z + tanhf((float)p[3]) * w.w;
    for (int o = 32; o > 0; o >>= 1) s += __shfl_down(s, o);
    if (lane == 0) gate[n] = s + b2[0];
}

__global__ __launch_bounds__(256) void pool_stats_kernel(
    float* __restrict__ gate, const int* __restrict__ gstart)
{
    int g = blockIdx.x, t = threadIdx.x;
    int lo = gstart[g], hi = gstart[g + 1];
    __shared__ float red[256];
    float m = -INFINITY;
    for (int n = lo + t; n < hi; n += 256) m = fmaxf(m, gate[n]);
    red[t] = m; __syncthreads();
    for (int st = 128; st > 0; st >>= 1) { if (t < st) red[t] = fmaxf(red[t], red[t + st]); __syncthreads(); }
    m = red[0]; __syncthreads();
    float s = 0.f;
    for (int n = lo + t; n < hi; n += 256) s += __expf(gate[n] - m);
    red[t] = s; __syncthreads();
    for (int st = 128; st > 0; st >>= 1) { if (t < st) red[t] += red[t + st]; __syncthreads(); }
    float sinv = 1.f / (red[0] + 1e-16f);
    for (int n = lo + t; n < hi; n += 256) gate[n] = __expf(gate[n] - m) * sinv;
}

__global__ __launch_bounds__(256) void emb_accum_kernel(
    const float* __restrict__ a, const int* __restrict__ batch,
    const bf16* __restrict__ h, float* __restrict__ emb)
{
    int n0 = blockIdx.x * 32, t = threadIdx.x;
    int cur = batch[n0]; float acc = 0.f;
    for (int j = 0; j < 32; j++) {
        int n = n0 + j;
        int b = batch[n];
        if (b != cur) { atomicAdd(&emb[cur * HID + t], acc); cur = b; acc = 0.f; }
        acc += a[n] * (float)h[(size_t)n * HID + t];
    }
    atomicAdd(&emb[cur * HID + t], acc);
}

// ---------- label heads ----------
__global__ __launch_bounds__(256) void heads_kernel(
    const float* __restrict__ emb, const float* __restrict__ W1, const float* __restrict__ b1,
    const float* __restrict__ hg, const float* __restrict__ hbe, const float* __restrict__ W2,
    const float* __restrict__ b2, float* __restrict__ out)
{
    int o = blockIdx.x;
    int g0 = blockIdx.y * 4;
    int k = threadIdx.x;
    __shared__ float se[4][HID];
    __shared__ float red[256];
#pragma unroll
    for (int j = 0; j < 4; j++) se[j][k] = emb[(g0 + j) * HID + k];
    __syncthreads();
    const float* w1p = W1 + (size_t)o * HID * HID + k;
    float zb = b1[o * HID + k];
    float z0 = zb, z1 = zb, z2 = zb, z3 = zb;
#pragma unroll 8
    for (int d = 0; d < HID; d++) {
        float w = w1p[(size_t)d * HID];
        z0 = fmaf(se[0][d], w, z0);
        z1 = fmaf(se[1][d], w, z1);
        z2 = fmaf(se[2][d], w, z2);
        z3 = fmaf(se[3][d], w, z3);
    }
    const float gk = hg[o * HID + k] * rsqrtf(1.f + EPSC);
    const float bek = hbe[o * HID + k];
    const float w2 = W2[o * HID + k];
    const float b2o = b2[o];
    float zz[4] = {z0, z1, z2, z3};
#pragma unroll
    for (int j = 0; j < 4; j++) {
        float z = zz[j];
        float sil = z / (1.f + expf(-z));
        red[k] = (sil * gk + bek) * w2;
        __syncthreads();
        for (int st = 128; st > 0; st >>= 1) { if (k < st) red[k] += red[k + st]; __syncthreads(); }
        if (k == 0) out[(g0 + j) * NO + o] = red[0] + b2o;
        __syncthreads();
    }
}

extern "C" void kernel_launch(void* const* d_in, const int* in_sizes, int n_in,
                              void* d_out, int out_size, void* d_ws, size_t ws_size,
                              hipStream_t stream) {
    const float* x        = (const float*)d_in[0];
    const int*   ei       = (const int*)  d_in[1];
    const int*   batch    = (const int*)  d_in[2];
    const float* fp_W     = (const float*)d_in[3];
    const float* fp_b     = (const float*)d_in[4];
    const float* fp_g     = (const float*)d_in[5];
    const float* fp_be    = (const float*)d_in[6];
    const float* gat_Wl   = (const float*)d_in[7];
    const float* gat_bl   = (const float*)d_in[8];
    const float* gat_Wr   = (const float*)d_in[9];
    const float* gat_br   = (const float*)d_in[10];
    const float* gat_att  = (const float*)d_in[11];
    const float* gat_bias = (const float*)d_in[12];
    const float* gin_W    = (const float*)d_in[13];
    const float* gin_b    = (const float*)d_in[14];
    const float* gin_g    = (const float*)d_in[15];
    const float* gin_be   = (const float*)d_in[16];
    const float* ln_g     = (const float*)d_in[17];
    const float* ln_b     = (const float*)d_in[18];
    const float* res_W    = (const float*)d_in[19];
    const float* res_b    = (const float*)d_in[20];
    const float* pool_W1  = (const float*)d_in[21];
    const float* pool_b1  = (const float*)d_in[22];
    const float* pool_W2  = (const float*)d_in[23];
    const float* pool_b2  = (const float*)d_in[24];
    const float* head_W1  = (const float*)d_in[25];
    const float* head_b1  = (const float*)d_in[26];
    const float* head_g   = (const float*)d_in[27];
    const float* head_be  = (const float*)d_in[28];
    const float* head_W2  = (const float*)d_in[29];
    const float* head_b2  = (const float*)d_in[30];
    float* out = (float*)d_out;

    char* base = (char*)d_ws;
    size_t off = 0;
    auto alloc = [&](size_t bytes) -> char* {
        char* p = base + off; off += (bytes + 255) & ~(size_t)255; return p;
    };
    int*   esrc   = (int*)  alloc((size_t)EPE * 4);
    int*   cnt    = (int*)  alloc((size_t)N_NODES * 4);
    int*   roff   = (int*)  alloc((size_t)(N_NODES + 1) * 4);
    int*   cursor = (int*)  alloc((size_t)N_NODES * 4);
    float* gate   = (float*)alloc((size_t)N_NODES * 4);
    int*   gstart = (int*)  alloc((NG + 1) * 4);
    float* emb    = (float*)alloc(NG * HID * 4);
    float* stat   = (float*)alloc(8);
    float2* statp = (float2*)alloc(256 * 8);
    bf16*  Hb0    = (bf16*) alloc((size_t)N_NODES * HID * 2);
    bf16*  Hb1    = (bf16*) alloc((size_t)N_NODES * HID * 2);
    bf16*  XLR    = (bf16*) alloc((size_t)N_NODES * 512 * 2);
    bf16*  fpWt   = (bf16*) alloc((size_t)DIN * HID * 2);
    bf16*  wlrT0  = (bf16*) alloc((size_t)512 * HID * 2);
    bf16*  wlrT1  = (bf16*) alloc((size_t)512 * HID * 2);
    bf16*  gwT    = (bf16*) alloc((size_t)2 * HID * HID * 2);
    bf16*  rwT    = (bf16*) alloc((size_t)2 * HID * HID * 2);
    bf16*  pwT    = (bf16*) alloc((size_t)HID * HID * 2);
    bf16*  Ub     = XLR;
    bf16*  wlrT[2] = { wlrT0, wlrT1 };

    // ---- weight conversions ----
    wconv_gen<<<(DIN * HID + 255) / 256, 256, 0, stream>>>(fp_W, fpWt, DIN, DIN * HID);
    wconv_pair<<<512, 256, 0, stream>>>(gat_Wl, gat_Wr, wlrT0);
    wconv_pair<<<512, 256, 0, stream>>>(gat_Wl + HID * HID, gat_Wr + HID * HID, wlrT1);
    wconv_gen<<<512, 256, 0, stream>>>(gin_W, gwT, HID, 2 * HID * HID);
    wconv_gen<<<512, 256, 0, stream>>>(res_W, rwT, HID, 2 * HID * HID);
    wconv_gen<<<256, 256, 0, stream>>>(pool_W1, pwT, HID, HID * HID);

    // ---- CSR build ----
    hipMemsetAsync(cnt, 0, N_NODES * sizeof(int), stream);
    hist_kernel<<<(EPE + 255) / 256, 256, 0, stream>>>(ei, cnt);
    scan_kernel<<<1, 1024, 0, stream>>>(cnt, roff, cursor);
    scatter_kernel<<<(EPE + 255) / 256, 256, 0, stream>>>(ei, cursor, esrc);
    gbound_kernel<<<1, 64, 0, stream>>>(batch, gstart);

    // ---- feature projection ----
    dim3 gridF(2, 125);          // 128x128 tiles
    dim3 g64_256(4, 250);        // 64x64 tiles, 256 cols
    dim3 g64_512(8, 250);        // 64x64 tiles, 512 cols
    gemm_f32A<<<gridF, 256, 0, stream>>>(x, fpWt, fp_b, Hb0, DIN, fp_g, fp_be);

    for (int i = 0; i < 2; i++) {
        gemm64<<<g64_512, 256, 0, stream>>>(Hb0, wlrT[i], gat_bl + i * HID, gat_br + i * HID,
                                            XLR, HID, 512, 0, nullptr, nullptr);
        gat_fused<<<N_NODES, 256, 0, stream>>>(XLR, roff, esrc, gat_att + i * HEADS * CPH,
                                               gat_bias + i * HID, Hb1);
        gin_gather<<<N_NODES, 256, 0, stream>>>((const unsigned int*)Hb1, roff, esrc,
                                                (unsigned int*)Ub);
        gemm64<<<g64_256, 256, 0, stream>>>(Ub, gwT + (size_t)i * HID * HID, gin_b + i * HID,
                                            nullptr, Hb0, HID, HID, 2,
                                            gin_g + i * HID, gin_be + i * HID);
        stats_kernel<<<256, 256, 0, stream>>>(Hb0, statp, (N_NODES * HID) / 8);
        stats_reduce<<<1, 256, 0, stream>>>(statp, stat);
        gemm64<<<g64_256, 256, 0, stream>>>(Hb0, rwT + (size_t)i * HID * HID, res_b + i * HID,
                                            nullptr, Hb1, HID, HID, 0, nullptr, nullptr);
        ln_res_kernel<<<(N_NODES * HID) / 1024, 256, 0, stream>>>(Hb0, Hb1, stat,
                                                                  ln_g + i * HID, ln_b + i * HID, Hb0);
    }

    // ---- global attention pooling ----
    gemm64<<<g64_256, 256, 0, stream>>>(Hb0, pwT, pool_b1, nullptr, Hb1, HID, HID, 0, nullptr, nullptr);
    pool_gate_kernel<<<N_NODES / 4, 256, 0, stream>>>(Hb1, pool_W2, pool_b2, gate);
    pool_stats_kernel<<<NG, 256, 0, stream>>>(gate, gstart);
    hipMemsetAsync(emb, 0, NG * HID * sizeof(float), stream);
    emb_accum_kernel<<<N_NODES / 32, 256, 0, stream>>>(gate, batch, Hb0, emb);

    // ---- label heads ----
    dim3 hgrid(NO, 8);
    heads_kernel<<<hgrid, 256, 0, stream>>>(emb, head_W1, head_b1, head_g, head_be,
                                            head_W2, head_b2, out);
}